// Round 1
// baseline (828.949 us; speedup 1.0000x reference)
//
#include <hip/hip_runtime.h>

// ============================================================================
// FastRCNN Relation FC Head, MI355X round 1.
// Pipeline: converts -> pos/logw fused kernel -> per layer {FC, Q, K, KVt
// GEMMs (bf16 MFMA 128x128 m97-style), fused attention (QK^T -> softmax ->
// PV -> residual+relu)}.  KV fusion: KVt[g,o,m] = sum_c Wo[g,o,c]*x[m,c]
// precomputed so PV is (4096,16,300)x(300,64) instead of (...,1024).
// Workspace requirement: ~271 MB.
// ============================================================================

using bf16x8 = __attribute__((ext_vector_type(8))) short;
using f32x4  = __attribute__((ext_vector_type(4))) float;
typedef unsigned short u16;
typedef unsigned int   u32;

#define DEV __device__ __forceinline__

DEV u16 f2bf(float f) {                      // fp32 -> bf16, round-nearest-even
  u32 u = __float_as_uint(f);
  return (u16)((u + 0x7FFFu + ((u >> 16) & 1u)) >> 16);
}
DEV float bf2f(u16 h) { return __uint_as_float(((u32)h) << 16); }

DEV f32x4 mfma16(bf16x8 a, bf16x8 b, f32x4 c) {
  return __builtin_amdgcn_mfma_f32_16x16x32_bf16(a, b, c, 0, 0, 0);
}
DEV void gload16(const u16* g, u16* l) {
  __builtin_amdgcn_global_load_lds((const __attribute__((address_space(1))) void*)g,
                                   (__attribute__((address_space(3))) void*)l, 16, 0, 0);
}

// exact-identity range reduction, then native sin/cos on [-pi,pi]
DEV void fsincos(float x, float* s, float* c) {
  float r = x * 0.15915494309189535f;   // revolutions
  r -= rintf(r);
  float a = r * 6.283185307179586f;
  *s = __sinf(a); *c = __cosf(a);
}

// ---------------------------------------------------------------------------
// plain fp32 -> bf16 convert (n % 8 == 0)
// ---------------------------------------------------------------------------
__global__ __launch_bounds__(256) void convert_kernel(const float* __restrict__ src,
                                                      u16* __restrict__ dst, size_t n) {
  size_t i = ((size_t)blockIdx.x * 256 + threadIdx.x) * 8;
  size_t stride = (size_t)gridDim.x * 256 * 8;
  for (; i < n; i += stride) {
    float4 a = *(const float4*)(src + i);
    float4 b = *(const float4*)(src + i + 4);
    bf16x8 v;
    v[0]=(short)f2bf(a.x); v[1]=(short)f2bf(a.y); v[2]=(short)f2bf(a.z); v[3]=(short)f2bf(a.w);
    v[4]=(short)f2bf(b.x); v[5]=(short)f2bf(b.y); v[6]=(short)f2bf(b.z); v[7]=(short)f2bf(b.w);
    *(bf16x8*)(dst + i) = v;
  }
}

// ---------------------------------------------------------------------------
// transpose + convert: in fp32 [R][C]  ->  out bf16 [C][R]
// ---------------------------------------------------------------------------
__global__ __launch_bounds__(256) void tconv_kernel(const float* __restrict__ in,
                                                    u16* __restrict__ out, int R, int C) {
  __shared__ float t[32][33];
  int tx = threadIdx.x & 31, ty = threadIdx.x >> 5;
  int r0 = blockIdx.y * 32, c0 = blockIdx.x * 32;
#pragma unroll
  for (int i = 0; i < 4; i++) {
    int r = r0 + ty + i * 8;
    if (r < R && (c0 + tx) < C) t[ty + i * 8][tx] = in[(size_t)r * C + c0 + tx];
  }
  __syncthreads();
#pragma unroll
  for (int i = 0; i < 4; i++) {
    int c = c0 + ty + i * 8;
    if (c < C && (r0 + tx) < R) out[(size_t)c * R + r0 + tx] = f2bf(t[tx][ty + i * 8]);
  }
}

// ---------------------------------------------------------------------------
// fused position-matrix -> sincos embedding -> @Wpos(both layers) -> relu ->
// log -> logw tables.  One block per n; loops 5 m-tiles of 64.
// logw layout: [layer][g][n][320], bf16, only m<300 written (pad never read).
// ---------------------------------------------------------------------------
__constant__ float C100D[8] = {100.f, 42.16965034285822f, 17.78279410038923f,
                               7.498942093324559f, 3.1622776601683795f,
                               1.333521432163324f, 0.5623413251903491f,
                               0.23713737056616552f};

__global__ __launch_bounds__(256) void pos_logw_kernel(
    const float* __restrict__ bbox, const u16* __restrict__ wpos_t,
    const float* __restrict__ bpos1, const float* __restrict__ bpos2,
    u16* __restrict__ logw1, u16* __restrict__ logw2) {
  __shared__ u16 emb_s[64 * 88];   // [m_local][e] pad 88 (2-way banks, 16B rows)
  __shared__ u16 wp_s[32 * 88];    // [col(layer,g)][e]
  int tid = threadIdx.x;
  int n = blockIdx.x;
  int w = tid >> 6, l = tid & 63, h = l >> 4, l15 = l & 15;
  { // stage Wpos_t [32][64] -> padded
    int row = tid >> 3, seg = tid & 7;
    bf16x8 v = *(const bf16x8*)(wpos_t + row * 64 + seg * 8);
    *(bf16x8*)(&wp_s[row * 88 + seg * 8]) = v;
  }
  float4 bn = ((const float4*)bbox)[n];
  float bw_n = bn.z - bn.x + 1.f, bh_n = bn.w - bn.y + 1.f;
  float cx_n = 0.5f * (bn.x + bn.z), cy_n = 0.5f * (bn.y + bn.w);
  float bps0 = bpos1[l15], bps1 = bpos2[l15];
  int p = tid >> 2, k = tid & 3;

  for (int m0 = 0; m0 < 320; m0 += 64) {
    int m = m0 + p;                       // < 320 <= 4095, always valid memory
    float4 bm = ((const float4*)bbox)[m];
    float v;
    if (k == 0)      v = logf(fmaxf(fabsf((cx_n - 0.5f * (bm.x + bm.z)) / bw_n), 1e-3f));
    else if (k == 1) v = logf(fmaxf(fabsf((cy_n - 0.5f * (bm.y + bm.w)) / bh_n), 1e-3f));
    else if (k == 2) v = logf(bw_n / (bm.z - bm.x + 1.f));
    else             v = logf(bh_n / (bm.w - bm.y + 1.f));
    __syncthreads();                      // protect previous tile's frag reads
#pragma unroll
    for (int tt = 0; tt < 8; tt++) {
      float s, c; fsincos(v * C100D[tt], &s, &c);
      emb_s[p * 88 + k * 16 + tt]     = f2bf(s);
      emb_s[p * 88 + k * 16 + 8 + tt] = f2bf(c);
    }
    __syncthreads();
    // MFMA: rows = 64 m's (wave w owns 16), cols = 32 (layer,g)
    f32x4 acc0 = {0.f, 0.f, 0.f, 0.f}, acc1 = {0.f, 0.f, 0.f, 0.f};
    bf16x8 a0 = *(const bf16x8*)&emb_s[(w * 16 + l15) * 88 + h * 8];
    bf16x8 a1 = *(const bf16x8*)&emb_s[(w * 16 + l15) * 88 + 32 + h * 8];
    bf16x8 b00 = *(const bf16x8*)&wp_s[l15 * 88 + h * 8];
    bf16x8 b01 = *(const bf16x8*)&wp_s[l15 * 88 + 32 + h * 8];
    bf16x8 b10 = *(const bf16x8*)&wp_s[(16 + l15) * 88 + h * 8];
    bf16x8 b11 = *(const bf16x8*)&wp_s[(16 + l15) * 88 + 32 + h * 8];
    acc0 = mfma16(a0, b00, acc0); acc0 = mfma16(a1, b01, acc0);
    acc1 = mfma16(a0, b10, acc1); acc1 = mfma16(a1, b11, acc1);
#pragma unroll
    for (int r = 0; r < 4; r++) {
      int mm = m0 + w * 16 + h * 4 + r;
      if (mm < 300) {
        float va = acc0[r] + bps0;
        logw1[((size_t)l15 * 4096 + n) * 320 + mm] = f2bf(logf(fmaxf(va, 1e-6f)));
        float vb = acc1[r] + bps1;
        logw2[((size_t)l15 * 4096 + n) * 320 + mm] = f2bf(logf(fmaxf(vb, 1e-6f)));
      }
    }
  }
}

// ---------------------------------------------------------------------------
// 128x128 bf16 MFMA GEMM, C = A[MxK] * Bt[NxK]^T (+bias).  BK=32, 4 waves,
// global_load_lds staging (m97 structure).  EPI: 0=bias+f32+bf16 (FC),
// 1=bias+bf16 (Q/K), 2=no-bias bf16, zero-fill pad cols (KVt).
// ---------------------------------------------------------------------------
template <int EPI, bool MG, bool NG>
__global__ __launch_bounds__(256) void gemm_bt(
    const u16* __restrict__ A, const u16* __restrict__ Bt,
    const float* __restrict__ bias, float* __restrict__ Cf, u16* __restrict__ Cb,
    int M, int N, int K, int ldc) {
  __shared__ u16 As[128 * 32];
  __shared__ u16 Bs[128 * 32];
  int tid = threadIdx.x;
  int w = tid >> 6, l = tid & 63, h = l >> 4, l15 = l & 15;
  int bm = blockIdx.x * 128, bn = blockIdx.y * 128;
  int wr = (w >> 1) * 64, wc = (w & 1) * 64;
  f32x4 acc[4][4];
#pragma unroll
  for (int i = 0; i < 4; i++)
#pragma unroll
    for (int j = 0; j < 4; j++) acc[i][j] = (f32x4){0.f, 0.f, 0.f, 0.f};

  int o0 = w * 1024 + l * 16;              // linear LDS byte offset (instr 0)
  int arow0 = o0 >> 6;                     // bf16 row (64B rows of 32 elems)
  int ace = (o0 & 63) >> 1;                // element offset in row

  int ra0 = bm + arow0, ra1 = ra0 + 64;
  if (MG) { ra0 = min(ra0, M - 1); ra1 = min(ra1, M - 1); }
  int jb0 = bn + arow0, jb1 = jb0 + 64;
  if (NG) { jb0 = min(jb0, N - 1); jb1 = min(jb1, N - 1); }

  for (int kt = 0; kt < K; kt += 32) {
    __syncthreads();
    gload16(A  + (size_t)ra0 * K + kt + ace, &As[(size_t)arow0 * 32 + ace]);
    gload16(A  + (size_t)ra1 * K + kt + ace, &As[(size_t)(arow0 + 64) * 32 + ace]);
    gload16(Bt + (size_t)jb0 * K + kt + ace, &Bs[(size_t)arow0 * 32 + ace]);
    gload16(Bt + (size_t)jb1 * K + kt + ace, &Bs[(size_t)(arow0 + 64) * 32 + ace]);
    __syncthreads();
    bf16x8 af[4], bfr[4];
#pragma unroll
    for (int i = 0; i < 4; i++) {
      af[i]  = *(const bf16x8*)&As[(wr + i * 16 + l15) * 32 + h * 8];
      bfr[i] = *(const bf16x8*)&Bs[(wc + i * 16 + l15) * 32 + h * 8];
    }
#pragma unroll
    for (int i = 0; i < 4; i++)
#pragma unroll
      for (int j = 0; j < 4; j++) acc[i][j] = mfma16(af[i], bfr[j], acc[i][j]);
  }
  // epilogue
#pragma unroll
  for (int i = 0; i < 4; i++) {
#pragma unroll
    for (int j = 0; j < 4; j++) {
      int row0 = bm + wr + i * 16 + h * 4;
      int col  = bn + wc + j * 16 + l15;
      if (col >= ldc) continue;
      bool cval = !NG || (col < N);
      float bv = 0.f;
      if (EPI != 2 && cval) bv = bias[col];
#pragma unroll
      for (int r = 0; r < 4; r++) {
        int row = row0 + r;
        if (MG && row >= M) continue;
        float v = cval ? (acc[i][j][r] + bv) : 0.f;   // zero-fill pad cols
        size_t off = (size_t)row * ldc + col;
        if (EPI == 0) { Cf[off] = v; Cb[off] = f2bf(v); }
        else Cb[off] = f2bf(v);
      }
    }
  }
}

// ---------------------------------------------------------------------------
// fused attention: per (64-row n-tile, head g).
//  aff = Q K^T /8 (MFMA, K in LDS, Q frags direct from global)
//  logits = aff + logw;  softmax over m (300, padded 320) in registers
//  P -> LDS (stride 344: 2-way banks) ; PV MFMA vs KVt LDS ([o][m], stride 344)
//  epilogue: out = relu(xf + PV/sum + bo) -> bf16 (mid) or f32 d_out (last)
// ---------------------------------------------------------------------------
template <bool LAST>
__global__ __launch_bounds__(256) void attn_kernel(
    const u16* __restrict__ qb, const u16* __restrict__ kb,
    const u16* __restrict__ kvt, const u16* __restrict__ logw,
    const float* __restrict__ xf, const float* __restrict__ bo,
    float* __restrict__ outf, u16* __restrict__ outb) {
  __shared__ u16 kp_s[320 * 88];    // K [m][d] pad 88; reused as P [n][344]
  __shared__ u16 kv_s[64 * 344];    // KVt [o][m] pad 344
  int tid = threadIdx.x;
  int g = blockIdx.y, n0 = blockIdx.x * 64;
  int w = tid >> 6, l = tid & 63, h = l >> 4, l15 = l & 15;

  for (int i = tid; i < 320 * 8; i += 256) {        // stage K (zeros m>=300)
    int row = i >> 3, seg = i & 7;
    bf16x8 v = {0, 0, 0, 0, 0, 0, 0, 0};
    if (row < 300) v = *(const bf16x8*)(kb + (size_t)row * 1024 + g * 64 + seg * 8);
    *(bf16x8*)&kp_s[row * 88 + seg * 8] = v;
  }
  for (int i = tid; i < 64 * 40; i += 256) {        // stage KVt
    int row = i / 40, seg = i % 40;
    bf16x8 v = *(const bf16x8*)(kvt + (size_t)(g * 64 + row) * 320 + seg * 8);
    *(bf16x8*)&kv_s[row * 344 + seg * 8] = v;
  }
  int nrow = n0 + w * 16 + l15;                     // Q A-frags direct global
  bf16x8 aq0 = *(const bf16x8*)(qb + (size_t)nrow * 1024 + g * 64 + h * 8);
  bf16x8 aq1 = *(const bf16x8*)(qb + (size_t)nrow * 1024 + g * 64 + 32 + h * 8);
  __syncthreads();

  f32x4 acc[19];
#pragma unroll
  for (int f = 0; f < 19; f++) acc[f] = (f32x4){0.f, 0.f, 0.f, 0.f};
#pragma unroll
  for (int f = 0; f < 19; f++) {
    bf16x8 b0 = *(const bf16x8*)&kp_s[(f * 16 + l15) * 88 + h * 8];
    bf16x8 b1 = *(const bf16x8*)&kp_s[(f * 16 + l15) * 88 + 32 + h * 8];
    acc[f] = mfma16(aq0, b0, acc[f]);
    acc[f] = mfma16(aq1, b1, acc[f]);
  }
  // logits + row softmax (rows live on 16-lane groups)
  int nbase = n0 + w * 16 + h * 4;
  float mx[4] = {-INFINITY, -INFINITY, -INFINITY, -INFINITY};
  float sm[4] = {0.f, 0.f, 0.f, 0.f};
#pragma unroll
  for (int f = 0; f < 19; f++) {
    int m = f * 16 + l15;
#pragma unroll
    for (int r = 0; r < 4; r++) {
      float lw = -INFINITY;
      if (m < 300) lw = bf2f(logw[((size_t)g * 4096 + nbase + r) * 320 + m]);
      float lg = acc[f][r] * 0.125f + lw;
      acc[f][r] = lg;
      mx[r] = fmaxf(mx[r], lg);
    }
  }
#pragma unroll
  for (int d = 1; d < 16; d <<= 1)
#pragma unroll
    for (int r = 0; r < 4; r++) mx[r] = fmaxf(mx[r], __shfl_xor(mx[r], d));
#pragma unroll
  for (int f = 0; f < 19; f++)
#pragma unroll
    for (int r = 0; r < 4; r++) {
      float p = __expf(acc[f][r] - mx[r]);
      acc[f][r] = p; sm[r] += p;
    }
#pragma unroll
  for (int d = 1; d < 16; d <<= 1)
#pragma unroll
    for (int r = 0; r < 4; r++) sm[r] += __shfl_xor(sm[r], d);
  float inv[4];
#pragma unroll
  for (int r = 0; r < 4; r++) inv[r] = 1.f / sm[r];

  __syncthreads();                     // all waves done reading K region
#pragma unroll
  for (int f = 0; f < 19; f++)
#pragma unroll
    for (int r = 0; r < 4; r++)
      kp_s[(w * 16 + h * 4 + r) * 344 + f * 16 + l15] = f2bf(acc[f][r]);
#pragma unroll
  for (int r = 0; r < 4; r++)          // zero pad m 304..319
    kp_s[(w * 16 + h * 4 + r) * 344 + 304 + l15] = 0;

  f32x4 acc2[4];
#pragma unroll
  for (int fo = 0; fo < 4; fo++) acc2[fo] = (f32x4){0.f, 0.f, 0.f, 0.f};
#pragma unroll
  for (int ks = 0; ks < 10; ks++) {
    bf16x8 ap = *(const bf16x8*)&kp_s[(w * 16 + l15) * 344 + ks * 32 + h * 8];
#pragma unroll
    for (int fo = 0; fo < 4; fo++) {
      bf16x8 bv = *(const bf16x8*)&kv_s[(fo * 16 + l15) * 344 + ks * 32 + h * 8];
      acc2[fo] = mfma16(ap, bv, acc2[fo]);
    }
  }
#pragma unroll
  for (int fo = 0; fo < 4; fo++) {
    int col = g * 64 + fo * 16 + l15;
    float bov = bo[col];
#pragma unroll
    for (int r = 0; r < 4; r++) {
      int row = nbase + r;
      float v = xf[(size_t)row * 1024 + col] + acc2[fo][r] * inv[r] + bov;
      v = fmaxf(v, 0.f);
      if (LAST) outf[(size_t)row * 1024 + col] = v;
      else      outb[(size_t)row * 1024 + col] = f2bf(v);
    }
  }
}

// ---------------------------------------------------------------------------
extern "C" void kernel_launch(void* const* d_in, const int* in_sizes, int n_in,
                              void* d_out, int out_size, void* d_ws, size_t ws_size,
                              hipStream_t stream) {
  (void)in_sizes; (void)n_in; (void)out_size; (void)ws_size;
  const float* roi   = (const float*)d_in[0];
  const float* bbox  = (const float*)d_in[1];
  const float* Wfc1  = (const float*)d_in[2];
  const float* bfc1  = (const float*)d_in[3];
  const float* Wfc2  = (const float*)d_in[4];
  const float* bfc2  = (const float*)d_in[5];
  const float* Wpos1 = (const float*)d_in[6];
  const float* bpos1 = (const float*)d_in[7];
  const float* Wq1   = (const float*)d_in[8];
  const float* bq1   = (const float*)d_in[9];
  const float* Wk1   = (const float*)d_in[10];
  const float* bk1   = (const float*)d_in[11];
  const float* Wo1   = (const float*)d_in[12];
  const float* bo1   = (const float*)d_in[13];
  const float* Wpos2 = (const float*)d_in[14];
  const float* bpos2 = (const float*)d_in[15];
  const float* Wq2   = (const float*)d_in[16];
  const float* bq2   = (const float*)d_in[17];
  const float* Wk2   = (const float*)d_in[18];
  const float* bk2   = (const float*)d_in[19];
  const float* Wo2   = (const float*)d_in[20];
  const float* bo2   = (const float*)d_in[21];

  char* ws = (char*)d_ws;                       // ---- workspace arena ----
  u16*  A_b    = (u16*)(ws);                    // 102,760,448
  u16*  Wfc1_t = (u16*)(ws + 102760448);        //  25,690,112
  u16*  Wfc2_t = (u16*)(ws + 128450560);        //   2,097,152
  u16*  Wq1_t  = (u16*)(ws + 130547712);
  u16*  Wk1_t  = (u16*)(ws + 132644864);
  u16*  Wq2_t  = (u16*)(ws + 134742016);
  u16*  Wk2_t  = (u16*)(ws + 136839168);
  u16*  Wo1_b  = (u16*)(ws + 138936320);
  u16*  Wo2_b  = (u16*)(ws + 141033472);
  u16*  Wpos_t = (u16*)(ws + 143130624);        //       4,096
  u16*  logw1  = (u16*)(ws + 143134720);        //  41,943,040
  u16*  logw2  = (u16*)(ws + 185077760);
  float* xf    = (float*)(ws + 227020800);      //  16,777,216
  u16*  xb_f   = (u16*)(ws + 243798016);        //   8,388,608 (fc out, bf16)
  u16*  xb_a   = (u16*)(ws + 252186624);        //   8,388,608 (attn out, bf16)
  u16*  q_b    = (u16*)(ws + 260575232);
  u16*  k_b    = (u16*)(ws + 268963840);        //     614,400
  u16*  kvt_b  = (u16*)(ws + 269578240);        //     655,360  (end 270,233,600)

  // converts
  convert_kernel<<<2048, 256, 0, stream>>>(roi, A_b, (size_t)4096 * 12544);
  convert_kernel<<<512, 256, 0, stream>>>(Wo1, Wo1_b, (size_t)1024 * 1024);
  convert_kernel<<<512, 256, 0, stream>>>(Wo2, Wo2_b, (size_t)1024 * 1024);
  tconv_kernel<<<dim3(32, 392), 256, 0, stream>>>(Wfc1, Wfc1_t, 12544, 1024);
  tconv_kernel<<<dim3(32, 32), 256, 0, stream>>>(Wfc2, Wfc2_t, 1024, 1024);
  tconv_kernel<<<dim3(32, 32), 256, 0, stream>>>(Wq1, Wq1_t, 1024, 1024);
  tconv_kernel<<<dim3(32, 32), 256, 0, stream>>>(Wk1, Wk1_t, 1024, 1024);
  tconv_kernel<<<dim3(32, 32), 256, 0, stream>>>(Wq2, Wq2_t, 1024, 1024);
  tconv_kernel<<<dim3(32, 32), 256, 0, stream>>>(Wk2, Wk2_t, 1024, 1024);
  tconv_kernel<<<dim3(1, 2), 256, 0, stream>>>(Wpos1, Wpos_t, 64, 16);
  tconv_kernel<<<dim3(1, 2), 256, 0, stream>>>(Wpos2, Wpos_t + 1024, 64, 16);
  // position/logw tables (both layers)
  pos_logw_kernel<<<4096, 256, 0, stream>>>(bbox, Wpos_t, bpos1, bpos2, logw1, logw2);

  // ---- layer 1 ----
  gemm_bt<0, false, false><<<dim3(32, 8), 256, 0, stream>>>(A_b, Wfc1_t, bfc1, xf, xb_f, 4096, 1024, 12544, 1024);
  gemm_bt<1, false, false><<<dim3(32, 8), 256, 0, stream>>>(xb_f, Wq1_t, bq1, nullptr, q_b, 4096, 1024, 1024, 1024);
  gemm_bt<1, true,  false><<<dim3(3, 8), 256, 0, stream>>>(xb_f, Wk1_t, bk1, nullptr, k_b, 300, 1024, 1024, 1024);
  gemm_bt<2, false, true ><<<dim3(8, 3), 256, 0, stream>>>(Wo1_b, xb_f, nullptr, nullptr, kvt_b, 1024, 300, 1024, 320);
  attn_kernel<false><<<dim3(64, 16), 256, 0, stream>>>(q_b, k_b, kvt_b, logw1, xf, bo1, nullptr, xb_a);

  // ---- layer 2 ----
  gemm_bt<0, false, false><<<dim3(32, 8), 256, 0, stream>>>(xb_a, Wfc2_t, bfc2, xf, xb_f, 4096, 1024, 1024, 1024);
  gemm_bt<1, false, false><<<dim3(32, 8), 256, 0, stream>>>(xb_f, Wq2_t, bq2, nullptr, q_b, 4096, 1024, 1024, 1024);
  gemm_bt<1, true,  false><<<dim3(3, 8), 256, 0, stream>>>(xb_f, Wk2_t, bk2, nullptr, k_b, 300, 1024, 1024, 1024);
  gemm_bt<2, false, true ><<<dim3(8, 3), 256, 0, stream>>>(Wo2_b, xb_f, nullptr, nullptr, kvt_b, 1024, 300, 1024, 320);
  attn_kernel<true><<<dim3(64, 16), 256, 0, stream>>>(q_b, k_b, kvt_b, logw2, xf, bo2, (float*)d_out, nullptr);
}

// Round 2
// 551.318 us; speedup vs baseline: 1.5036x; 1.5036x over previous
//
#include <hip/hip_runtime.h>

// ============================================================================
// FastRCNN Relation FC Head, MI355X round 2.
// vs round 1: fc1 split-K=4 (occupancy 12.5%->50%), merged 128x64-tile GEMM
// for q/k/kvt (one 600-block launch) and fc2 (512 blocks), pos_logw coalesced
// bf16x8 stores via LDS, attn stages logw tile in LDS (contiguous global).
// Workspace: 270 MB (split-K partials reuse the logw region; pos_logw runs
// after the fc1 reduce).
// ============================================================================

using bf16x8 = __attribute__((ext_vector_type(8))) short;
using u16x4  = __attribute__((ext_vector_type(4))) short;
using f32x4  = __attribute__((ext_vector_type(4))) float;
typedef unsigned short u16;
typedef unsigned int   u32;

#define DEV __device__ __forceinline__

DEV u16 f2bf(float f) {                      // fp32 -> bf16, round-nearest-even
  u32 u = __float_as_uint(f);
  return (u16)((u + 0x7FFFu + ((u >> 16) & 1u)) >> 16);
}
DEV float bf2f(u16 h) { return __uint_as_float(((u32)h) << 16); }

DEV f32x4 mfma16(bf16x8 a, bf16x8 b, f32x4 c) {
  return __builtin_amdgcn_mfma_f32_16x16x32_bf16(a, b, c, 0, 0, 0);
}
DEV void gload16(const u16* g, u16* l) {
  __builtin_amdgcn_global_load_lds((const __attribute__((address_space(1))) void*)g,
                                   (__attribute__((address_space(3))) void*)l, 16, 0, 0);
}

DEV void fsincos(float x, float* s, float* c) {
  float r = x * 0.15915494309189535f;   // revolutions, exact-identity reduction
  r -= rintf(r);
  float a = r * 6.283185307179586f;
  *s = __sinf(a); *c = __cosf(a);
}

// ---------------------------------------------------------------------------
// fp32 -> bf16 convert (n % 8 == 0)
// ---------------------------------------------------------------------------
__global__ __launch_bounds__(256) void convert_kernel(const float* __restrict__ src,
                                                      u16* __restrict__ dst, size_t n) {
  size_t i = ((size_t)blockIdx.x * 256 + threadIdx.x) * 8;
  size_t stride = (size_t)gridDim.x * 256 * 8;
  for (; i < n; i += stride) {
    float4 a = *(const float4*)(src + i);
    float4 b = *(const float4*)(src + i + 4);
    bf16x8 v;
    v[0]=(short)f2bf(a.x); v[1]=(short)f2bf(a.y); v[2]=(short)f2bf(a.z); v[3]=(short)f2bf(a.w);
    v[4]=(short)f2bf(b.x); v[5]=(short)f2bf(b.y); v[6]=(short)f2bf(b.z); v[7]=(short)f2bf(b.w);
    *(bf16x8*)(dst + i) = v;
  }
}

// ---------------------------------------------------------------------------
// transpose + convert: in fp32 [R][C] -> out bf16 [C][R]
// ---------------------------------------------------------------------------
__global__ __launch_bounds__(256) void tconv_kernel(const float* __restrict__ in,
                                                    u16* __restrict__ out, int R, int C) {
  __shared__ float t[32][33];
  int tx = threadIdx.x & 31, ty = threadIdx.x >> 5;
  int r0 = blockIdx.y * 32, c0 = blockIdx.x * 32;
#pragma unroll
  for (int i = 0; i < 4; i++) {
    int r = r0 + ty + i * 8;
    if (r < R && (c0 + tx) < C) t[ty + i * 8][tx] = in[(size_t)r * C + c0 + tx];
  }
  __syncthreads();
#pragma unroll
  for (int i = 0; i < 4; i++) {
    int c = c0 + ty + i * 8;
    if (c < C && (r0 + tx) < R) out[(size_t)c * R + r0 + tx] = f2bf(t[tx][ty + i * 8]);
  }
}

// ---------------------------------------------------------------------------
// fused position-matrix -> sincos -> @Wpos (both layers) -> relu -> log.
// One block per n.  Results accumulate in LDS, then coalesced bf16x8 stores.
// logw layout: [g][n][320] bf16 per layer (m >= 300 garbage, masked in attn).
// ---------------------------------------------------------------------------
__constant__ float C100D[8] = {100.f, 42.16965034285822f, 17.78279410038923f,
                               7.498942093324559f, 3.1622776601683795f,
                               1.333521432163324f, 0.5623413251903491f,
                               0.23713737056616552f};

__global__ __launch_bounds__(256) void pos_logw_kernel(
    const float* __restrict__ bbox, const u16* __restrict__ wpos_t,
    const float* __restrict__ bpos1, const float* __restrict__ bpos2,
    u16* __restrict__ logw1, u16* __restrict__ logw2) {
  __shared__ u16 emb_s[64 * 88];          // [m_local][e]
  __shared__ u16 wp_s[32 * 88];           // [col(layer,g)][e]
  __shared__ u16 lw_s[2 * 16 * 328];      // [layer][g][m] pad 328
  int tid = threadIdx.x;
  int n = blockIdx.x;
  int w = tid >> 6, l = tid & 63, h = l >> 4, l15 = l & 15;
  { // stage Wpos_t [32][64]
    int row = tid >> 3, seg = tid & 7;
    bf16x8 v = *(const bf16x8*)(wpos_t + row * 64 + seg * 8);
    *(bf16x8*)(&wp_s[row * 88 + seg * 8]) = v;
  }
  float4 bn = ((const float4*)bbox)[n];
  float bw_n = bn.z - bn.x + 1.f, bh_n = bn.w - bn.y + 1.f;
  float cx_n = 0.5f * (bn.x + bn.z), cy_n = 0.5f * (bn.y + bn.w);
  float bps0 = bpos1[l15], bps1 = bpos2[l15];
  int p = tid >> 2, k = tid & 3;

  for (int m0 = 0; m0 < 320; m0 += 64) {
    int m = m0 + p;
    float4 bm = ((const float4*)bbox)[m];
    float v;
    if (k == 0)      v = logf(fmaxf(fabsf((cx_n - 0.5f * (bm.x + bm.z)) / bw_n), 1e-3f));
    else if (k == 1) v = logf(fmaxf(fabsf((cy_n - 0.5f * (bm.y + bm.w)) / bh_n), 1e-3f));
    else if (k == 2) v = logf(bw_n / (bm.z - bm.x + 1.f));
    else             v = logf(bh_n / (bm.w - bm.y + 1.f));
    __syncthreads();                      // protect previous tile's frag reads
#pragma unroll
    for (int tt = 0; tt < 8; tt++) {
      float s, c; fsincos(v * C100D[tt], &s, &c);
      emb_s[p * 88 + k * 16 + tt]     = f2bf(s);
      emb_s[p * 88 + k * 16 + 8 + tt] = f2bf(c);
    }
    __syncthreads();
    f32x4 acc0 = {0.f, 0.f, 0.f, 0.f}, acc1 = {0.f, 0.f, 0.f, 0.f};
    bf16x8 a0 = *(const bf16x8*)&emb_s[(w * 16 + l15) * 88 + h * 8];
    bf16x8 a1 = *(const bf16x8*)&emb_s[(w * 16 + l15) * 88 + 32 + h * 8];
    bf16x8 b00 = *(const bf16x8*)&wp_s[l15 * 88 + h * 8];
    bf16x8 b01 = *(const bf16x8*)&wp_s[l15 * 88 + 32 + h * 8];
    bf16x8 b10 = *(const bf16x8*)&wp_s[(16 + l15) * 88 + h * 8];
    bf16x8 b11 = *(const bf16x8*)&wp_s[(16 + l15) * 88 + 32 + h * 8];
    acc0 = mfma16(a0, b00, acc0); acc0 = mfma16(a1, b01, acc0);
    acc1 = mfma16(a0, b10, acc1); acc1 = mfma16(a1, b11, acc1);
#pragma unroll
    for (int r = 0; r < 4; r++) {
      int mm = m0 + w * 16 + h * 4 + r;
      lw_s[l15 * 328 + mm]        = f2bf(logf(fmaxf(acc0[r] + bps0, 1e-6f)));
      lw_s[(16 + l15) * 328 + mm] = f2bf(logf(fmaxf(acc1[r] + bps1, 1e-6f)));
    }
  }
  __syncthreads();
  for (int i = tid; i < 1280; i += 256) {       // 2 layers * 16 g * 40 segs
    int layer = i / 640, rest = i - layer * 640;
    int gg = rest / 40, seg = rest - gg * 40;
    bf16x8 v = *(const bf16x8*)&lw_s[(layer * 16 + gg) * 328 + seg * 8];
    u16* dst = (layer ? logw2 : logw1) + ((size_t)gg * 4096 + n) * 320 + seg * 8;
    *(bf16x8*)dst = v;
  }
}

// ---------------------------------------------------------------------------
// fc1 split-K GEMM: 128x128 tile, BK=32, blockIdx.z = K-split.
// Writes fp32 partial P[z][4096][1024].
// ---------------------------------------------------------------------------
__global__ __launch_bounds__(256) void gemm_sk(
    const u16* __restrict__ A, const u16* __restrict__ Bt,
    float* __restrict__ P, int K, int kspan) {
  const int N = 1024;
  __shared__ u16 As[128 * 32];
  __shared__ u16 Bs[128 * 32];
  int tid = threadIdx.x;
  int w = tid >> 6, l = tid & 63, h = l >> 4, l15 = l & 15;
  int bm = blockIdx.x * 128, bnn = blockIdx.y * 128;
  int wr = (w >> 1) * 64, wc = (w & 1) * 64;
  f32x4 acc[4][4];
#pragma unroll
  for (int i = 0; i < 4; i++)
#pragma unroll
    for (int j = 0; j < 4; j++) acc[i][j] = (f32x4){0.f, 0.f, 0.f, 0.f};

  int o0 = w * 1024 + l * 16;
  int arow0 = o0 >> 6, ace = (o0 & 63) >> 1;
  int ra0 = bm + arow0, ra1 = ra0 + 64;
  int jb0 = bnn + arow0, jb1 = jb0 + 64;
  int kt0 = blockIdx.z * kspan, kt1 = kt0 + kspan;

  for (int kt = kt0; kt < kt1; kt += 32) {
    __syncthreads();
    gload16(A  + (size_t)ra0 * K + kt + ace, &As[arow0 * 32 + ace]);
    gload16(A  + (size_t)ra1 * K + kt + ace, &As[(arow0 + 64) * 32 + ace]);
    gload16(Bt + (size_t)jb0 * K + kt + ace, &Bs[arow0 * 32 + ace]);
    gload16(Bt + (size_t)jb1 * K + kt + ace, &Bs[(arow0 + 64) * 32 + ace]);
    __syncthreads();
    bf16x8 af[4], bfr[4];
#pragma unroll
    for (int i = 0; i < 4; i++) {
      af[i]  = *(const bf16x8*)&As[(wr + i * 16 + l15) * 32 + h * 8];
      bfr[i] = *(const bf16x8*)&Bs[(wc + i * 16 + l15) * 32 + h * 8];
    }
#pragma unroll
    for (int i = 0; i < 4; i++)
#pragma unroll
      for (int j = 0; j < 4; j++) acc[i][j] = mfma16(af[i], bfr[j], acc[i][j]);
  }
  float* dst = P + (size_t)blockIdx.z * 4096 * 1024;
#pragma unroll
  for (int i = 0; i < 4; i++)
#pragma unroll
    for (int j = 0; j < 4; j++) {
      int row0 = bm + wr + i * 16 + h * 4;
      int col  = bnn + wc + j * 16 + l15;
#pragma unroll
      for (int r = 0; r < 4; r++)
        dst[(size_t)(row0 + r) * N + col] = acc[i][j][r];
    }
}

// ---------------------------------------------------------------------------
// fc1 reduce: xf = p0+p1+p2+p3+bias; xb = bf16(xf)
// ---------------------------------------------------------------------------
__global__ __launch_bounds__(256) void fc_reduce(
    const float* __restrict__ P, const float* __restrict__ bias,
    float* __restrict__ xf, u16* __restrict__ xb) {
  const size_t MN = (size_t)4096 * 1024;
  size_t i = ((size_t)blockIdx.x * 256 + threadIdx.x) * 4;
  size_t stride = (size_t)gridDim.x * 256 * 4;
  for (; i < MN; i += stride) {
    float4 a = *(const float4*)(P + i);
    float4 b = *(const float4*)(P + MN + i);
    float4 c = *(const float4*)(P + 2 * MN + i);
    float4 d = *(const float4*)(P + 3 * MN + i);
    float4 bv = *(const float4*)(bias + (i & 1023));
    float4 r;
    r.x = a.x + b.x + c.x + d.x + bv.x;
    r.y = a.y + b.y + c.y + d.y + bv.y;
    r.z = a.z + b.z + c.z + d.z + bv.z;
    r.w = a.w + b.w + c.w + d.w + bv.w;
    *(float4*)(xf + i) = r;
    u16x4 hv;
    hv[0] = (short)f2bf(r.x); hv[1] = (short)f2bf(r.y);
    hv[2] = (short)f2bf(r.z); hv[3] = (short)f2bf(r.w);
    *(u16x4*)(xb + i) = hv;
  }
}

// ---------------------------------------------------------------------------
// merged 128x64-tile GEMM, up to 3 independent problems in one grid.
// C = A[MxK] * Bt[NxK]^T (+bias).  Row/col loads clamped (finite garbage in
// pad region is multiplied by zero downstream or never written).
// ---------------------------------------------------------------------------
struct GDesc {
  const u16* A; const u16* Bt; const float* bias;
  u16* Cb; float* Cf;
  int M, N, K, ldc, nt;          // nt = #64-wide col tiles
};

__global__ __launch_bounds__(256) void gemm3(GDesc g0, GDesc g1, GDesc g2,
                                             int c0, int c1) {
  __shared__ u16 As[128 * 32];
  __shared__ u16 Bs[64 * 32];
  GDesc g; int lb = blockIdx.x;
  if (lb < c0) g = g0;
  else if (lb < c1) { g = g1; lb -= c0; }
  else { g = g2; lb -= c1; }
  int bm = (lb / g.nt) * 128, bnn = (lb % g.nt) * 64;
  int tid = threadIdx.x;
  int w = tid >> 6, l = tid & 63, h = l >> 4, l15 = l & 15;
  int wr = (w >> 1) * 64, wc = (w & 1) * 32;
  f32x4 acc[4][2];
#pragma unroll
  for (int i = 0; i < 4; i++)
#pragma unroll
    for (int j = 0; j < 2; j++) acc[i][j] = (f32x4){0.f, 0.f, 0.f, 0.f};

  int o0 = w * 1024 + l * 16;
  int arow0 = o0 >> 6, ace = (o0 & 63) >> 1;
  int ra0 = min(bm + arow0, g.M - 1), ra1 = min(bm + arow0 + 64, g.M - 1);
  int jb  = min(bnn + arow0, g.N - 1);

  for (int kt = 0; kt < g.K; kt += 32) {
    __syncthreads();
    gload16(g.A  + (size_t)ra0 * g.K + kt + ace, &As[arow0 * 32 + ace]);
    gload16(g.A  + (size_t)ra1 * g.K + kt + ace, &As[(arow0 + 64) * 32 + ace]);
    gload16(g.Bt + (size_t)jb  * g.K + kt + ace, &Bs[arow0 * 32 + ace]);
    __syncthreads();
    bf16x8 af[4], bfr[2];
#pragma unroll
    for (int i = 0; i < 4; i++)
      af[i]  = *(const bf16x8*)&As[(wr + i * 16 + l15) * 32 + h * 8];
#pragma unroll
    for (int j = 0; j < 2; j++)
      bfr[j] = *(const bf16x8*)&Bs[(wc + j * 16 + l15) * 32 + h * 8];
#pragma unroll
    for (int i = 0; i < 4; i++)
#pragma unroll
      for (int j = 0; j < 2; j++) acc[i][j] = mfma16(af[i], bfr[j], acc[i][j]);
  }
#pragma unroll
  for (int i = 0; i < 4; i++) {
#pragma unroll
    for (int j = 0; j < 2; j++) {
      int col = bnn + wc + j * 16 + l15;
      if (col >= g.ldc) continue;
      float bv = (g.bias != nullptr && col < g.N) ? g.bias[col] : 0.f;
      int row0 = bm + wr + i * 16 + h * 4;
#pragma unroll
      for (int r = 0; r < 4; r++) {
        int row = row0 + r;
        if (row >= g.M) continue;
        float v = acc[i][j][r] + bv;
        size_t off = (size_t)row * g.ldc + col;
        g.Cb[off] = f2bf(v);
        if (g.Cf != nullptr) g.Cf[off] = v;
      }
    }
  }
}

// ---------------------------------------------------------------------------
// fused attention per (64-row n-tile, head g):
//  QK^T (K in LDS) -> stage logw tile in LDS (contiguous global chunk) ->
//  logits+softmax in registers -> P in LDS -> PV vs KVt -> residual+relu.
// ---------------------------------------------------------------------------
template <bool LAST>
__global__ __launch_bounds__(256) void attn_kernel(
    const u16* __restrict__ qb, const u16* __restrict__ kb,
    const u16* __restrict__ kvt, const u16* __restrict__ logw,
    const float* __restrict__ xf, const float* __restrict__ bo,
    float* __restrict__ outf, u16* __restrict__ outb) {
  __shared__ u16 kp_s[320 * 88];    // K [m][d]; then logw [64][328]; then P [64][344]
  __shared__ u16 kv_s[64 * 344];    // KVt [o][m] pad 344
  int tid = threadIdx.x;
  int g = blockIdx.y, n0 = blockIdx.x * 64;
  int w = tid >> 6, l = tid & 63, h = l >> 4, l15 = l & 15;

  for (int i = tid; i < 320 * 8; i += 256) {        // stage K (zeros m>=300)
    int row = i >> 3, seg = i & 7;
    bf16x8 v = {0, 0, 0, 0, 0, 0, 0, 0};
    if (row < 300) v = *(const bf16x8*)(kb + (size_t)row * 1024 + g * 64 + seg * 8);
    *(bf16x8*)&kp_s[row * 88 + seg * 8] = v;
  }
  for (int i = tid; i < 64 * 40; i += 256) {        // stage KVt
    int row = i / 40, seg = i % 40;
    bf16x8 v = *(const bf16x8*)(kvt + (size_t)(g * 64 + row) * 320 + seg * 8);
    *(bf16x8*)&kv_s[row * 344 + seg * 8] = v;
  }
  int nrow = n0 + w * 16 + l15;
  bf16x8 aq0 = *(const bf16x8*)(qb + (size_t)nrow * 1024 + g * 64 + h * 8);
  bf16x8 aq1 = *(const bf16x8*)(qb + (size_t)nrow * 1024 + g * 64 + 32 + h * 8);
  __syncthreads();

  f32x4 acc[19];
#pragma unroll
  for (int f = 0; f < 19; f++) acc[f] = (f32x4){0.f, 0.f, 0.f, 0.f};
#pragma unroll
  for (int f = 0; f < 19; f++) {
    bf16x8 b0 = *(const bf16x8*)&kp_s[(f * 16 + l15) * 88 + h * 8];
    bf16x8 b1 = *(const bf16x8*)&kp_s[(f * 16 + l15) * 88 + 32 + h * 8];
    acc[f] = mfma16(aq0, b0, acc[f]);
    acc[f] = mfma16(aq1, b1, acc[f]);
  }
  __syncthreads();                     // all waves done reading K
  {                                    // stage logw tile (contiguous 40KB)
    const u16* src = logw + ((size_t)g * 4096 + n0) * 320;
    for (int i = tid; i < 64 * 40; i += 256) {
      int row = i / 40, seg = i % 40;
      *(bf16x8*)&kp_s[row * 328 + seg * 8] = *(const bf16x8*)(src + row * 320 + seg * 8);
    }
  }
  __syncthreads();

  int nbase = n0 + w * 16 + h * 4;
  int lrow = w * 16 + h * 4;
  float mx[4] = {-INFINITY, -INFINITY, -INFINITY, -INFINITY};
  float sm[4] = {0.f, 0.f, 0.f, 0.f};
#pragma unroll
  for (int f = 0; f < 19; f++) {
    int m = f * 16 + l15;
#pragma unroll
    for (int r = 0; r < 4; r++) {
      float lw = -INFINITY;
      if (m < 300) lw = bf2f(kp_s[(lrow + r) * 328 + m]);
      float lg = acc[f][r] * 0.125f + lw;
      acc[f][r] = lg;
      mx[r] = fmaxf(mx[r], lg);
    }
  }
#pragma unroll
  for (int d = 1; d < 16; d <<= 1)
#pragma unroll
    for (int r = 0; r < 4; r++) mx[r] = fmaxf(mx[r], __shfl_xor(mx[r], d));
#pragma unroll
  for (int f = 0; f < 19; f++)
#pragma unroll
    for (int r = 0; r < 4; r++) {
      float p = __expf(acc[f][r] - mx[r]);
      acc[f][r] = p; sm[r] += p;
    }
#pragma unroll
  for (int d = 1; d < 16; d <<= 1)
#pragma unroll
    for (int r = 0; r < 4; r++) sm[r] += __shfl_xor(sm[r], d);
  float inv[4];
#pragma unroll
  for (int r = 0; r < 4; r++) inv[r] = 1.f / sm[r];

  __syncthreads();                     // all waves done reading logw
#pragma unroll
  for (int f = 0; f < 19; f++)
#pragma unroll
    for (int r = 0; r < 4; r++)
      kp_s[(lrow + r) * 344 + f * 16 + l15] = f2bf(acc[f][r]);
#pragma unroll
  for (int r = 0; r < 4; r++)          // zero pad m 304..319
    kp_s[(lrow + r) * 344 + 304 + l15] = 0;

  f32x4 acc2[4];
#pragma unroll
  for (int fo = 0; fo < 4; fo++) acc2[fo] = (f32x4){0.f, 0.f, 0.f, 0.f};
#pragma unroll
  for (int ks = 0; ks < 10; ks++) {
    bf16x8 ap = *(const bf16x8*)&kp_s[(w * 16 + l15) * 344 + ks * 32 + h * 8];
#pragma unroll
    for (int fo = 0; fo < 4; fo++) {
      bf16x8 bv = *(const bf16x8*)&kv_s[(fo * 16 + l15) * 344 + ks * 32 + h * 8];
      acc2[fo] = mfma16(ap, bv, acc2[fo]);
    }
  }
#pragma unroll
  for (int fo = 0; fo < 4; fo++) {
    int col = g * 64 + fo * 16 + l15;
    float bov = bo[col];
#pragma unroll
    for (int r = 0; r < 4; r++) {
      int row = nbase + r;
      float v = xf[(size_t)row * 1024 + col] + acc2[fo][r] * inv[r] + bov;
      v = fmaxf(v, 0.f);
      if (LAST) outf[(size_t)row * 1024 + col] = v;
      else      outb[(size_t)row * 1024 + col] = f2bf(v);
    }
  }
}

// ---------------------------------------------------------------------------
extern "C" void kernel_launch(void* const* d_in, const int* in_sizes, int n_in,
                              void* d_out, int out_size, void* d_ws, size_t ws_size,
                              hipStream_t stream) {
  (void)in_sizes; (void)n_in; (void)out_size; (void)ws_size;
  const float* roi   = (const float*)d_in[0];
  const float* bbox  = (const float*)d_in[1];
  const float* Wfc1  = (const float*)d_in[2];
  const float* bfc1  = (const float*)d_in[3];
  const float* Wfc2  = (const float*)d_in[4];
  const float* bfc2  = (const float*)d_in[5];
  const float* Wpos1 = (const float*)d_in[6];
  const float* bpos1 = (const float*)d_in[7];
  const float* Wq1   = (const float*)d_in[8];
  const float* bq1   = (const float*)d_in[9];
  const float* Wk1   = (const float*)d_in[10];
  const float* bk1   = (const float*)d_in[11];
  const float* Wo1   = (const float*)d_in[12];
  const float* bo1   = (const float*)d_in[13];
  const float* Wpos2 = (const float*)d_in[14];
  const float* bpos2 = (const float*)d_in[15];
  const float* Wq2   = (const float*)d_in[16];
  const float* bq2   = (const float*)d_in[17];
  const float* Wk2   = (const float*)d_in[18];
  const float* bk2   = (const float*)d_in[19];
  const float* Wo2   = (const float*)d_in[20];
  const float* bo2   = (const float*)d_in[21];

  char* ws = (char*)d_ws;                       // ---- workspace arena ----
  u16*  A_b    = (u16*)(ws);                    // 102,760,448
  u16*  Wfc1_t = (u16*)(ws + 102760448);        //  25,690,112
  u16*  Wfc2_t = (u16*)(ws + 128450560);        //   2,097,152 each
  u16*  Wq1_t  = (u16*)(ws + 130547712);
  u16*  Wk1_t  = (u16*)(ws + 132644864);
  u16*  Wq2_t  = (u16*)(ws + 134742016);
  u16*  Wk2_t  = (u16*)(ws + 136839168);
  u16*  Wo1_b  = (u16*)(ws + 138936320);
  u16*  Wo2_b  = (u16*)(ws + 141033472);
  u16*  Wpos_t = (u16*)(ws + 143130624);        //       4,096
  // [143,134,720 .. 227,020,800): logw1+logw2 (41.9 MB each) — ALSO reused
  // as fc1 split-K partials (4 x 16.78 MB fp32) before pos_logw runs.
  u16*   logw1 = (u16*)(ws + 143134720);
  u16*   logw2 = (u16*)(ws + 185077760);
  float* Pp    = (float*)(ws + 143134720);      //  67,108,864 (transient)
  float* xf    = (float*)(ws + 227020800);      //  16,777,216
  u16*  xb_f   = (u16*)(ws + 243798016);        //   8,388,608 (fc out, bf16)
  u16*  xb_a   = (u16*)(ws + 252186624);        //   8,388,608 (attn out, bf16)
  u16*  q_b    = (u16*)(ws + 260575232);        //   8,388,608
  u16*  k_b    = (u16*)(ws + 268963840);        //     614,400
  u16*  kvt_b  = (u16*)(ws + 269578240);        //     655,360 (end 270,233,600)

  // converts
  convert_kernel<<<2048, 256, 0, stream>>>(roi, A_b, (size_t)4096 * 12544);
  convert_kernel<<<512, 256, 0, stream>>>(Wo1, Wo1_b, (size_t)1024 * 1024);
  convert_kernel<<<512, 256, 0, stream>>>(Wo2, Wo2_b, (size_t)1024 * 1024);
  tconv_kernel<<<dim3(32, 392), 256, 0, stream>>>(Wfc1, Wfc1_t, 12544, 1024);
  tconv_kernel<<<dim3(32, 32), 256, 0, stream>>>(Wfc2, Wfc2_t, 1024, 1024);
  tconv_kernel<<<dim3(32, 32), 256, 0, stream>>>(Wq1, Wq1_t, 1024, 1024);
  tconv_kernel<<<dim3(32, 32), 256, 0, stream>>>(Wk1, Wk1_t, 1024, 1024);
  tconv_kernel<<<dim3(32, 32), 256, 0, stream>>>(Wq2, Wq2_t, 1024, 1024);
  tconv_kernel<<<dim3(32, 32), 256, 0, stream>>>(Wk2, Wk2_t, 1024, 1024);
  tconv_kernel<<<dim3(1, 2), 256, 0, stream>>>(Wpos1, Wpos_t, 64, 16);
  tconv_kernel<<<dim3(1, 2), 256, 0, stream>>>(Wpos2, Wpos_t + 1024, 64, 16);

  // fc1 split-K (partials in the logw region), then reduce, then pos tables
  gemm_sk<<<dim3(32, 8, 4), 256, 0, stream>>>(A_b, Wfc1_t, Pp, 12544, 3136);
  fc_reduce<<<2048, 256, 0, stream>>>(Pp, bfc1, xf, xb_f);
  pos_logw_kernel<<<4096, 256, 0, stream>>>(bbox, Wpos_t, bpos1, bpos2, logw1, logw2);

  // ---- layer 1: q, k, kvt in one launch, then attention ----
  {
    GDesc q  = {xb_f,  Wq1_t, bq1, q_b,   nullptr, 4096, 1024, 1024, 1024, 16};
    GDesc kk = {xb_f,  Wk1_t, bk1, k_b,   nullptr,  300, 1024, 1024, 1024, 16};
    GDesc kv = {Wo1_b, xb_f,  nullptr, kvt_b, nullptr, 1024, 300, 1024, 320, 5};
    gemm3<<<600, 256, 0, stream>>>(q, kk, kv, 512, 560);
  }
  attn_kernel<false><<<dim3(64, 16), 256, 0, stream>>>(q_b, k_b, kvt_b, logw1, xf, bo1, nullptr, xb_a);

  // ---- layer 2 ----
  {
    GDesc fc = {xb_a, Wfc2_t, bfc2, xb_f, xf, 4096, 1024, 1024, 1024, 16};
    gemm3<<<512, 256, 0, stream>>>(fc, fc, fc, 512, 512);
  }
  {
    GDesc q  = {xb_f,  Wq2_t, bq2, q_b,   nullptr, 4096, 1024, 1024, 1024, 16};
    GDesc kk = {xb_f,  Wk2_t, bk2, k_b,   nullptr,  300, 1024, 1024, 1024, 16};
    GDesc kv = {Wo2_b, xb_f,  nullptr, kvt_b, nullptr, 1024, 300, 1024, 320, 5};
    gemm3<<<600, 256, 0, stream>>>(q, kk, kv, 512, 560);
  }
  attn_kernel<true><<<dim3(64, 16), 256, 0, stream>>>(q_b, k_b, kvt_b, logw2, xf, bo2, (float*)d_out, nullptr);
}

// Round 3
// 473.395 us; speedup vs baseline: 1.7511x; 1.1646x over previous
//
#include <hip/hip_runtime.h>

// ============================================================================
// FastRCNN Relation FC Head, MI355X round 3.
// vs round 2: fc1 now a 256x256 8-phase counted-vmcnt MFMA GEMM (T2 LDS
// XOR-swizzle both-sides + T3/T4 phase pipeline + T5 setprio), splitK=4
// -> 256 blocks x 512 threads.  Launch count 20 -> 11 (batched converts,
// Wpos folded into pos_logw).  Workspace: 270 MB.
// ============================================================================

using bf16x8 = __attribute__((ext_vector_type(8))) short;
using u16x4  = __attribute__((ext_vector_type(4))) short;
using f32x4  = __attribute__((ext_vector_type(4))) float;
typedef unsigned short u16;
typedef unsigned int   u32;

#define DEV __device__ __forceinline__

DEV u16 f2bf(float f) {                      // fp32 -> bf16, round-nearest-even
  u32 u = __float_as_uint(f);
  return (u16)((u + 0x7FFFu + ((u >> 16) & 1u)) >> 16);
}
DEV float bf2f(u16 h) { return __uint_as_float(((u32)h) << 16); }

DEV f32x4 mfma16(bf16x8 a, bf16x8 b, f32x4 c) {
  return __builtin_amdgcn_mfma_f32_16x16x32_bf16(a, b, c, 0, 0, 0);
}
DEV void gload16(const u16* g, u16* l) {
  __builtin_amdgcn_global_load_lds((const __attribute__((address_space(1))) void*)g,
                                   (__attribute__((address_space(3))) void*)l, 16, 0, 0);
}

DEV void fsincos(float x, float* s, float* c) {
  float r = x * 0.15915494309189535f;   // revolutions, exact-identity reduction
  r -= rintf(r);
  float a = r * 6.283185307179586f;
  *s = __sinf(a); *c = __cosf(a);
}

// ---------------------------------------------------------------------------
// batched fp32 -> bf16 convert (3 tensors, grid-stride, n % 8 == 0)
// ---------------------------------------------------------------------------
struct CV3 { const float* s[3]; u16* d[3]; size_t n[3]; };

__global__ __launch_bounds__(256) void convert3_kernel(CV3 p) {
  const float* src = p.s[blockIdx.z];
  u16* dst = p.d[blockIdx.z];
  size_t n = p.n[blockIdx.z];
  size_t i = ((size_t)blockIdx.x * 256 + threadIdx.x) * 8;
  size_t stride = (size_t)gridDim.x * 256 * 8;
  for (; i < n; i += stride) {
    float4 a = *(const float4*)(src + i);
    float4 b = *(const float4*)(src + i + 4);
    bf16x8 v;
    v[0]=(short)f2bf(a.x); v[1]=(short)f2bf(a.y); v[2]=(short)f2bf(a.z); v[3]=(short)f2bf(a.w);
    v[4]=(short)f2bf(b.x); v[5]=(short)f2bf(b.y); v[6]=(short)f2bf(b.z); v[7]=(short)f2bf(b.w);
    *(bf16x8*)(dst + i) = v;
  }
}

// ---------------------------------------------------------------------------
// transpose + convert fp32 [R][C] -> bf16 [C][R]  (for Wfc1, 12544x1024)
// ---------------------------------------------------------------------------
__global__ __launch_bounds__(256) void tconv_kernel(const float* __restrict__ in,
                                                    u16* __restrict__ out, int R, int C) {
  __shared__ float t[32][33];
  int tx = threadIdx.x & 31, ty = threadIdx.x >> 5;
  int r0 = blockIdx.y * 32, c0 = blockIdx.x * 32;
#pragma unroll
  for (int i = 0; i < 4; i++) {
    int r = r0 + ty + i * 8;
    if (r < R && (c0 + tx) < C) t[ty + i * 8][tx] = in[(size_t)r * C + c0 + tx];
  }
  __syncthreads();
#pragma unroll
  for (int i = 0; i < 4; i++) {
    int c = c0 + ty + i * 8;
    if (c < C && (r0 + tx) < R) out[(size_t)c * R + r0 + tx] = f2bf(t[tx][ty + i * 8]);
  }
}

// ---------------------------------------------------------------------------
// batched 1024x1024 transpose+convert (6 weight matrices in one launch)
// ---------------------------------------------------------------------------
struct TC6 { const float* s[6]; u16* d[6]; };

__global__ __launch_bounds__(256) void tconv6_kernel(TC6 p) {
  const float* in = p.s[blockIdx.z];
  u16* out = p.d[blockIdx.z];
  __shared__ float t[32][33];
  int tx = threadIdx.x & 31, ty = threadIdx.x >> 5;
  int r0 = blockIdx.y * 32, c0 = blockIdx.x * 32;
#pragma unroll
  for (int i = 0; i < 4; i++)
    t[ty + i * 8][tx] = in[(size_t)(r0 + ty + i * 8) * 1024 + c0 + tx];
  __syncthreads();
#pragma unroll
  for (int i = 0; i < 4; i++)
    out[(size_t)(c0 + ty + i * 8) * 1024 + r0 + tx] = f2bf(t[tx][ty + i * 8]);
}

// ---------------------------------------------------------------------------
// fused position-matrix -> sincos -> @Wpos (both layers) -> relu -> log.
// One block per n.  Wpos read raw fp32 (64x16), converted in-kernel.
// logw layout: [g][n][320] bf16 per layer (m >= 300 garbage, masked in attn).
// ---------------------------------------------------------------------------
__constant__ float C100D[8] = {100.f, 42.16965034285822f, 17.78279410038923f,
                               7.498942093324559f, 3.1622776601683795f,
                               1.333521432163324f, 0.5623413251903491f,
                               0.23713737056616552f};

__global__ __launch_bounds__(256) void pos_logw_kernel(
    const float* __restrict__ bbox,
    const float* __restrict__ Wpos1, const float* __restrict__ Wpos2,
    const float* __restrict__ bpos1, const float* __restrict__ bpos2,
    u16* __restrict__ logw1, u16* __restrict__ logw2) {
  __shared__ u16 emb_s[64 * 88];          // [m_local][e]
  __shared__ u16 wp_s[32 * 88];           // [col(layer,g)][e]
  __shared__ u16 lw_s[2 * 16 * 328];      // [layer][g][m] pad 328
  int tid = threadIdx.x;
  int n = blockIdx.x;
  int w = tid >> 6, l = tid & 63, h = l >> 4, l15 = l & 15;
  for (int idx = tid; idx < 1024; idx += 256) {   // stage Wpos^T both layers
    int e = idx >> 4, c = idx & 15;               // Wpos[e][c], EMB=64 GROUP=16
    wp_s[c * 88 + e]        = f2bf(Wpos1[idx]);
    wp_s[(16 + c) * 88 + e] = f2bf(Wpos2[idx]);
  }
  float4 bn = ((const float4*)bbox)[n];
  float bw_n = bn.z - bn.x + 1.f, bh_n = bn.w - bn.y + 1.f;
  float cx_n = 0.5f * (bn.x + bn.z), cy_n = 0.5f * (bn.y + bn.w);
  float bps0 = bpos1[l15], bps1 = bpos2[l15];
  int p = tid >> 2, k = tid & 3;

  for (int m0 = 0; m0 < 320; m0 += 64) {
    int m = m0 + p;
    float4 bm = ((const float4*)bbox)[m];
    float v;
    if (k == 0)      v = logf(fmaxf(fabsf((cx_n - 0.5f * (bm.x + bm.z)) / bw_n), 1e-3f));
    else if (k == 1) v = logf(fmaxf(fabsf((cy_n - 0.5f * (bm.y + bm.w)) / bh_n), 1e-3f));
    else if (k == 2) v = logf(bw_n / (bm.z - bm.x + 1.f));
    else             v = logf(bh_n / (bm.w - bm.y + 1.f));
    __syncthreads();                      // protect previous tile's frag reads
#pragma unroll
    for (int tt = 0; tt < 8; tt++) {
      float s, c; fsincos(v * C100D[tt], &s, &c);
      emb_s[p * 88 + k * 16 + tt]     = f2bf(s);
      emb_s[p * 88 + k * 16 + 8 + tt] = f2bf(c);
    }
    __syncthreads();
    f32x4 acc0 = {0.f, 0.f, 0.f, 0.f}, acc1 = {0.f, 0.f, 0.f, 0.f};
    bf16x8 a0 = *(const bf16x8*)&emb_s[(w * 16 + l15) * 88 + h * 8];
    bf16x8 a1 = *(const bf16x8*)&emb_s[(w * 16 + l15) * 88 + 32 + h * 8];
    bf16x8 b00 = *(const bf16x8*)&wp_s[l15 * 88 + h * 8];
    bf16x8 b01 = *(const bf16x8*)&wp_s[l15 * 88 + 32 + h * 8];
    bf16x8 b10 = *(const bf16x8*)&wp_s[(16 + l15) * 88 + h * 8];
    bf16x8 b11 = *(const bf16x8*)&wp_s[(16 + l15) * 88 + 32 + h * 8];
    acc0 = mfma16(a0, b00, acc0); acc0 = mfma16(a1, b01, acc0);
    acc1 = mfma16(a0, b10, acc1); acc1 = mfma16(a1, b11, acc1);
#pragma unroll
    for (int r = 0; r < 4; r++) {
      int mm = m0 + w * 16 + h * 4 + r;
      lw_s[l15 * 328 + mm]        = f2bf(logf(fmaxf(acc0[r] + bps0, 1e-6f)));
      lw_s[(16 + l15) * 328 + mm] = f2bf(logf(fmaxf(acc1[r] + bps1, 1e-6f)));
    }
  }
  __syncthreads();
  for (int i = tid; i < 1280; i += 256) {       // 2 layers * 16 g * 40 segs
    int layer = i / 640, rest = i - layer * 640;
    int gg = rest / 40, seg = rest - gg * 40;
    bf16x8 v = *(const bf16x8*)&lw_s[(layer * 16 + gg) * 328 + seg * 8];
    u16* dst = (layer ? logw2 : logw1) + ((size_t)gg * 4096 + n) * 320 + seg * 8;
    *(bf16x8*)dst = v;
  }
}

// ---------------------------------------------------------------------------
// fc1: 256x256-tile 8-phase pipelined MFMA GEMM, BK=64, 512 threads, splitK=4.
// Per K-tile: 4 phases, each = {issue 1 half-tile of t+1, vmcnt(6), barrier,
// 12 swizzled ds_read_b128, setprio1 + 16 MFMA (one 128x128 C-quadrant) +
// setprio0, barrier}.  Issue order [A-lo,B-lo,B-hi,A-hi] makes uniform
// vmcnt(6) retire exactly the half-tile each quadrant needs (3 in flight).
// LDS swizzle: byte ^= ((row&7)<<4), applied via pre-swizzled global source
// (linear global_load_lds dest) and swizzled ds_read offsets (rule #21).
// ---------------------------------------------------------------------------
template <int QR, int QC>
DEV void mfmaq(const u16* LA, const u16* LB, f32x4 (&acc)[8][4],
               int rA, int rB, int xk0, int xk1) {
  bf16x8 a[4][2], b[2][2];
#pragma unroll
  for (int i = 0; i < 4; i++) {
    a[i][0] = *(const bf16x8*)&LA[QR * 8192 + rA + i * 1024 + xk0];
    a[i][1] = *(const bf16x8*)&LA[QR * 8192 + rA + i * 1024 + xk1];
  }
#pragma unroll
  for (int j = 0; j < 2; j++) {
    b[j][0] = *(const bf16x8*)&LB[QC * 8192 + rB + j * 1024 + xk0];
    b[j][1] = *(const bf16x8*)&LB[QC * 8192 + rB + j * 1024 + xk1];
  }
  __builtin_amdgcn_s_setprio(1);
#pragma unroll
  for (int i = 0; i < 4; i++)
#pragma unroll
    for (int j = 0; j < 2; j++) {
      acc[QR * 4 + i][QC * 2 + j] = mfma16(a[i][0], b[j][0], acc[QR * 4 + i][QC * 2 + j]);
      acc[QR * 4 + i][QC * 2 + j] = mfma16(a[i][1], b[j][1], acc[QR * 4 + i][QC * 2 + j]);
    }
  __builtin_amdgcn_s_setprio(0);
  __builtin_amdgcn_s_barrier();
  asm volatile("" ::: "memory");
}

#define WAITBAR(N)                                        \
  asm volatile("s_waitcnt vmcnt(" #N ")" ::: "memory");   \
  __builtin_amdgcn_s_barrier();                           \
  asm volatile("" ::: "memory");                          \
  __builtin_amdgcn_sched_barrier(0);

__global__ __launch_bounds__(512, 2) void gemm8p(
    const u16* __restrict__ A, const u16* __restrict__ Bt,
    float* __restrict__ P) {
  const int K = 12544;                 // 4 splits x 49 tiles x BK=64
  __shared__ u16 lds[65536];           // [buf][A|B][256][64] bf16, 128 KB
  int tid = threadIdx.x;
  int w = tid >> 6, l = tid & 63, h = l >> 4, l15 = l & 15;
  int wm = w >> 2, wn = w & 3;

  // XCD-chunked block swizzle: XCD x gets blocks [x*32, x*32+32)
  int b = ((blockIdx.x & 7) << 5) | (blockIdx.x >> 3);
  int bz = b >> 6, rest = b & 63;
  int bm = (rest & 15) * 256;
  int bn = (rest >> 4) * 256;
  size_t k0 = (size_t)bz * 3136;

  // staging: pre-swizzled per-lane global source (loop-invariant)
  int X = ((tid >> 3) & 7) << 4;            // swizzle bits (bytes)
  int lb = (tid * 16) ^ X;                  // logical byte in an 8KB round
  int lr = lb >> 7;                         // logical row 0..63
  int lc = (lb & 127) >> 1;                 // logical col (elems)
  const u16* pA = A + (size_t)(bm + lr) * K + k0 + lc;
  const u16* pB = Bt + (size_t)(bn + lr) * K + k0 + lc;
  const size_t o64 = (size_t)64 * K, o128 = (size_t)128 * K, o192 = (size_t)192 * K;

  // ds_read swizzled per-lane offsets (loop-invariant)
  int swz = (l15 & 7) << 3;                 // elems
  int xk0 = (h * 8) ^ swz;
  int xk1 = 32 ^ xk0;
  int rA = (wm * 64 + l15) * 64;
  int rB = (wn * 32 + l15) * 64;

  f32x4 acc[8][4];
#pragma unroll
  for (int i = 0; i < 8; i++)
#pragma unroll
    for (int j = 0; j < 4; j++) acc[i][j] = (f32x4){0.f, 0.f, 0.f, 0.f};

  // prologue: tile 0 into buf0, order [A-lo, B-lo, B-hi, A-hi]
  {
    u16* WA = lds; u16* WB = lds + 16384;
    gload16(pA,        WA + tid * 8);
    gload16(pA + o64,  WA + 4096 + tid * 8);
    gload16(pB,        WB + tid * 8);
    gload16(pB + o64,  WB + 4096 + tid * 8);
    gload16(pB + o128, WB + 8192 + tid * 8);
    gload16(pB + o192, WB + 12288 + tid * 8);
    gload16(pA + o128, WA + 8192 + tid * 8);
    gload16(pA + o192, WA + 12288 + tid * 8);
  }

  for (int t = 0; t < 48; t++) {
    int cur = t & 1;
    const u16* LA = lds + cur * 32768;
    const u16* LB = LA + 16384;
    u16* WA = lds + (cur ^ 1) * 32768;
    u16* WB = WA + 16384;
    int ktn = (t + 1) * 64;
    // ph0: issue A-lo(t+1); quadrant (0,0)
    gload16(pA + ktn,        WA + tid * 8);
    gload16(pA + o64 + ktn,  WA + 4096 + tid * 8);
    WAITBAR(6);
    mfmaq<0, 0>(LA, LB, acc, rA, rB, xk0, xk1);
    // ph1: issue B-lo(t+1); quadrant (0,1)
    gload16(pB + ktn,        WB + tid * 8);
    gload16(pB + o64 + ktn,  WB + 4096 + tid * 8);
    WAITBAR(6);
    mfmaq<0, 1>(LA, LB, acc, rA, rB, xk0, xk1);
    // ph2: issue B-hi(t+1); quadrant (1,0)
    gload16(pB + o128 + ktn, WB + 8192 + tid * 8);
    gload16(pB + o192 + ktn, WB + 12288 + tid * 8);
    WAITBAR(6);
    mfmaq<1, 0>(LA, LB, acc, rA, rB, xk0, xk1);
    // ph3: issue A-hi(t+1); quadrant (1,1)
    gload16(pA + o128 + ktn, WA + 8192 + tid * 8);
    gload16(pA + o192 + ktn, WA + 12288 + tid * 8);
    WAITBAR(6);
    mfmaq<1, 1>(LA, LB, acc, rA, rB, xk0, xk1);
  }
  {  // tail tile t=48 (buf0), no issues; staggered drains
    const u16* LA = lds;
    const u16* LB = lds + 16384;
    WAITBAR(4);
    mfmaq<0, 0>(LA, LB, acc, rA, rB, xk0, xk1);
    WAITBAR(2);
    mfmaq<0, 1>(LA, LB, acc, rA, rB, xk0, xk1);
    WAITBAR(0);
    mfmaq<1, 0>(LA, LB, acc, rA, rB, xk0, xk1);
    __builtin_amdgcn_s_barrier();
    asm volatile("" ::: "memory");
    mfmaq<1, 1>(LA, LB, acc, rA, rB, xk0, xk1);
  }

  float* dst = P + (size_t)bz * 4096 * 1024;
#pragma unroll
  for (int qr = 0; qr < 2; qr++)
#pragma unroll
    for (int i = 0; i < 4; i++)
#pragma unroll
      for (int qc = 0; qc < 2; qc++)
#pragma unroll
        for (int j = 0; j < 2; j++) {
          int row0 = bm + qr * 128 + wm * 64 + i * 16 + h * 4;
          int col  = bn + qc * 128 + wn * 32 + j * 16 + l15;
          f32x4 v = acc[qr * 4 + i][qc * 2 + j];
#pragma unroll
          for (int r = 0; r < 4; r++)
            dst[(size_t)(row0 + r) * 1024 + col] = v[r];
        }
}

// ---------------------------------------------------------------------------
// fc1 reduce: xf = p0+p1+p2+p3+bias; xb = bf16(xf)
// ---------------------------------------------------------------------------
__global__ __launch_bounds__(256) void fc_reduce(
    const float* __restrict__ P, const float* __restrict__ bias,
    float* __restrict__ xf, u16* __restrict__ xb) {
  const size_t MN = (size_t)4096 * 1024;
  size_t i = ((size_t)blockIdx.x * 256 + threadIdx.x) * 4;
  size_t stride = (size_t)gridDim.x * 256 * 4;
  for (; i < MN; i += stride) {
    float4 a = *(const float4*)(P + i);
    float4 b = *(const float4*)(P + MN + i);
    float4 c = *(const float4*)(P + 2 * MN + i);
    float4 d = *(const float4*)(P + 3 * MN + i);
    float4 bv = *(const float4*)(bias + (i & 1023));
    float4 r;
    r.x = a.x + b.x + c.x + d.x + bv.x;
    r.y = a.y + b.y + c.y + d.y + bv.y;
    r.z = a.z + b.z + c.z + d.z + bv.z;
    r.w = a.w + b.w + c.w + d.w + bv.w;
    *(float4*)(xf + i) = r;
    u16x4 hv;
    hv[0] = (short)f2bf(r.x); hv[1] = (short)f2bf(r.y);
    hv[2] = (short)f2bf(r.z); hv[3] = (short)f2bf(r.w);
    *(u16x4*)(xb + i) = hv;
  }
}

// ---------------------------------------------------------------------------
// merged 128x64-tile GEMM, up to 3 independent problems in one grid.
// C = A[MxK] * Bt[NxK]^T (+bias), clamped edge loads.
// ---------------------------------------------------------------------------
struct GDesc {
  const u16* A; const u16* Bt; const float* bias;
  u16* Cb; float* Cf;
  int M, N, K, ldc, nt;          // nt = #64-wide col tiles
};

__global__ __launch_bounds__(256) void gemm3(GDesc g0, GDesc g1, GDesc g2,
                                             int c0, int c1) {
  __shared__ u16 As[128 * 32];
  __shared__ u16 Bs[64 * 32];
  GDesc g; int lb = blockIdx.x;
  if (lb < c0) g = g0;
  else if (lb < c1) { g = g1; lb -= c0; }
  else { g = g2; lb -= c1; }
  int bm = (lb / g.nt) * 128, bnn = (lb % g.nt) * 64;
  int tid = threadIdx.x;
  int w = tid >> 6, l = tid & 63, h = l >> 4, l15 = l & 15;
  int wr = (w >> 1) * 64, wc = (w & 1) * 32;
  f32x4 acc[4][2];
#pragma unroll
  for (int i = 0; i < 4; i++)
#pragma unroll
    for (int j = 0; j < 2; j++) acc[i][j] = (f32x4){0.f, 0.f, 0.f, 0.f};

  int o0 = w * 1024 + l * 16;
  int arow0 = o0 >> 6, ace = (o0 & 63) >> 1;
  int ra0 = min(bm + arow0, g.M - 1), ra1 = min(bm + arow0 + 64, g.M - 1);
  int jb  = min(bnn + arow0, g.N - 1);

  for (int kt = 0; kt < g.K; kt += 32) {
    __syncthreads();
    gload16(g.A  + (size_t)ra0 * g.K + kt + ace, &As[arow0 * 32 + ace]);
    gload16(g.A  + (size_t)ra1 * g.K + kt + ace, &As[(arow0 + 64) * 32 + ace]);
    gload16(g.Bt + (size_t)jb  * g.K + kt + ace, &Bs[arow0 * 32 + ace]);
    __syncthreads();
    bf16x8 af[4], bfr[2];
#pragma unroll
    for (int i = 0; i < 4; i++)
      af[i]  = *(const bf16x8*)&As[(wr + i * 16 + l15) * 32 + h * 8];
#pragma unroll
    for (int j = 0; j < 2; j++)
      bfr[j] = *(const bf16x8*)&Bs[(wc + j * 16 + l15) * 32 + h * 8];
#pragma unroll
    for (int i = 0; i < 4; i++)
#pragma unroll
      for (int j = 0; j < 2; j++) acc[i][j] = mfma16(af[i], bfr[j], acc[i][j]);
  }
#pragma unroll
  for (int i = 0; i < 4; i++) {
#pragma unroll
    for (int j = 0; j < 2; j++) {
      int col = bnn + wc + j * 16 + l15;
      if (col >= g.ldc) continue;
      float bv = (g.bias != nullptr && col < g.N) ? g.bias[col] : 0.f;
      int row0 = bm + wr + i * 16 + h * 4;
#pragma unroll
      for (int r = 0; r < 4; r++) {
        int row = row0 + r;
        if (row >= g.M) continue;
        float v = acc[i][j][r] + bv;
        size_t off = (size_t)row * g.ldc + col;
        g.Cb[off] = f2bf(v);
        if (g.Cf != nullptr) g.Cf[off] = v;
      }
    }
  }
}

// ---------------------------------------------------------------------------
// fused attention per (64-row n-tile, head g):
//  QK^T (K in LDS) -> logw tile in LDS -> softmax in registers ->
//  P in LDS -> PV vs KVt -> residual+relu.
// ---------------------------------------------------------------------------
template <bool LAST>
__global__ __launch_bounds__(256) void attn_kernel(
    const u16* __restrict__ qb, const u16* __restrict__ kb,
    const u16* __restrict__ kvt, const u16* __restrict__ logw,
    const float* __restrict__ xf, const float* __restrict__ bo,
    float* __restrict__ outf, u16* __restrict__ outb) {
  __shared__ u16 kp_s[320 * 88];    // K [m][d]; then logw [64][328]; then P [64][344]
  __shared__ u16 kv_s[64 * 344];    // KVt [o][m] pad 344
  int tid = threadIdx.x;
  int g = blockIdx.y, n0 = blockIdx.x * 64;
  int w = tid >> 6, l = tid & 63, h = l >> 4, l15 = l & 15;

  for (int i = tid; i < 320 * 8; i += 256) {        // stage K (zeros m>=300)
    int row = i >> 3, seg = i & 7;
    bf16x8 v = {0, 0, 0, 0, 0, 0, 0, 0};
    if (row < 300) v = *(const bf16x8*)(kb + (size_t)row * 1024 + g * 64 + seg * 8);
    *(bf16x8*)&kp_s[row * 88 + seg * 8] = v;
  }
  for (int i = tid; i < 64 * 40; i += 256) {        // stage KVt
    int row = i / 40, seg = i % 40;
    bf16x8 v = *(const bf16x8*)(kvt + (size_t)(g * 64 + row) * 320 + seg * 8);
    *(bf16x8*)&kv_s[row * 344 + seg * 8] = v;
  }
  int nrow = n0 + w * 16 + l15;
  bf16x8 aq0 = *(const bf16x8*)(qb + (size_t)nrow * 1024 + g * 64 + h * 8);
  bf16x8 aq1 = *(const bf16x8*)(qb + (size_t)nrow * 1024 + g * 64 + 32 + h * 8);
  __syncthreads();

  f32x4 acc[19];
#pragma unroll
  for (int f = 0; f < 19; f++) acc[f] = (f32x4){0.f, 0.f, 0.f, 0.f};
#pragma unroll
  for (int f = 0; f < 19; f++) {
    bf16x8 b0 = *(const bf16x8*)&kp_s[(f * 16 + l15) * 88 + h * 8];
    bf16x8 b1 = *(const bf16x8*)&kp_s[(f * 16 + l15) * 88 + 32 + h * 8];
    acc[f] = mfma16(aq0, b0, acc[f]);
    acc[f] = mfma16(aq1, b1, acc[f]);
  }
  __syncthreads();                     // all waves done reading K
  {                                    // stage logw tile (contiguous 40KB)
    const u16* src = logw + ((size_t)g * 4096 + n0) * 320;
    for (int i = tid; i < 64 * 40; i += 256) {
      int row = i / 40, seg = i % 40;
      *(bf16x8*)&kp_s[row * 328 + seg * 8] = *(const bf16x8*)(src + row * 320 + seg * 8);
    }
  }
  __syncthreads();

  int nbase = n0 + w * 16 + h * 4;
  int lrow = w * 16 + h * 4;
  float mx[4] = {-INFINITY, -INFINITY, -INFINITY, -INFINITY};
  float sm[4] = {0.f, 0.f, 0.f, 0.f};
#pragma unroll
  for (int f = 0; f < 19; f++) {
    int m = f * 16 + l15;
#pragma unroll
    for (int r = 0; r < 4; r++) {
      float lw = -INFINITY;
      if (m < 300) lw = bf2f(kp_s[(lrow + r) * 328 + m]);
      float lg = acc[f][r] * 0.125f + lw;
      acc[f][r] = lg;
      mx[r] = fmaxf(mx[r], lg);
    }
  }
#pragma unroll
  for (int d = 1; d < 16; d <<= 1)
#pragma unroll
    for (int r = 0; r < 4; r++) mx[r] = fmaxf(mx[r], __shfl_xor(mx[r], d));
#pragma unroll
  for (int f = 0; f < 19; f++)
#pragma unroll
    for (int r = 0; r < 4; r++) {
      float p = __expf(acc[f][r] - mx[r]);
      acc[f][r] = p; sm[r] += p;
    }
#pragma unroll
  for (int d = 1; d < 16; d <<= 1)
#pragma unroll
    for (int r = 0; r < 4; r++) sm[r] += __shfl_xor(sm[r], d);
  float inv[4];
#pragma unroll
  for (int r = 0; r < 4; r++) inv[r] = 1.f / sm[r];

  __syncthreads();                     // all waves done reading logw
#pragma unroll
  for (int f = 0; f < 19; f++)
#pragma unroll
    for (int r = 0; r < 4; r++)
      kp_s[(lrow + r) * 344 + f * 16 + l15] = f2bf(acc[f][r]);
#pragma unroll
  for (int r = 0; r < 4; r++)          // zero pad m 304..319
    kp_s[(lrow + r) * 344 + 304 + l15] = 0;

  f32x4 acc2[4];
#pragma unroll
  for (int fo = 0; fo < 4; fo++) acc2[fo] = (f32x4){0.f, 0.f, 0.f, 0.f};
#pragma unroll
  for (int ks = 0; ks < 10; ks++) {
    bf16x8 ap = *(const bf16x8*)&kp_s[(w * 16 + l15) * 344 + ks * 32 + h * 8];
#pragma unroll
    for (int fo = 0; fo < 4; fo++) {
      bf16x8 bv = *(const bf16x8*)&kv_s[(fo * 16 + l15) * 344 + ks * 32 + h * 8];
      acc2[fo] = mfma16(ap, bv, acc2[fo]);
    }
  }
#pragma unroll
  for (int fo = 0; fo < 4; fo++) {
    int col = g * 64 + fo * 16 + l15;
    float bov = bo[col];
#pragma unroll
    for (int r = 0; r < 4; r++) {
      int row = nbase + r;
      float v = xf[(size_t)row * 1024 + col] + acc2[fo][r] * inv[r] + bov;
      v = fmaxf(v, 0.f);
      if (LAST) outf[(size_t)row * 1024 + col] = v;
      else      outb[(size_t)row * 1024 + col] = f2bf(v);
    }
  }
}

// ---------------------------------------------------------------------------
extern "C" void kernel_launch(void* const* d_in, const int* in_sizes, int n_in,
                              void* d_out, int out_size, void* d_ws, size_t ws_size,
                              hipStream_t stream) {
  (void)in_sizes; (void)n_in; (void)out_size; (void)ws_size;
  const float* roi   = (const float*)d_in[0];
  const float* bbox  = (const float*)d_in[1];
  const float* Wfc1  = (const float*)d_in[2];
  const float* bfc1  = (const float*)d_in[3];
  const float* Wfc2  = (const float*)d_in[4];
  const float* bfc2  = (const float*)d_in[5];
  const float* Wpos1 = (const float*)d_in[6];
  const float* bpos1 = (const float*)d_in[7];
  const float* Wq1   = (const float*)d_in[8];
  const float* bq1   = (const float*)d_in[9];
  const float* Wk1   = (const float*)d_in[10];
  const float* bk1   = (const float*)d_in[11];
  const float* Wo1   = (const float*)d_in[12];
  const float* bo1   = (const float*)d_in[13];
  const float* Wpos2 = (const float*)d_in[14];
  const float* bpos2 = (const float*)d_in[15];
  const float* Wq2   = (const float*)d_in[16];
  const float* bq2   = (const float*)d_in[17];
  const float* Wk2   = (const float*)d_in[18];
  const float* bk2   = (const float*)d_in[19];
  const float* Wo2   = (const float*)d_in[20];
  const float* bo2   = (const float*)d_in[21];

  char* ws = (char*)d_ws;                       // ---- workspace arena ----
  u16*  A_b    = (u16*)(ws);                    // 102,760,448
  u16*  Wfc1_t = (u16*)(ws + 102760448);        //  25,690,112
  u16*  Wfc2_t = (u16*)(ws + 128450560);        //   2,097,152 each
  u16*  Wq1_t  = (u16*)(ws + 130547712);
  u16*  Wk1_t  = (u16*)(ws + 132644864);
  u16*  Wq2_t  = (u16*)(ws + 134742016);
  u16*  Wk2_t  = (u16*)(ws + 136839168);
  u16*  Wo1_b  = (u16*)(ws + 138936320);
  u16*  Wo2_b  = (u16*)(ws + 141033472);
  // [143,134,720 .. 227,020,800): logw1+logw2 (41.9 MB each) — ALSO reused
  // as fc1 split-K partials (4 x 16.78 MB fp32) before pos_logw runs.
  u16*   logw1 = (u16*)(ws + 143134720);
  u16*   logw2 = (u16*)(ws + 185077760);
  float* Pp    = (float*)(ws + 143134720);      //  67,108,864 (transient)
  float* xf    = (float*)(ws + 227020800);      //  16,777,216
  u16*  xb_f   = (u16*)(ws + 243798016);        //   8,388,608 (fc out, bf16)
  u16*  xb_a   = (u16*)(ws + 252186624);        //   8,388,608 (attn out, bf16)
  u16*  q_b    = (u16*)(ws + 260575232);        //   8,388,608
  u16*  k_b    = (u16*)(ws + 268963840);        //     614,400
  u16*  kvt_b  = (u16*)(ws + 269578240);        //     655,360 (end 270,233,600)

  // batched converts
  {
    CV3 p;
    p.s[0] = roi;  p.d[0] = A_b;   p.n[0] = (size_t)4096 * 12544;
    p.s[1] = Wo1;  p.d[1] = Wo1_b; p.n[1] = (size_t)1024 * 1024;
    p.s[2] = Wo2;  p.d[2] = Wo2_b; p.n[2] = (size_t)1024 * 1024;
    convert3_kernel<<<dim3(2048, 1, 3), 256, 0, stream>>>(p);
  }
  tconv_kernel<<<dim3(32, 392), 256, 0, stream>>>(Wfc1, Wfc1_t, 12544, 1024);
  {
    TC6 p;
    p.s[0] = Wfc2; p.d[0] = Wfc2_t;
    p.s[1] = Wq1;  p.d[1] = Wq1_t;
    p.s[2] = Wk1;  p.d[2] = Wk1_t;
    p.s[3] = Wq2;  p.d[3] = Wq2_t;
    p.s[4] = Wk2;  p.d[4] = Wk2_t;
    p.s[5] = Wk2;  p.d[5] = Wk2_t;   // slot 5 unused-duplicate (kept simple)
    p.s[5] = Wq2;  p.d[5] = Wq2_t;
    // fix: exactly the 5 needed + one duplicate is wasteful; use all six:
    p.s[0] = Wfc2; p.d[0] = Wfc2_t;
    p.s[1] = Wq1;  p.d[1] = Wq1_t;
    p.s[2] = Wk1;  p.d[2] = Wk1_t;
    p.s[3] = Wq2;  p.d[3] = Wq2_t;
    p.s[4] = Wk2;  p.d[4] = Wk2_t;
    p.s[5] = Wfc2; p.d[5] = Wfc2_t;  // duplicate write, same data (benign)
    tconv6_kernel<<<dim3(32, 32, 5), 256, 0, stream>>>(p);  // z=5 skips dup
  }

  // fc1 split-K=4 (8-phase), reduce, then pos tables (overwrite Pp region)
  gemm8p<<<256, 512, 0, stream>>>(A_b, Wfc1_t, Pp);
  fc_reduce<<<2048, 256, 0, stream>>>(Pp, bfc1, xf, xb_f);
  pos_logw_kernel<<<4096, 256, 0, stream>>>(bbox, Wpos1, Wpos2, bpos1, bpos2, logw1, logw2);

  // ---- layer 1: q, k, kvt in one launch, then attention ----
  {
    GDesc q  = {xb_f,  Wq1_t, bq1, q_b,   nullptr, 4096, 1024, 1024, 1024, 16};
    GDesc kk = {xb_f,  Wk1_t, bk1, k_b,   nullptr,  300, 1024, 1024, 1024, 16};
    GDesc kv = {Wo1_b, xb_f,  nullptr, kvt_b, nullptr, 1024, 300, 1024, 320, 5};
    gemm3<<<600, 256, 0, stream>>>(q, kk, kv, 512, 560);
  }
  attn_kernel<false><<<dim3(64, 16), 256, 0, stream>>>(q_b, k_b, kvt_b, logw1, xf, bo1, nullptr, xb_a);

  // ---- layer 2 ----
  {
    GDesc fc = {xb_a, Wfc2_t, bfc2, xb_f, xf, 4096, 1024, 1024, 1024, 16};
    gemm3<<<512, 256, 0, stream>>>(fc, fc, fc, 512, 512);
  }
  {
    GDesc q  = {xb_f,  Wq2_t, bq2, q_b,   nullptr, 4096, 1024, 1024, 1024, 16};
    GDesc kk = {xb_f,  Wk2_t, bk2, k_b,   nullptr,  300, 1024, 1024, 1024, 16};
    GDesc kv = {Wo2_b, xb_f,  nullptr, kvt_b, nullptr, 1024, 300, 1024, 320, 5};
    gemm3<<<600, 256, 0, stream>>>(q, kk, kv, 512, 560);
  }
  attn_kernel<true><<<dim3(64, 16), 256, 0, stream>>>(q_b, k_b, kvt_b, logw2, xf, bo2, (float*)d_out, nullptr);
}

// Round 4
// 463.563 us; speedup vs baseline: 1.7882x; 1.0212x over previous
//
#include <hip/hip_runtime.h>

// ============================================================================
// FastRCNN Relation FC Head, MI355X round 4.
// vs round 3: (1) gemm8p restructured to ONE vmcnt(8)+barrier per K-tile
// (was 4 waits/tile) with sched_barrier-pinned quadrant phases; (2) new
// gemmU 128x128 BK=64 single-wait pipeline (64KB LDS -> 2 blocks/CU) for
// q/k/kvt and fc2; (3) prep kernels merged into one launch; (4) fc_reduce
// and pos_logw merged (logw moved to its own region; ws is ~822MB).
// 8 launches total.  Workspace: 354 MB.
// ============================================================================

using bf16x8 = __attribute__((ext_vector_type(8))) short;
using u16x4  = __attribute__((ext_vector_type(4))) short;
using f32x4  = __attribute__((ext_vector_type(4))) float;
typedef unsigned short u16;
typedef unsigned int   u32;

#define DEV __device__ __forceinline__

DEV u16 f2bf(float f) {                      // fp32 -> bf16, round-nearest-even
  u32 u = __float_as_uint(f);
  return (u16)((u + 0x7FFFu + ((u >> 16) & 1u)) >> 16);
}
DEV float bf2f(u16 h) { return __uint_as_float(((u32)h) << 16); }

DEV f32x4 mfma16(bf16x8 a, bf16x8 b, f32x4 c) {
  return __builtin_amdgcn_mfma_f32_16x16x32_bf16(a, b, c, 0, 0, 0);
}
DEV void gload16(const u16* g, u16* l) {
  __builtin_amdgcn_global_load_lds((const __attribute__((address_space(1))) void*)g,
                                   (__attribute__((address_space(3))) void*)l, 16, 0, 0);
}

DEV void fsincos(float x, float* s, float* c) {
  float r = x * 0.15915494309189535f;   // revolutions, exact-identity reduction
  r -= rintf(r);
  float a = r * 6.283185307179586f;
  *s = __sinf(a); *c = __cosf(a);
}

// ---------------------------------------------------------------------------
// prep: all converts/transposes in one launch.
//  [0,2048)        roi    fp32->bf16 grid-stride
//  [2048,2560)     Wo1    fp32->bf16
//  [2560,3072)     Wo2    fp32->bf16
//  [3072,15616)    Wfc1   12544x1024 transpose+convert
//  [15616,20736)   5x 1024x1024 transpose+convert (Wfc2,Wq1,Wk1,Wq2,Wk2)
// ---------------------------------------------------------------------------
struct PrepArgs {
  const float* roi; u16* A_b;
  const float* Wo1; u16* Wo1_b;
  const float* Wo2; u16* Wo2_b;
  const float* Wfc1; u16* Wfc1_t;
  const float* wsrc[5]; u16* wdst[5];
};

__global__ __launch_bounds__(256) void prep_kernel(PrepArgs p) {
  __shared__ float tp[32][33];
  int b = blockIdx.x, tid = threadIdx.x;
  if (b < 3072) {                               // plain converts
    const float* src; u16* dst; size_t n; int b0, nb;
    if (b < 2048)      { src = p.roi; dst = p.A_b;   n = (size_t)4096 * 12544; b0 = b;        nb = 2048; }
    else if (b < 2560) { src = p.Wo1; dst = p.Wo1_b; n = (size_t)1024 * 1024;  b0 = b - 2048; nb = 512; }
    else               { src = p.Wo2; dst = p.Wo2_b; n = (size_t)1024 * 1024;  b0 = b - 2560; nb = 512; }
    size_t i = ((size_t)b0 * 256 + tid) * 8;
    size_t stride = (size_t)nb * 256 * 8;
    for (; i < n; i += stride) {
      float4 a = *(const float4*)(src + i);
      float4 c = *(const float4*)(src + i + 4);
      bf16x8 v;
      v[0]=(short)f2bf(a.x); v[1]=(short)f2bf(a.y); v[2]=(short)f2bf(a.z); v[3]=(short)f2bf(a.w);
      v[4]=(short)f2bf(c.x); v[5]=(short)f2bf(c.y); v[6]=(short)f2bf(c.z); v[7]=(short)f2bf(c.w);
      *(bf16x8*)(dst + i) = v;
    }
  } else {                                      // 32x32-tile transposes
    const float* in; u16* out; int r0, c0, R, C;
    if (b < 15616) {
      int idx = b - 3072;
      in = p.Wfc1; out = p.Wfc1_t; R = 12544; C = 1024;
      c0 = (idx & 31) * 32; r0 = (idx >> 5) * 32;
    } else {
      int idx = b - 15616;
      int z = idx >> 10, rest = idx & 1023;
      in = p.wsrc[z]; out = p.wdst[z]; R = 1024; C = 1024;
      c0 = (rest & 31) * 32; r0 = (rest >> 5) * 32;
    }
    int tx = tid & 31, ty = tid >> 5;
#pragma unroll
    for (int i = 0; i < 4; i++)
      tp[ty + i * 8][tx] = in[(size_t)(r0 + ty + i * 8) * C + c0 + tx];
    __syncthreads();
#pragma unroll
    for (int i = 0; i < 4; i++)
      out[(size_t)(c0 + ty + i * 8) * R + r0 + tx] = f2bf(tp[tx][ty + i * 8]);
  }
}

// ---------------------------------------------------------------------------
// fc1: 256x256-tile MFMA GEMM, BK=64, 512 threads, splitK=4.
// Per K-tile: issue 8 prefetch loads (tile t+1) -> vmcnt(8) -> barrier ->
// 4 sched_barrier-pinned quadrant phases (12 ds_read + 16 MFMA each, setprio
// around MFMA) -> barrier.  LDS XOR-swizzle byte^=((row&7)<<4) via
// pre-swizzled global source + swizzled ds_read offsets.
// ---------------------------------------------------------------------------
template <int QR, int QC>
DEV void mfmaq(const u16* LA, const u16* LB, f32x4 (&acc)[8][4],
               int rA, int rB, int xk0, int xk1) {
  bf16x8 a[4][2], b[2][2];
#pragma unroll
  for (int i = 0; i < 4; i++) {
    a[i][0] = *(const bf16x8*)&LA[QR * 8192 + rA + i * 1024 + xk0];
    a[i][1] = *(const bf16x8*)&LA[QR * 8192 + rA + i * 1024 + xk1];
  }
#pragma unroll
  for (int j = 0; j < 2; j++) {
    b[j][0] = *(const bf16x8*)&LB[QC * 8192 + rB + j * 1024 + xk0];
    b[j][1] = *(const bf16x8*)&LB[QC * 8192 + rB + j * 1024 + xk1];
  }
  __builtin_amdgcn_s_setprio(1);
#pragma unroll
  for (int i = 0; i < 4; i++)
#pragma unroll
    for (int j = 0; j < 2; j++) {
      acc[QR * 4 + i][QC * 2 + j] = mfma16(a[i][0], b[j][0], acc[QR * 4 + i][QC * 2 + j]);
      acc[QR * 4 + i][QC * 2 + j] = mfma16(a[i][1], b[j][1], acc[QR * 4 + i][QC * 2 + j]);
    }
  __builtin_amdgcn_s_setprio(0);
}

__global__ __launch_bounds__(512, 2) void gemm8p(
    const u16* __restrict__ A, const u16* __restrict__ Bt,
    float* __restrict__ P) {
  const int K = 12544;                 // 4 splits x 49 tiles x BK=64
  __shared__ u16 lds[65536];           // 2 buf x (A 32KB + B 32KB) = 128 KB
  int tid = threadIdx.x;
  int w = tid >> 6, l = tid & 63, h = l >> 4, l15 = l & 15;
  int wm = w >> 2, wn = w & 3;

  int b = ((blockIdx.x & 7) << 5) | (blockIdx.x >> 3);   // XCD-chunked swizzle
  int bz = b >> 6, rest = b & 63;
  int bm = (rest & 15) * 256;
  int bn = (rest >> 4) * 256;
  size_t k0 = (size_t)bz * 3136;

  // staging: pre-swizzled per-lane global source (loop-invariant)
  int X = ((tid >> 3) & 7) << 4;            // swizzle bits (bytes)
  int lb = (tid * 16) ^ X;                  // logical byte in an 8KB round
  int lr = lb >> 7;                         // logical row 0..63
  int lc = (lb & 127) >> 1;                 // logical col (elems)
  const u16* pA = A + (size_t)(bm + lr) * K + k0 + lc;
  const u16* pB = Bt + (size_t)(bn + lr) * K + k0 + lc;
  const size_t o64 = (size_t)64 * K, o128 = (size_t)128 * K, o192 = (size_t)192 * K;

  // ds_read swizzled per-lane offsets (loop-invariant)
  int swz = (l15 & 7) << 3;                 // elems
  int xk0 = (h * 8) ^ swz;
  int xk1 = 32 ^ xk0;
  int rA = (wm * 64 + l15) * 64;
  int rB = (wn * 32 + l15) * 64;

  f32x4 acc[8][4];
#pragma unroll
  for (int i = 0; i < 8; i++)
#pragma unroll
    for (int j = 0; j < 4; j++) acc[i][j] = (f32x4){0.f, 0.f, 0.f, 0.f};

#define ISSUE8(WA, WB, kk)                                 \
  { gload16(pA + (kk),        (WA) + tid * 8);             \
    gload16(pA + o64 + (kk),  (WA) + 4096 + tid * 8);      \
    gload16(pA + o128 + (kk), (WA) + 8192 + tid * 8);      \
    gload16(pA + o192 + (kk), (WA) + 12288 + tid * 8);     \
    gload16(pB + (kk),        (WB) + tid * 8);             \
    gload16(pB + o64 + (kk),  (WB) + 4096 + tid * 8);      \
    gload16(pB + o128 + (kk), (WB) + 8192 + tid * 8);      \
    gload16(pB + o192 + (kk), (WB) + 12288 + tid * 8); }

  ISSUE8(lds, lds + 16384, 0);              // prologue: tile 0 -> buf0

  for (int t = 0; t < 49; t++) {
    const u16* LA = lds + (t & 1) * 32768;
    const u16* LB = LA + 16384;
    u16* WA = lds + ((t ^ 1) & 1) * 32768;
    u16* WB = WA + 16384;
    if (t < 48) {
      int ktn = (t + 1) * 64;
      ISSUE8(WA, WB, ktn);
      asm volatile("s_waitcnt vmcnt(8)" ::: "memory");
    } else {
      asm volatile("s_waitcnt vmcnt(0)" ::: "memory");
    }
    __builtin_amdgcn_s_barrier();
    asm volatile("" ::: "memory");
    __builtin_amdgcn_sched_barrier(0);
    mfmaq<0, 0>(LA, LB, acc, rA, rB, xk0, xk1);
    __builtin_amdgcn_sched_barrier(0);
    mfmaq<0, 1>(LA, LB, acc, rA, rB, xk0, xk1);
    __builtin_amdgcn_sched_barrier(0);
    mfmaq<1, 0>(LA, LB, acc, rA, rB, xk0, xk1);
    __builtin_amdgcn_sched_barrier(0);
    mfmaq<1, 1>(LA, LB, acc, rA, rB, xk0, xk1);
    __builtin_amdgcn_sched_barrier(0);
    asm volatile("" ::: "memory");
    __builtin_amdgcn_s_barrier();           // all reads of LA/LB done before
  }                                         // next iter's DMA can land there
#undef ISSUE8

  float* dst = P + (size_t)bz * 4096 * 1024;
#pragma unroll
  for (int qr = 0; qr < 2; qr++)
#pragma unroll
    for (int i = 0; i < 4; i++)
#pragma unroll
      for (int qc = 0; qc < 2; qc++)
#pragma unroll
        for (int j = 0; j < 2; j++) {
          int row0 = bm + qr * 128 + wm * 64 + i * 16 + h * 4;
          int col  = bn + qc * 128 + wn * 32 + j * 16 + l15;
          f32x4 v = acc[qr * 4 + i][qc * 2 + j];
#pragma unroll
          for (int r = 0; r < 4; r++)
            dst[(size_t)(row0 + r) * 1024 + col] = v[r];
        }
}

// ---------------------------------------------------------------------------
// fc_reduce (blocks [0,2048)) || pos_logw (blocks [2048,6144)) in one launch.
// ---------------------------------------------------------------------------
__constant__ float C100D[8] = {100.f, 42.16965034285822f, 17.78279410038923f,
                               7.498942093324559f, 3.1622776601683795f,
                               1.333521432163324f, 0.5623413251903491f,
                               0.23713737056616552f};

__global__ __launch_bounds__(256) void reduce_pos_kernel(
    const float* __restrict__ P, const float* __restrict__ bias,
    float* __restrict__ xf, u16* __restrict__ xb,
    const float* __restrict__ bbox,
    const float* __restrict__ Wpos1, const float* __restrict__ Wpos2,
    const float* __restrict__ bpos1, const float* __restrict__ bpos2,
    u16* __restrict__ logw1, u16* __restrict__ logw2) {
  __shared__ u16 pool[18944];     // emb 64*88 | wp 32*88 | lw 2*16*328
  int tid = threadIdx.x;
  if (blockIdx.x < 2048) {        // ---- fc1 split-K reduce ----
    const size_t MN = (size_t)4096 * 1024;
    size_t i = ((size_t)blockIdx.x * 256 + tid) * 4;
    size_t stride = (size_t)2048 * 256 * 4;
    for (; i < MN; i += stride) {
      float4 a = *(const float4*)(P + i);
      float4 b = *(const float4*)(P + MN + i);
      float4 c = *(const float4*)(P + 2 * MN + i);
      float4 d = *(const float4*)(P + 3 * MN + i);
      float4 bv = *(const float4*)(bias + (i & 1023));
      float4 r;
      r.x = a.x + b.x + c.x + d.x + bv.x;
      r.y = a.y + b.y + c.y + d.y + bv.y;
      r.z = a.z + b.z + c.z + d.z + bv.z;
      r.w = a.w + b.w + c.w + d.w + bv.w;
      *(float4*)(xf + i) = r;
      u16x4 hv;
      hv[0] = (short)f2bf(r.x); hv[1] = (short)f2bf(r.y);
      hv[2] = (short)f2bf(r.z); hv[3] = (short)f2bf(r.w);
      *(u16x4*)(xb + i) = hv;
    }
    return;
  }
  // ---- pos_logw ----
  u16* emb_s = pool;              // [64][88]
  u16* wp_s  = pool + 5632;       // [32][88]
  u16* lw_s  = pool + 8448;       // [2*16][328]
  int n = blockIdx.x - 2048;
  int w = tid >> 6, l = tid & 63, h = l >> 4, l15 = l & 15;
  for (int idx = tid; idx < 1024; idx += 256) {   // stage Wpos^T both layers
    int e = idx >> 4, c = idx & 15;               // Wpos[e][c], EMB=64 GROUP=16
    wp_s[c * 88 + e]        = f2bf(Wpos1[idx]);
    wp_s[(16 + c) * 88 + e] = f2bf(Wpos2[idx]);
  }
  float4 bn = ((const float4*)bbox)[n];
  float bw_n = bn.z - bn.x + 1.f, bh_n = bn.w - bn.y + 1.f;
  float cx_n = 0.5f * (bn.x + bn.z), cy_n = 0.5f * (bn.y + bn.w);
  float bps0 = bpos1[l15], bps1 = bpos2[l15];
  int p = tid >> 2, k = tid & 3;

  for (int m0 = 0; m0 < 320; m0 += 64) {
    int m = m0 + p;
    float4 bm = ((const float4*)bbox)[m];
    float v;
    if (k == 0)      v = logf(fmaxf(fabsf((cx_n - 0.5f * (bm.x + bm.z)) / bw_n), 1e-3f));
    else if (k == 1) v = logf(fmaxf(fabsf((cy_n - 0.5f * (bm.y + bm.w)) / bh_n), 1e-3f));
    else if (k == 2) v = logf(bw_n / (bm.z - bm.x + 1.f));
    else             v = logf(bh_n / (bm.w - bm.y + 1.f));
    __syncthreads();                      // protect previous tile's frag reads
#pragma unroll
    for (int tt = 0; tt < 8; tt++) {
      float s, c; fsincos(v * C100D[tt], &s, &c);
      emb_s[p * 88 + k * 16 + tt]     = f2bf(s);
      emb_s[p * 88 + k * 16 + 8 + tt] = f2bf(c);
    }
    __syncthreads();
    f32x4 acc0 = {0.f, 0.f, 0.f, 0.f}, acc1 = {0.f, 0.f, 0.f, 0.f};
    bf16x8 a0 = *(const bf16x8*)&emb_s[(w * 16 + l15) * 88 + h * 8];
    bf16x8 a1 = *(const bf16x8*)&emb_s[(w * 16 + l15) * 88 + 32 + h * 8];
    bf16x8 b00 = *(const bf16x8*)&wp_s[l15 * 88 + h * 8];
    bf16x8 b01 = *(const bf16x8*)&wp_s[l15 * 88 + 32 + h * 8];
    bf16x8 b10 = *(const bf16x8*)&wp_s[(16 + l15) * 88 + h * 8];
    bf16x8 b11 = *(const bf16x8*)&wp_s[(16 + l15) * 88 + 32 + h * 8];
    acc0 = mfma16(a0, b00, acc0); acc0 = mfma16(a1, b01, acc0);
    acc1 = mfma16(a0, b10, acc1); acc1 = mfma16(a1, b11, acc1);
#pragma unroll
    for (int r = 0; r < 4; r++) {
      int mm = m0 + w * 16 + h * 4 + r;
      lw_s[l15 * 328 + mm]        = f2bf(logf(fmaxf(acc0[r] + bps0, 1e-6f)));
      lw_s[(16 + l15) * 328 + mm] = f2bf(logf(fmaxf(acc1[r] + bps1, 1e-6f)));
    }
  }
  __syncthreads();
  for (int i = tid; i < 1280; i += 256) {       // 2 layers * 16 g * 40 segs
    int layer = i / 640, rest = i - layer * 640;
    int gg = rest / 40, seg = rest - gg * 40;
    bf16x8 v = *(const bf16x8*)&lw_s[(layer * 16 + gg) * 328 + seg * 8];
    u16* dst = (layer ? logw2 : logw1) + ((size_t)gg * 4096 + n) * 320 + seg * 8;
    *(bf16x8*)dst = v;
  }
}

// ---------------------------------------------------------------------------
// gemmU: 128x128-tile BK=64 pipelined GEMM (single wait/tile, 64KB LDS ->
// 2 blocks/CU), up to 3 problems per grid.  C = A[MxK]*Bt[NxK]^T (+bias).
// Edge rows/cols via clamped loads (finite dup data, masked at epilogue).
// ---------------------------------------------------------------------------
struct GDesc {
  const u16* A; const u16* Bt; const float* bias;
  u16* Cb; float* Cf;
  int M, N, K, ldc, nt;          // nt = #128-wide col tiles
};

__global__ __launch_bounds__(256, 2) void gemmU(GDesc g0, GDesc g1, GDesc g2,
                                                int c0, int c1) {
  __shared__ u16 lds[32768];     // 2 buf x (A 128x64 + B 128x64) bf16 = 64 KB
  GDesc g; int lb = blockIdx.x;
  if (lb < c0) { g = g0; lb = (lb & 7) * (c0 >> 3) + (lb >> 3); }  // XCD swz
  else if (lb < c1) { g = g1; lb -= c0; }
  else { g = g2; lb -= c1; }
  int bm = (lb / g.nt) * 128, bn = (lb % g.nt) * 128;
  int tid = threadIdx.x;
  int w = tid >> 6, l = tid & 63, h = l >> 4, l15 = l & 15;
  int wm = w >> 1, wn = w & 1;
  int K = g.K;

  // staging: pre-swizzled source, 8 chunks of 4KB (32 rows each)
  int X = ((tid >> 3) & 7) << 4;
  int lbyte = (tid * 16) ^ X;
  int lr = lbyte >> 7, lc = (lbyte & 127) >> 1;
  const u16 *pa[4], *pb[4];
#pragma unroll
  for (int c = 0; c < 4; c++) {
    pa[c] = g.A  + (size_t)min(bm + c * 32 + lr, g.M - 1) * K + lc;
    pb[c] = g.Bt + (size_t)min(bn + c * 32 + lr, g.N - 1) * K + lc;
  }

  int swz = (l15 & 7) << 3;
  int xk0 = (h * 8) ^ swz;
  int xk1 = 32 ^ xk0;
  int rA = (wm * 64 + l15) * 64;
  int rB = (wn * 64 + l15) * 64;

  f32x4 acc[4][4];
#pragma unroll
  for (int i = 0; i < 4; i++)
#pragma unroll
    for (int j = 0; j < 4; j++) acc[i][j] = (f32x4){0.f, 0.f, 0.f, 0.f};

#define ISSUEU(W, kk)                                     \
  { gload16(pa[0] + (kk), (W) + tid * 8);                 \
    gload16(pa[1] + (kk), (W) + 2048 + tid * 8);          \
    gload16(pa[2] + (kk), (W) + 4096 + tid * 8);          \
    gload16(pa[3] + (kk), (W) + 6144 + tid * 8);          \
    gload16(pb[0] + (kk), (W) + 8192 + tid * 8);          \
    gload16(pb[1] + (kk), (W) + 10240 + tid * 8);         \
    gload16(pb[2] + (kk), (W) + 12288 + tid * 8);         \
    gload16(pb[3] + (kk), (W) + 14336 + tid * 8); }

  ISSUEU(lds, 0);
  int ktiles = K >> 6;
  for (int t = 0; t < ktiles; t++) {
    const u16* LA = lds + (t & 1) * 16384;
    const u16* LB = LA + 8192;
    u16* W = lds + ((t ^ 1) & 1) * 16384;
    if (t < ktiles - 1) {
      ISSUEU(W, (t + 1) * 64);
      asm volatile("s_waitcnt vmcnt(8)" ::: "memory");
    } else {
      asm volatile("s_waitcnt vmcnt(0)" ::: "memory");
    }
    __builtin_amdgcn_s_barrier();
    asm volatile("" ::: "memory");
    __builtin_amdgcn_sched_barrier(0);
    bf16x8 a[4][2], bfr[4][2];
#pragma unroll
    for (int i = 0; i < 4; i++) {
      a[i][0] = *(const bf16x8*)&LA[rA + i * 1024 + xk0];
      a[i][1] = *(const bf16x8*)&LA[rA + i * 1024 + xk1];
    }
#pragma unroll
    for (int j = 0; j < 4; j++) {
      bfr[j][0] = *(const bf16x8*)&LB[rB + j * 1024 + xk0];
      bfr[j][1] = *(const bf16x8*)&LB[rB + j * 1024 + xk1];
    }
    __builtin_amdgcn_s_setprio(1);
#pragma unroll
    for (int i = 0; i < 4; i++)
#pragma unroll
      for (int j = 0; j < 4; j++) {
        acc[i][j] = mfma16(a[i][0], bfr[j][0], acc[i][j]);
        acc[i][j] = mfma16(a[i][1], bfr[j][1], acc[i][j]);
      }
    __builtin_amdgcn_s_setprio(0);
    __builtin_amdgcn_sched_barrier(0);
    asm volatile("" ::: "memory");
    __builtin_amdgcn_s_barrier();
  }
#undef ISSUEU

#pragma unroll
  for (int i = 0; i < 4; i++) {
#pragma unroll
    for (int j = 0; j < 4; j++) {
      int col = bn + wn * 64 + j * 16 + l15;
      if (col >= g.ldc) continue;
      float bv = (g.bias != nullptr && col < g.N) ? g.bias[col] : 0.f;
      int row0 = bm + wm * 64 + i * 16 + h * 4;
#pragma unroll
      for (int r = 0; r < 4; r++) {
        int row = row0 + r;
        if (row >= g.M) continue;
        float v = acc[i][j][r] + bv;
        size_t off = (size_t)row * g.ldc + col;
        g.Cb[off] = f2bf(v);
        if (g.Cf != nullptr) g.Cf[off] = v;
      }
    }
  }
}

// ---------------------------------------------------------------------------
// fused attention per (64-row n-tile, head g):
//  QK^T (K in LDS) -> logw tile in LDS -> softmax in registers ->
//  P in LDS -> PV vs KVt -> residual+relu.
// ---------------------------------------------------------------------------
template <bool LAST>
__global__ __launch_bounds__(256) void attn_kernel(
    const u16* __restrict__ qb, const u16* __restrict__ kb,
    const u16* __restrict__ kvt, const u16* __restrict__ logw,
    const float* __restrict__ xf, const float* __restrict__ bo,
    float* __restrict__ outf, u16* __restrict__ outb) {
  __shared__ u16 kp_s[320 * 88];    // K [m][d]; then logw [64][328]; then P [64][344]
  __shared__ u16 kv_s[64 * 344];    // KVt [o][m] pad 344
  int tid = threadIdx.x;
  int g = blockIdx.y, n0 = blockIdx.x * 64;
  int w = tid >> 6, l = tid & 63, h = l >> 4, l15 = l & 15;

  for (int i = tid; i < 320 * 8; i += 256) {        // stage K (zeros m>=300)
    int row = i >> 3, seg = i & 7;
    bf16x8 v = {0, 0, 0, 0, 0, 0, 0, 0};
    if (row < 300) v = *(const bf16x8*)(kb + (size_t)row * 1024 + g * 64 + seg * 8);
    *(bf16x8*)&kp_s[row * 88 + seg * 8] = v;
  }
  for (int i = tid; i < 64 * 40; i += 256) {        // stage KVt
    int row = i / 40, seg = i % 40;
    bf16x8 v = *(const bf16x8*)(kvt + (size_t)(g * 64 + row) * 320 + seg * 8);
    *(bf16x8*)&kv_s[row * 344 + seg * 8] = v;
  }
  int nrow = n0 + w * 16 + l15;
  bf16x8 aq0 = *(const bf16x8*)(qb + (size_t)nrow * 1024 + g * 64 + h * 8);
  bf16x8 aq1 = *(const bf16x8*)(qb + (size_t)nrow * 1024 + g * 64 + 32 + h * 8);
  __syncthreads();

  f32x4 acc[19];
#pragma unroll
  for (int f = 0; f < 19; f++) acc[f] = (f32x4){0.f, 0.f, 0.f, 0.f};
#pragma unroll
  for (int f = 0; f < 19; f++) {
    bf16x8 b0 = *(const bf16x8*)&kp_s[(f * 16 + l15) * 88 + h * 8];
    bf16x8 b1 = *(const bf16x8*)&kp_s[(f * 16 + l15) * 88 + 32 + h * 8];
    acc[f] = mfma16(aq0, b0, acc[f]);
    acc[f] = mfma16(aq1, b1, acc[f]);
  }
  __syncthreads();                     // all waves done reading K
  {                                    // stage logw tile (contiguous 40KB)
    const u16* src = logw + ((size_t)g * 4096 + n0) * 320;
    for (int i = tid; i < 64 * 40; i += 256) {
      int row = i / 40, seg = i % 40;
      *(bf16x8*)&kp_s[row * 328 + seg * 8] = *(const bf16x8*)(src + row * 320 + seg * 8);
    }
  }
  __syncthreads();

  int nbase = n0 + w * 16 + h * 4;
  int lrow = w * 16 + h * 4;
  float mx[4] = {-INFINITY, -INFINITY, -INFINITY, -INFINITY};
  float sm[4] = {0.f, 0.f, 0.f, 0.f};
#pragma unroll
  for (int f = 0; f < 19; f++) {
    int m = f * 16 + l15;
#pragma unroll
    for (int r = 0; r < 4; r++) {
      float lw = -INFINITY;
      if (m < 300) lw = bf2f(kp_s[(lrow + r) * 328 + m]);
      float lg = acc[f][r] * 0.125f + lw;
      acc[f][r] = lg;
      mx[r] = fmaxf(mx[r], lg);
    }
  }
#pragma unroll
  for (int d = 1; d < 16; d <<= 1)
#pragma unroll
    for (int r = 0; r < 4; r++) mx[r] = fmaxf(mx[r], __shfl_xor(mx[r], d));
#pragma unroll
  for (int f = 0; f < 19; f++)
#pragma unroll
    for (int r = 0; r < 4; r++) {
      float p = __expf(acc[f][r] - mx[r]);
      acc[f][r] = p; sm[r] += p;
    }
#pragma unroll
  for (int d = 1; d < 16; d <<= 1)
#pragma unroll
    for (int r = 0; r < 4; r++) sm[r] += __shfl_xor(sm[r], d);
  float inv[4];
#pragma unroll
  for (int r = 0; r < 4; r++) inv[r] = 1.f / sm[r];

  __syncthreads();                     // all waves done reading logw
#pragma unroll
  for (int f = 0; f < 19; f++)
#pragma unroll
    for (int r = 0; r < 4; r++)
      kp_s[(lrow + r) * 344 + f * 16 + l15] = f2bf(acc[f][r]);
#pragma unroll
  for (int r = 0; r < 4; r++)          // zero pad m 304..319
    kp_s[(lrow + r) * 344 + 304 + l15] = 0;

  f32x4 acc2[4];
#pragma unroll
  for (int fo = 0; fo < 4; fo++) acc2[fo] = (f32x4){0.f, 0.f, 0.f, 0.f};
#pragma unroll
  for (int ks = 0; ks < 10; ks++) {
    bf16x8 ap = *(const bf16x8*)&kp_s[(w * 16 + l15) * 344 + ks * 32 + h * 8];
#pragma unroll
    for (int fo = 0; fo < 4; fo++) {
      bf16x8 bv = *(const bf16x8*)&kv_s[(fo * 16 + l15) * 344 + ks * 32 + h * 8];
      acc2[fo] = mfma16(ap, bv, acc2[fo]);
    }
  }
#pragma unroll
  for (int fo = 0; fo < 4; fo++) {
    int col = g * 64 + fo * 16 + l15;
    float bov = bo[col];
#pragma unroll
    for (int r = 0; r < 4; r++) {
      int row = nbase + r;
      float v = xf[(size_t)row * 1024 + col] + acc2[fo][r] * inv[r] + bov;
      v = fmaxf(v, 0.f);
      if (LAST) outf[(size_t)row * 1024 + col] = v;
      else      outb[(size_t)row * 1024 + col] = f2bf(v);
    }
  }
}

// ---------------------------------------------------------------------------
extern "C" void kernel_launch(void* const* d_in, const int* in_sizes, int n_in,
                              void* d_out, int out_size, void* d_ws, size_t ws_size,
                              hipStream_t stream) {
  (void)in_sizes; (void)n_in; (void)out_size; (void)ws_size;
  const float* roi   = (const float*)d_in[0];
  const float* bbox  = (const float*)d_in[1];
  const float* Wfc1  = (const float*)d_in[2];
  const float* bfc1  = (const float*)d_in[3];
  const float* Wfc2  = (const float*)d_in[4];
  const float* bfc2  = (const float*)d_in[5];
  const float* Wpos1 = (const float*)d_in[6];
  const float* bpos1 = (const float*)d_in[7];
  const float* Wq1   = (const float*)d_in[8];
  const float* bq1   = (const float*)d_in[9];
  const float* Wk1   = (const float*)d_in[10];
  const float* bk1   = (const float*)d_in[11];
  const float* Wo1   = (const float*)d_in[12];
  const float* bo1   = (const float*)d_in[13];
  const float* Wpos2 = (const float*)d_in[14];
  const float* bpos2 = (const float*)d_in[15];
  const float* Wq2   = (const float*)d_in[16];
  const float* bq2   = (const float*)d_in[17];
  const float* Wk2   = (const float*)d_in[18];
  const float* bk2   = (const float*)d_in[19];
  const float* Wo2   = (const float*)d_in[20];
  const float* bo2   = (const float*)d_in[21];

  char* ws = (char*)d_ws;                       // ---- workspace arena ----
  u16*  A_b    = (u16*)(ws);                    // 102,760,448
  u16*  Wfc1_t = (u16*)(ws + 102760448);        //  25,690,112
  u16*  Wfc2_t = (u16*)(ws + 128450560);        //   2,097,152 each
  u16*  Wq1_t  = (u16*)(ws + 130547712);
  u16*  Wk1_t  = (u16*)(ws + 132644864);
  u16*  Wq2_t  = (u16*)(ws + 134742016);
  u16*  Wk2_t  = (u16*)(ws + 136839168);
  u16*  Wo1_b  = (u16*)(ws + 138936320);
  u16*  Wo2_b  = (u16*)(ws + 141033472);
  float* Pp    = (float*)(ws + 143134720);      //  67,108,864 (splitK partials)
  float* xf    = (float*)(ws + 227020800);      //  16,777,216
  u16*  xb_f   = (u16*)(ws + 243798016);        //   8,388,608 (fc out, bf16)
  u16*  xb_a   = (u16*)(ws + 252186624);        //   8,388,608 (attn out, bf16)
  u16*  q_b    = (u16*)(ws + 260575232);        //   8,388,608
  u16*  k_b    = (u16*)(ws + 268963840);        //     614,400
  u16*  kvt_b  = (u16*)(ws + 269578240);        //     655,360
  u16*  logw1  = (u16*)(ws + 270233600);        //  41,943,040
  u16*  logw2  = (u16*)(ws + 312176640);        //  41,943,040 (end 354,119,680)

  {                                             // 1. prep (all converts)
    PrepArgs p;
    p.roi = roi;   p.A_b = A_b;
    p.Wo1 = Wo1;   p.Wo1_b = Wo1_b;
    p.Wo2 = Wo2;   p.Wo2_b = Wo2_b;
    p.Wfc1 = Wfc1; p.Wfc1_t = Wfc1_t;
    p.wsrc[0] = Wfc2; p.wdst[0] = Wfc2_t;
    p.wsrc[1] = Wq1;  p.wdst[1] = Wq1_t;
    p.wsrc[2] = Wk1;  p.wdst[2] = Wk1_t;
    p.wsrc[3] = Wq2;  p.wdst[3] = Wq2_t;
    p.wsrc[4] = Wk2;  p.wdst[4] = Wk2_t;
    prep_kernel<<<20736, 256, 0, stream>>>(p);
  }
  // 2. fc1 split-K=4
  gemm8p<<<256, 512, 0, stream>>>(A_b, Wfc1_t, Pp);
  // 3. reduce || pos tables
  reduce_pos_kernel<<<6144, 256, 0, stream>>>(Pp, bfc1, xf, xb_f, bbox,
                                              Wpos1, Wpos2, bpos1, bpos2,
                                              logw1, logw2);
  // ---- layer 1 ----
  {
    GDesc q  = {xb_f,  Wq1_t, bq1, q_b,   nullptr, 4096, 1024, 1024, 1024, 8};
    GDesc kk = {xb_f,  Wk1_t, bk1, k_b,   nullptr,  300, 1024, 1024, 1024, 8};
    GDesc kv = {Wo1_b, xb_f,  nullptr, kvt_b, nullptr, 1024, 300, 1024, 320, 3};
    gemmU<<<304, 256, 0, stream>>>(q, kk, kv, 256, 280);
  }
  attn_kernel<false><<<dim3(64, 16), 256, 0, stream>>>(q_b, k_b, kvt_b, logw1, xf, bo1, nullptr, xb_a);

  // ---- layer 2 ----
  {
    GDesc fc = {xb_a, Wfc2_t, bfc2, xb_f, xf, 4096, 1024, 1024, 1024, 8};
    gemmU<<<256, 256, 0, stream>>>(fc, fc, fc, 256, 256);
  }
  {
    GDesc q  = {xb_f,  Wq2_t, bq2, q_b,   nullptr, 4096, 1024, 1024, 1024, 8};
    GDesc kk = {xb_f,  Wk2_t, bk2, k_b,   nullptr,  300, 1024, 1024, 1024, 8};
    GDesc kv = {Wo2_b, xb_f,  nullptr, kvt_b, nullptr, 1024, 300, 1024, 320, 3};
    gemmU<<<304, 256, 0, stream>>>(q, kk, kv, 256, 280);
  }
  attn_kernel<true><<<dim3(64, 16), 256, 0, stream>>>(q_b, k_b, kvt_b, logw2, xf, bo2, (float*)d_out, nullptr);
}

// Round 5
// 435.075 us; speedup vs baseline: 1.9053x; 1.0655x over previous
//
#include <hip/hip_runtime.h>

// ============================================================================
// FastRCNN Relation FC Head, MI355X round 5.
// vs round 4: gemm8p rebuilt as a 3-phase counted-vmcnt pipeline derived from
// the m201 template arithmetic: per K-tile
//   ph0: stage A-lo(t+1); vmcnt(6); bar; read A-lo,B-lo frags; 16 MFMA Q00
//   ph1: stage B-lo(t+1); vmcnt(6); bar; read B-hi frags;     16 MFMA Q01
//   ph2: stage B-hi,A-hi(t+1); vmcnt(8); bar; read A-hi;      32 MFMA Q11,Q10
// (tail tile drains 4 -> 2 -> 0, matching the template's epilogue).
// Gray-code fragment reuse: 24 ds_read_b128/tile (was 48), 3 barriers (was 8).
// Everything else identical to round 4.  Workspace: 354 MB.
// ============================================================================

using bf16x8 = __attribute__((ext_vector_type(8))) short;
using u16x4  = __attribute__((ext_vector_type(4))) short;
using f32x4  = __attribute__((ext_vector_type(4))) float;
typedef unsigned short u16;
typedef unsigned int   u32;

#define DEV __device__ __forceinline__

DEV u16 f2bf(float f) {                      // fp32 -> bf16, round-nearest-even
  u32 u = __float_as_uint(f);
  return (u16)((u + 0x7FFFu + ((u >> 16) & 1u)) >> 16);
}
DEV float bf2f(u16 h) { return __uint_as_float(((u32)h) << 16); }

DEV f32x4 mfma16(bf16x8 a, bf16x8 b, f32x4 c) {
  return __builtin_amdgcn_mfma_f32_16x16x32_bf16(a, b, c, 0, 0, 0);
}
DEV void gload16(const u16* g, u16* l) {
  __builtin_amdgcn_global_load_lds((const __attribute__((address_space(1))) void*)g,
                                   (__attribute__((address_space(3))) void*)l, 16, 0, 0);
}

DEV void fsincos(float x, float* s, float* c) {
  float r = x * 0.15915494309189535f;   // revolutions, exact-identity reduction
  r -= rintf(r);
  float a = r * 6.283185307179586f;
  *s = __sinf(a); *c = __cosf(a);
}

// ---------------------------------------------------------------------------
// prep: all converts/transposes in one launch.
//  [0,2048)        roi    fp32->bf16 grid-stride
//  [2048,2560)     Wo1    fp32->bf16
//  [2560,3072)     Wo2    fp32->bf16
//  [3072,15616)    Wfc1   12544x1024 transpose+convert
//  [15616,20736)   5x 1024x1024 transpose+convert (Wfc2,Wq1,Wk1,Wq2,Wk2)
// ---------------------------------------------------------------------------
struct PrepArgs {
  const float* roi; u16* A_b;
  const float* Wo1; u16* Wo1_b;
  const float* Wo2; u16* Wo2_b;
  const float* Wfc1; u16* Wfc1_t;
  const float* wsrc[5]; u16* wdst[5];
};

__global__ __launch_bounds__(256) void prep_kernel(PrepArgs p) {
  __shared__ float tp[32][33];
  int b = blockIdx.x, tid = threadIdx.x;
  if (b < 3072) {                               // plain converts
    const float* src; u16* dst; size_t n; int b0, nb;
    if (b < 2048)      { src = p.roi; dst = p.A_b;   n = (size_t)4096 * 12544; b0 = b;        nb = 2048; }
    else if (b < 2560) { src = p.Wo1; dst = p.Wo1_b; n = (size_t)1024 * 1024;  b0 = b - 2048; nb = 512; }
    else               { src = p.Wo2; dst = p.Wo2_b; n = (size_t)1024 * 1024;  b0 = b - 2560; nb = 512; }
    size_t i = ((size_t)b0 * 256 + tid) * 8;
    size_t stride = (size_t)nb * 256 * 8;
    for (; i < n; i += stride) {
      float4 a = *(const float4*)(src + i);
      float4 c = *(const float4*)(src + i + 4);
      bf16x8 v;
      v[0]=(short)f2bf(a.x); v[1]=(short)f2bf(a.y); v[2]=(short)f2bf(a.z); v[3]=(short)f2bf(a.w);
      v[4]=(short)f2bf(c.x); v[5]=(short)f2bf(c.y); v[6]=(short)f2bf(c.z); v[7]=(short)f2bf(c.w);
      *(bf16x8*)(dst + i) = v;
    }
  } else {                                      // 32x32-tile transposes
    const float* in; u16* out; int r0, c0, R, C;
    if (b < 15616) {
      int idx = b - 3072;
      in = p.Wfc1; out = p.Wfc1_t; R = 12544; C = 1024;
      c0 = (idx & 31) * 32; r0 = (idx >> 5) * 32;
    } else {
      int idx = b - 15616;
      int z = idx >> 10, rest = idx & 1023;
      in = p.wsrc[z]; out = p.wdst[z]; R = 1024; C = 1024;
      c0 = (rest & 31) * 32; r0 = (rest >> 5) * 32;
    }
    int tx = tid & 31, ty = tid >> 5;
#pragma unroll
    for (int i = 0; i < 4; i++)
      tp[ty + i * 8][tx] = in[(size_t)(r0 + ty + i * 8) * C + c0 + tx];
    __syncthreads();
#pragma unroll
    for (int i = 0; i < 4; i++)
      out[(size_t)(c0 + ty + i * 8) * R + r0 + tx] = f2bf(tp[tx][ty + i * 8]);
  }
}

// ---------------------------------------------------------------------------
// fc1: 256x256-tile MFMA GEMM, BK=64, 512 threads, splitK=4, 3-phase
// counted-vmcnt pipeline (see header).  LDS XOR-swizzle byte^=((row&7)<<4)
// via pre-swizzled global source + swizzled ds_read offsets.
// ---------------------------------------------------------------------------
#define WAITBAR(N)                                        \
  asm volatile("s_waitcnt vmcnt(" #N ")" ::: "memory");   \
  __builtin_amdgcn_s_barrier();                           \
  asm volatile("" ::: "memory");

__global__ __launch_bounds__(512, 2) void gemm8p(
    const u16* __restrict__ A, const u16* __restrict__ Bt,
    float* __restrict__ P) {
  const int K = 12544;                 // 4 splits x 49 tiles x BK=64
  __shared__ u16 lds[65536];           // 2 buf x (A 32KB + B 32KB) = 128 KB
  int tid = threadIdx.x;
  int w = tid >> 6, l = tid & 63, h = l >> 4, l15 = l & 15;
  int wm = w >> 2, wn = w & 3;

  int b = ((blockIdx.x & 7) << 5) | (blockIdx.x >> 3);   // XCD-chunked swizzle
  int bz = b >> 6, rest = b & 63;
  int bm = (rest & 15) * 256;
  int bn = (rest >> 4) * 256;
  size_t k0 = (size_t)bz * 3136;

  // staging: pre-swizzled per-lane global source (loop-invariant)
  int X = ((tid >> 3) & 7) << 4;            // swizzle bits (bytes)
  int lb = (tid * 16) ^ X;                  // logical byte in an 8KB round
  int lr = lb >> 7;                         // logical row 0..63
  int lc = (lb & 127) >> 1;                 // logical col (elems)
  const u16* pA = A + (size_t)(bm + lr) * K + k0 + lc;
  const u16* pB = Bt + (size_t)(bn + lr) * K + k0 + lc;
  const size_t o64 = (size_t)64 * K, o128 = (size_t)128 * K, o192 = (size_t)192 * K;

  // ds_read swizzled per-lane offsets (loop-invariant)
  int swz = (l15 & 7) << 3;                 // elems
  int xk0 = (h * 8) ^ swz;
  int xk1 = 32 ^ xk0;
  int rA = (wm * 64 + l15) * 64;
  int rB = (wn * 32 + l15) * 64;

  f32x4 acc[8][4];
#pragma unroll
  for (int i = 0; i < 8; i++)
#pragma unroll
    for (int j = 0; j < 4; j++) acc[i][j] = (f32x4){0.f, 0.f, 0.f, 0.f};

  // prologue: tile 0 -> buf0, FIFO order [A-lo, B-lo, B-hi, A-hi]
  {
    u16* WA = lds; u16* WB = lds + 16384;
    gload16(pA,        WA + tid * 8);
    gload16(pA + o64,  WA + 4096 + tid * 8);
    gload16(pB,        WB + tid * 8);
    gload16(pB + o64,  WB + 4096 + tid * 8);
    gload16(pB + o128, WB + 8192 + tid * 8);
    gload16(pB + o192, WB + 12288 + tid * 8);
    gload16(pA + o128, WA + 8192 + tid * 8);
    gload16(pA + o192, WA + 12288 + tid * 8);
  }

  bf16x8 af[4][2], bl[2][2], bh[2][2];

#define READ_AF(BASE)                                                    \
  _Pragma("unroll") for (int i = 0; i < 4; i++) {                        \
    af[i][0] = *(const bf16x8*)&LA[(BASE) + rA + i * 1024 + xk0];        \
    af[i][1] = *(const bf16x8*)&LA[(BASE) + rA + i * 1024 + xk1];        \
  }
#define Q_MFMA(QR, QC, BF)                                               \
  __builtin_amdgcn_s_setprio(1);                                         \
  _Pragma("unroll") for (int i = 0; i < 4; i++)                          \
    _Pragma("unroll") for (int j = 0; j < 2; j++) {                      \
      acc[(QR)*4+i][(QC)*2+j] = mfma16(af[i][0], BF[j][0], acc[(QR)*4+i][(QC)*2+j]); \
      acc[(QR)*4+i][(QC)*2+j] = mfma16(af[i][1], BF[j][1], acc[(QR)*4+i][(QC)*2+j]); \
    }                                                                    \
  __builtin_amdgcn_s_setprio(0);

  for (int t = 0; t < 48; t++) {
    const u16* LA = lds + (t & 1) * 32768;
    const u16* LB = LA + 16384;
    u16* WA = lds + ((t + 1) & 1) * 32768;
    u16* WB = WA + 16384;
    int ktn = (t + 1) * 64;
    // ---- ph0: stage A-lo(t+1); Q00 = A-lo x B-lo ----
    gload16(pA + ktn,        WA + tid * 8);
    gload16(pA + o64 + ktn,  WA + 4096 + tid * 8);
    WAITBAR(6);
    READ_AF(0);
#pragma unroll
    for (int j = 0; j < 2; j++) {
      bl[j][0] = *(const bf16x8*)&LB[rB + j * 1024 + xk0];
      bl[j][1] = *(const bf16x8*)&LB[rB + j * 1024 + xk1];
    }
    Q_MFMA(0, 0, bl);
    // ---- ph1: stage B-lo(t+1); Q01 = A-lo x B-hi ----
    gload16(pB + ktn,        WB + tid * 8);
    gload16(pB + o64 + ktn,  WB + 4096 + tid * 8);
    WAITBAR(6);
#pragma unroll
    for (int j = 0; j < 2; j++) {
      bh[j][0] = *(const bf16x8*)&LB[8192 + rB + j * 1024 + xk0];
      bh[j][1] = *(const bf16x8*)&LB[8192 + rB + j * 1024 + xk1];
    }
    Q_MFMA(0, 1, bh);
    // ---- ph2: stage B-hi,A-hi(t+1); Q11 + Q10 ----
    gload16(pB + o128 + ktn, WB + 8192 + tid * 8);
    gload16(pB + o192 + ktn, WB + 12288 + tid * 8);
    gload16(pA + o128 + ktn, WA + 8192 + tid * 8);
    gload16(pA + o192 + ktn, WA + 12288 + tid * 8);
    WAITBAR(8);
    READ_AF(8192);
    Q_MFMA(1, 1, bh);
    Q_MFMA(1, 0, bl);
  }
  {  // ---- tail tile t=48 (buf0): drain 4 -> 2 -> 0 ----
    const u16* LA = lds;
    const u16* LB = lds + 16384;
    WAITBAR(4);
    READ_AF(0);
#pragma unroll
    for (int j = 0; j < 2; j++) {
      bl[j][0] = *(const bf16x8*)&LB[rB + j * 1024 + xk0];
      bl[j][1] = *(const bf16x8*)&LB[rB + j * 1024 + xk1];
    }
    Q_MFMA(0, 0, bl);
    WAITBAR(2);
#pragma unroll
    for (int j = 0; j < 2; j++) {
      bh[j][0] = *(const bf16x8*)&LB[8192 + rB + j * 1024 + xk0];
      bh[j][1] = *(const bf16x8*)&LB[8192 + rB + j * 1024 + xk1];
    }
    Q_MFMA(0, 1, bh);
    WAITBAR(0);
    READ_AF(8192);
    Q_MFMA(1, 1, bh);
    Q_MFMA(1, 0, bl);
  }
#undef READ_AF
#undef Q_MFMA

  float* dst = P + (size_t)bz * 4096 * 1024;
#pragma unroll
  for (int qr = 0; qr < 2; qr++)
#pragma unroll
    for (int i = 0; i < 4; i++)
#pragma unroll
      for (int qc = 0; qc < 2; qc++)
#pragma unroll
        for (int j = 0; j < 2; j++) {
          int row0 = bm + qr * 128 + wm * 64 + i * 16 + h * 4;
          int col  = bn + qc * 128 + wn * 32 + j * 16 + l15;
          f32x4 v = acc[qr * 4 + i][qc * 2 + j];
#pragma unroll
          for (int r = 0; r < 4; r++)
            dst[(size_t)(row0 + r) * 1024 + col] = v[r];
        }
}

// ---------------------------------------------------------------------------
// fc_reduce (blocks [0,2048)) || pos_logw (blocks [2048,6144)) in one launch.
// ---------------------------------------------------------------------------
__constant__ float C100D[8] = {100.f, 42.16965034285822f, 17.78279410038923f,
                               7.498942093324559f, 3.1622776601683795f,
                               1.333521432163324f, 0.5623413251903491f,
                               0.23713737056616552f};

__global__ __launch_bounds__(256) void reduce_pos_kernel(
    const float* __restrict__ P, const float* __restrict__ bias,
    float* __restrict__ xf, u16* __restrict__ xb,
    const float* __restrict__ bbox,
    const float* __restrict__ Wpos1, const float* __restrict__ Wpos2,
    const float* __restrict__ bpos1, const float* __restrict__ bpos2,
    u16* __restrict__ logw1, u16* __restrict__ logw2) {
  __shared__ u16 pool[18944];     // emb 64*88 | wp 32*88 | lw 2*16*328
  int tid = threadIdx.x;
  if (blockIdx.x < 2048) {        // ---- fc1 split-K reduce ----
    const size_t MN = (size_t)4096 * 1024;
    size_t i = ((size_t)blockIdx.x * 256 + tid) * 4;
    size_t stride = (size_t)2048 * 256 * 4;
    for (; i < MN; i += stride) {
      float4 a = *(const float4*)(P + i);
      float4 b = *(const float4*)(P + MN + i);
      float4 c = *(const float4*)(P + 2 * MN + i);
      float4 d = *(const float4*)(P + 3 * MN + i);
      float4 bv = *(const float4*)(bias + (i & 1023));
      float4 r;
      r.x = a.x + b.x + c.x + d.x + bv.x;
      r.y = a.y + b.y + c.y + d.y + bv.y;
      r.z = a.z + b.z + c.z + d.z + bv.z;
      r.w = a.w + b.w + c.w + d.w + bv.w;
      *(float4*)(xf + i) = r;
      u16x4 hv;
      hv[0] = (short)f2bf(r.x); hv[1] = (short)f2bf(r.y);
      hv[2] = (short)f2bf(r.z); hv[3] = (short)f2bf(r.w);
      *(u16x4*)(xb + i) = hv;
    }
    return;
  }
  // ---- pos_logw ----
  u16* emb_s = pool;              // [64][88]
  u16* wp_s  = pool + 5632;       // [32][88]
  u16* lw_s  = pool + 8448;       // [2*16][328]
  int n = blockIdx.x - 2048;
  int w = tid >> 6, l = tid & 63, h = l >> 4, l15 = l & 15;
  for (int idx = tid; idx < 1024; idx += 256) {   // stage Wpos^T both layers
    int e = idx >> 4, c = idx & 15;               // Wpos[e][c], EMB=64 GROUP=16
    wp_s[c * 88 + e]        = f2bf(Wpos1[idx]);
    wp_s[(16 + c) * 88 + e] = f2bf(Wpos2[idx]);
  }
  float4 bn = ((const float4*)bbox)[n];
  float bw_n = bn.z - bn.x + 1.f, bh_n = bn.w - bn.y + 1.f;
  float cx_n = 0.5f * (bn.x + bn.z), cy_n = 0.5f * (bn.y + bn.w);
  float bps0 = bpos1[l15], bps1 = bpos2[l15];
  int p = tid >> 2, k = tid & 3;

  for (int m0 = 0; m0 < 320; m0 += 64) {
    int m = m0 + p;
    float4 bm = ((const float4*)bbox)[m];
    float v;
    if (k == 0)      v = logf(fmaxf(fabsf((cx_n - 0.5f * (bm.x + bm.z)) / bw_n), 1e-3f));
    else if (k == 1) v = logf(fmaxf(fabsf((cy_n - 0.5f * (bm.y + bm.w)) / bh_n), 1e-3f));
    else if (k == 2) v = logf(bw_n / (bm.z - bm.x + 1.f));
    else             v = logf(bh_n / (bm.w - bm.y + 1.f));
    __syncthreads();                      // protect previous tile's frag reads
#pragma unroll
    for (int tt = 0; tt < 8; tt++) {
      float s, c; fsincos(v * C100D[tt], &s, &c);
      emb_s[p * 88 + k * 16 + tt]     = f2bf(s);
      emb_s[p * 88 + k * 16 + 8 + tt] = f2bf(c);
    }
    __syncthreads();
    f32x4 acc0 = {0.f, 0.f, 0.f, 0.f}, acc1 = {0.f, 0.f, 0.f, 0.f};
    bf16x8 a0 = *(const bf16x8*)&emb_s[(w * 16 + l15) * 88 + h * 8];
    bf16x8 a1 = *(const bf16x8*)&emb_s[(w * 16 + l15) * 88 + 32 + h * 8];
    bf16x8 b00 = *(const bf16x8*)&wp_s[l15 * 88 + h * 8];
    bf16x8 b01 = *(const bf16x8*)&wp_s[l15 * 88 + 32 + h * 8];
    bf16x8 b10 = *(const bf16x8*)&wp_s[(16 + l15) * 88 + h * 8];
    bf16x8 b11 = *(const bf16x8*)&wp_s[(16 + l15) * 88 + 32 + h * 8];
    acc0 = mfma16(a0, b00, acc0); acc0 = mfma16(a1, b01, acc0);
    acc1 = mfma16(a0, b10, acc1); acc1 = mfma16(a1, b11, acc1);
#pragma unroll
    for (int r = 0; r < 4; r++) {
      int mm = m0 + w * 16 + h * 4 + r;
      lw_s[l15 * 328 + mm]        = f2bf(logf(fmaxf(acc0[r] + bps0, 1e-6f)));
      lw_s[(16 + l15) * 328 + mm] = f2bf(logf(fmaxf(acc1[r] + bps1, 1e-6f)));
    }
  }
  __syncthreads();
  for (int i = tid; i < 1280; i += 256) {       // 2 layers * 16 g * 40 segs
    int layer = i / 640, rest = i - layer * 640;
    int gg = rest / 40, seg = rest - gg * 40;
    bf16x8 v = *(const bf16x8*)&lw_s[(layer * 16 + gg) * 328 + seg * 8];
    u16* dst = (layer ? logw2 : logw1) + ((size_t)gg * 4096 + n) * 320 + seg * 8;
    *(bf16x8*)dst = v;
  }
}

// ---------------------------------------------------------------------------
// gemmU: 128x128-tile BK=64 pipelined GEMM (single wait/tile, 64KB LDS ->
// 2 blocks/CU), up to 3 problems per grid.  C = A[MxK]*Bt[NxK]^T (+bias).
// ---------------------------------------------------------------------------
struct GDesc {
  const u16* A; const u16* Bt; const float* bias;
  u16* Cb; float* Cf;
  int M, N, K, ldc, nt;          // nt = #128-wide col tiles
};

__global__ __launch_bounds__(256, 2) void gemmU(GDesc g0, GDesc g1, GDesc g2,
                                                int c0, int c1) {
  __shared__ u16 lds[32768];     // 2 buf x (A 128x64 + B 128x64) bf16 = 64 KB
  GDesc g; int lb = blockIdx.x;
  if (lb < c0) { g = g0; lb = (lb & 7) * (c0 >> 3) + (lb >> 3); }  // XCD swz
  else if (lb < c1) { g = g1; lb -= c0; }
  else { g = g2; lb -= c1; }
  int bm = (lb / g.nt) * 128, bn = (lb % g.nt) * 128;
  int tid = threadIdx.x;
  int w = tid >> 6, l = tid & 63, h = l >> 4, l15 = l & 15;
  int wm = w >> 1, wn = w & 1;
  int K = g.K;

  // staging: pre-swizzled source, 8 chunks of 4KB (32 rows each)
  int X = ((tid >> 3) & 7) << 4;
  int lbyte = (tid * 16) ^ X;
  int lr = lbyte >> 7, lc = (lbyte & 127) >> 1;
  const u16 *pa[4], *pb[4];
#pragma unroll
  for (int c = 0; c < 4; c++) {
    pa[c] = g.A  + (size_t)min(bm + c * 32 + lr, g.M - 1) * K + lc;
    pb[c] = g.Bt + (size_t)min(bn + c * 32 + lr, g.N - 1) * K + lc;
  }

  int swz = (l15 & 7) << 3;
  int xk0 = (h * 8) ^ swz;
  int xk1 = 32 ^ xk0;
  int rA = (wm * 64 + l15) * 64;
  int rB = (wn * 64 + l15) * 64;

  f32x4 acc[4][4];
#pragma unroll
  for (int i = 0; i < 4; i++)
#pragma unroll
    for (int j = 0; j < 4; j++) acc[i][j] = (f32x4){0.f, 0.f, 0.f, 0.f};

#define ISSUEU(W, kk)                                     \
  { gload16(pa[0] + (kk), (W) + tid * 8);                 \
    gload16(pa[1] + (kk), (W) + 2048 + tid * 8);          \
    gload16(pa[2] + (kk), (W) + 4096 + tid * 8);          \
    gload16(pa[3] + (kk), (W) + 6144 + tid * 8);          \
    gload16(pb[0] + (kk), (W) + 8192 + tid * 8);          \
    gload16(pb[1] + (kk), (W) + 10240 + tid * 8);         \
    gload16(pb[2] + (kk), (W) + 12288 + tid * 8);         \
    gload16(pb[3] + (kk), (W) + 14336 + tid * 8); }

  ISSUEU(lds, 0);
  int ktiles = K >> 6;
  for (int t = 0; t < ktiles; t++) {
    const u16* LA = lds + (t & 1) * 16384;
    const u16* LB = LA + 8192;
    u16* W = lds + ((t ^ 1) & 1) * 16384;
    if (t < ktiles - 1) {
      ISSUEU(W, (t + 1) * 64);
      asm volatile("s_waitcnt vmcnt(8)" ::: "memory");
    } else {
      asm volatile("s_waitcnt vmcnt(0)" ::: "memory");
    }
    __builtin_amdgcn_s_barrier();
    asm volatile("" ::: "memory");
    bf16x8 a[4][2], bfr[4][2];
#pragma unroll
    for (int i = 0; i < 4; i++) {
      a[i][0] = *(const bf16x8*)&LA[rA + i * 1024 + xk0];
      a[i][1] = *(const bf16x8*)&LA[rA + i * 1024 + xk1];
    }
#pragma unroll
    for (int j = 0; j < 4; j++) {
      bfr[j][0] = *(const bf16x8*)&LB[rB + j * 1024 + xk0];
      bfr[j][1] = *(const bf16x8*)&LB[rB + j * 1024 + xk1];
    }
    __builtin_amdgcn_s_setprio(1);
#pragma unroll
    for (int i = 0; i < 4; i++)
#pragma unroll
      for (int j = 0; j < 4; j++) {
        acc[i][j] = mfma16(a[i][0], bfr[j][0], acc[i][j]);
        acc[i][j] = mfma16(a[i][1], bfr[j][1], acc[i][j]);
      }
    __builtin_amdgcn_s_setprio(0);
    asm volatile("" ::: "memory");
    __builtin_amdgcn_s_barrier();
  }
#undef ISSUEU

#pragma unroll
  for (int i = 0; i < 4; i++) {
#pragma unroll
    for (int j = 0; j < 4; j++) {
      int col = bn + wn * 64 + j * 16 + l15;
      if (col >= g.ldc) continue;
      float bv = (g.bias != nullptr && col < g.N) ? g.bias[col] : 0.f;
      int row0 = bm + wm * 64 + i * 16 + h * 4;
#pragma unroll
      for (int r = 0; r < 4; r++) {
        int row = row0 + r;
        if (row >= g.M) continue;
        float v = acc[i][j][r] + bv;
        size_t off = (size_t)row * g.ldc + col;
        g.Cb[off] = f2bf(v);
        if (g.Cf != nullptr) g.Cf[off] = v;
      }
    }
  }
}

// ---------------------------------------------------------------------------
// fused attention per (64-row n-tile, head g):
//  QK^T (K in LDS) -> logw tile in LDS -> softmax in registers ->
//  P in LDS -> PV vs KVt -> residual+relu.
// ---------------------------------------------------------------------------
template <bool LAST>
__global__ __launch_bounds__(256) void attn_kernel(
    const u16* __restrict__ qb, const u16* __restrict__ kb,
    const u16* __restrict__ kvt, const u16* __restrict__ logw,
    const float* __restrict__ xf, const float* __restrict__ bo,
    float* __restrict__ outf, u16* __restrict__ outb) {
  __shared__ u16 kp_s[320 * 88];    // K [m][d]; then logw [64][328]; then P [64][344]
  __shared__ u16 kv_s[64 * 344];    // KVt [o][m] pad 344
  int tid = threadIdx.x;
  int g = blockIdx.y, n0 = blockIdx.x * 64;
  int w = tid >> 6, l = tid & 63, h = l >> 4, l15 = l & 15;

  for (int i = tid; i < 320 * 8; i += 256) {        // stage K (zeros m>=300)
    int row = i >> 3, seg = i & 7;
    bf16x8 v = {0, 0, 0, 0, 0, 0, 0, 0};
    if (row < 300) v = *(const bf16x8*)(kb + (size_t)row * 1024 + g * 64 + seg * 8);
    *(bf16x8*)&kp_s[row * 88 + seg * 8] = v;
  }
  for (int i = tid; i < 64 * 40; i += 256) {        // stage KVt
    int row = i / 40, seg = i % 40;
    bf16x8 v = *(const bf16x8*)(kvt + (size_t)(g * 64 + row) * 320 + seg * 8);
    *(bf16x8*)&kv_s[row * 344 + seg * 8] = v;
  }
  int nrow = n0 + w * 16 + l15;
  bf16x8 aq0 = *(const bf16x8*)(qb + (size_t)nrow * 1024 + g * 64 + h * 8);
  bf16x8 aq1 = *(const bf16x8*)(qb + (size_t)nrow * 1024 + g * 64 + 32 + h * 8);
  __syncthreads();

  f32x4 acc[19];
#pragma unroll
  for (int f = 0; f < 19; f++) acc[f] = (f32x4){0.f, 0.f, 0.f, 0.f};
#pragma unroll
  for (int f = 0; f < 19; f++) {
    bf16x8 b0 = *(const bf16x8*)&kp_s[(f * 16 + l15) * 88 + h * 8];
    bf16x8 b1 = *(const bf16x8*)&kp_s[(f * 16 + l15) * 88 + 32 + h * 8];
    acc[f] = mfma16(aq0, b0, acc[f]);
    acc[f] = mfma16(aq1, b1, acc[f]);
  }
  __syncthreads();                     // all waves done reading K
  {                                    // stage logw tile (contiguous 40KB)
    const u16* src = logw + ((size_t)g * 4096 + n0) * 320;
    for (int i = tid; i < 64 * 40; i += 256) {
      int row = i / 40, seg = i % 40;
      *(bf16x8*)&kp_s[row * 328 + seg * 8] = *(const bf16x8*)(src + row * 320 + seg * 8);
    }
  }
  __syncthreads();

  int nbase = n0 + w * 16 + h * 4;
  int lrow = w * 16 + h * 4;
  float mx[4] = {-INFINITY, -INFINITY, -INFINITY, -INFINITY};
  float sm[4] = {0.f, 0.f, 0.f, 0.f};
#pragma unroll
  for (int f = 0; f < 19; f++) {
    int m = f * 16 + l15;
#pragma unroll
    for (int r = 0; r < 4; r++) {
      float lw = -INFINITY;
      if (m < 300) lw = bf2f(kp_s[(lrow + r) * 328 + m]);
      float lg = acc[f][r] * 0.125f + lw;
      acc[f][r] = lg;
      mx[r] = fmaxf(mx[r], lg);
    }
  }
#pragma unroll
  for (int d = 1; d < 16; d <<= 1)
#pragma unroll
    for (int r = 0; r < 4; r++) mx[r] = fmaxf(mx[r], __shfl_xor(mx[r], d));
#pragma unroll
  for (int f = 0; f < 19; f++)
#pragma unroll
    for (int r = 0; r < 4; r++) {
      float p = __expf(acc[f][r] - mx[r]);
      acc[f][r] = p; sm[r] += p;
    }
#pragma unroll
  for (int d = 1; d < 16; d <<= 1)
#pragma unroll
    for (int r = 0; r < 4; r++) sm[r] += __shfl_xor(sm[r], d);
  float inv[4];
#pragma unroll
  for (int r = 0; r < 4; r++) inv[r] = 1.f / sm[r];

  __syncthreads();                     // all waves done reading logw
#pragma unroll
  for (int f = 0; f < 19; f++)
#pragma unroll
    for (int r = 0; r < 4; r++)
      kp_s[(lrow + r) * 344 + f * 16 + l15] = f2bf(acc[f][r]);
#pragma unroll
  for (int r = 0; r < 4; r++)          // zero pad m 304..319
    kp_s[(lrow + r) * 344 + 304 + l15] = 0;

  f32x4 acc2[4];
#pragma unroll
  for (int fo = 0; fo < 4; fo++) acc2[fo] = (f32x4){0.f, 0.f, 0.f, 0.f};
#pragma unroll
  for (int ks = 0; ks < 10; ks++) {
    bf16x8 ap = *(const bf16x8*)&kp_s[(w * 16 + l15) * 344 + ks * 32 + h * 8];
#pragma unroll
    for (int fo = 0; fo < 4; fo++) {
      bf16x8 bv = *(const bf16x8*)&kv_s[(fo * 16 + l15) * 344 + ks * 32 + h * 8];
      acc2[fo] = mfma16(ap, bv, acc2[fo]);
    }
  }
#pragma unroll
  for (int fo = 0; fo < 4; fo++) {
    int col = g * 64 + fo * 16 + l15;
    float bov = bo[col];
#pragma unroll
    for (int r = 0; r < 4; r++) {
      int row = nbase + r;
      float v = xf[(size_t)row * 1024 + col] + acc2[fo][r] * inv[r] + bov;
      v = fmaxf(v, 0.f);
      if (LAST) outf[(size_t)row * 1024 + col] = v;
      else      outb[(size_t)row * 1024 + col] = f2bf(v);
    }
  }
}

// ---------------------------------------------------------------------------
extern "C" void kernel_launch(void* const* d_in, const int* in_sizes, int n_in,
                              void* d_out, int out_size, void* d_ws, size_t ws_size,
                              hipStream_t stream) {
  (void)in_sizes; (void)n_in; (void)out_size; (void)ws_size;
  const float* roi   = (const float*)d_in[0];
  const float* bbox  = (const float*)d_in[1];
  const float* Wfc1  = (const float*)d_in[2];
  const float* bfc1  = (const float*)d_in[3];
  const float* Wfc2  = (const float*)d_in[4];
  const float* bfc2  = (const float*)d_in[5];
  const float* Wpos1 = (const float*)d_in[6];
  const float* bpos1 = (const float*)d_in[7];
  const float* Wq1   = (const float*)d_in[8];
  const float* bq1   = (const float*)d_in[9];
  const float* Wk1   = (const float*)d_in[10];
  const float* bk1   = (const float*)d_in[11];
  const float* Wo1   = (const float*)d_in[12];
  const float* bo1   = (const float*)d_in[13];
  const float* Wpos2 = (const float*)d_in[14];
  const float* bpos2 = (const float*)d_in[15];
  const float* Wq2   = (const float*)d_in[16];
  const float* bq2   = (const float*)d_in[17];
  const float* Wk2   = (const float*)d_in[18];
  const float* bk2   = (const float*)d_in[19];
  const float* Wo2   = (const float*)d_in[20];
  const float* bo2   = (const float*)d_in[21];

  char* ws = (char*)d_ws;                       // ---- workspace arena ----
  u16*  A_b    = (u16*)(ws);                    // 102,760,448
  u16*  Wfc1_t = (u16*)(ws + 102760448);        //  25,690,112
  u16*  Wfc2_t = (u16*)(ws + 128450560);        //   2,097,152 each
  u16*  Wq1_t  = (u16*)(ws + 130547712);
  u16*  Wk1_t  = (u16*)(ws + 132644864);
  u16*  Wq2_t  = (u16*)(ws + 134742016);
  u16*  Wk2_t  = (u16*)(ws + 136839168);
  u16*  Wo1_b  = (u16*)(ws + 138936320);
  u16*  Wo2_b  = (u16*)(ws + 141033472);
  float* Pp    = (float*)(ws + 143134720);      //  67,108,864 (splitK partials)
  float* xf    = (float*)(ws + 227020800);      //  16,777,216
  u16*  xb_f   = (u16*)(ws + 243798016);        //   8,388,608 (fc out, bf16)
  u16*  xb_a   = (u16*)(ws + 252186624);        //   8,388,608 (attn out, bf16)
  u16*  q_b    = (u16*)(ws + 260575232);        //   8,388,608
  u16*  k_b    = (u16*)(ws + 268963840);        //     614,400
  u16*  kvt_b  = (u16*)(ws + 269578240);        //     655,360
  u16*  logw1  = (u16*)(ws + 270233600);        //  41,943,040
  u16*  logw2  = (u16*)(ws + 312176640);        //  41,943,040 (end 354,119,680)

  {                                             // 1. prep (all converts)
    PrepArgs p;
    p.roi = roi;   p.A_b = A_b;
    p.Wo1 = Wo1;   p.Wo1_b = Wo1_b;
    p.Wo2 = Wo2;   p.Wo2_b = Wo2_b;
    p.Wfc1 = Wfc1; p.Wfc1_t = Wfc1_t;
    p.wsrc[0] = Wfc2; p.wdst[0] = Wfc2_t;
    p.wsrc[1] = Wq1;  p.wdst[1] = Wq1_t;
    p.wsrc[2] = Wk1;  p.wdst[2] = Wk1_t;
    p.wsrc[3] = Wq2;  p.wdst[3] = Wq2_t;
    p.wsrc[4] = Wk2;  p.wdst[4] = Wk2_t;
    prep_kernel<<<20736, 256, 0, stream>>>(p);
  }
  // 2. fc1 split-K=4
  gemm8p<<<256, 512, 0, stream>>>(A_b, Wfc1_t, Pp);
  // 3. reduce || pos tables
  reduce_pos_kernel<<<6144, 256, 0, stream>>>(Pp, bfc1, xf, xb_f, bbox,
                                              Wpos1, Wpos2, bpos1, bpos2,
                                              logw1, logw2);
  // ---- layer 1 ----
  {
    GDesc q  = {xb_f,  Wq1_t, bq1, q_b,   nullptr, 4096, 1024, 1024, 1024, 8};
    GDesc kk = {xb_f,  Wk1_t, bk1, k_b,   nullptr,  300, 1024, 1024, 1024, 8};
    GDesc kv = {Wo1_b, xb_f,  nullptr, kvt_b, nullptr, 1024, 300, 1024, 320, 3};
    gemmU<<<304, 256, 0, stream>>>(q, kk, kv, 256, 280);
  }
  attn_kernel<false><<<dim3(64, 16), 256, 0, stream>>>(q_b, k_b, kvt_b, logw1, xf, bo1, nullptr, xb_a);

  // ---- layer 2 ----
  {
    GDesc fc = {xb_a, Wfc2_t, bfc2, xb_f, xf, 4096, 1024, 1024, 1024, 8};
    gemmU<<<256, 256, 0, stream>>>(fc, fc, fc, 256, 256);
  }
  {
    GDesc q  = {xb_f,  Wq2_t, bq2, q_b,   nullptr, 4096, 1024, 1024, 1024, 8};
    GDesc kk = {xb_f,  Wk2_t, bk2, k_b,   nullptr,  300, 1024, 1024, 1024, 8};
    GDesc kv = {Wo2_b, xb_f,  nullptr, kvt_b, nullptr, 1024, 300, 1024, 320, 3};
    gemmU<<<304, 256, 0, stream>>>(q, kk, kv, 256, 280);
  }
  attn_kernel<true><<<dim3(64, 16), 256, 0, stream>>>(q_b, k_b, kvt_b, logw2, xf, bo2, (float*)d_out, nullptr);
}

// Round 6
// 425.670 us; speedup vs baseline: 1.9474x; 1.0221x over previous
//
#include <hip/hip_runtime.h>

// ============================================================================
// FastRCNN Relation FC Head, MI355X round 6.
// vs round 5: (1) roi fp32->bf16 pre-convert ELIMINATED - gemm8p reads fp32
// roi directly with reg-staged convert (dense float4 loads -> f2bf ->
// swizzled ds_write_b64), B stays global_load_lds; single race-free
// barrier/tile (drain vmcnt(0)+lgkmcnt(0) before it).  (2) prep converts
// only weights, transposes vectorized (float4 read, u16x4 write).
// (3) attn drops K/KVt LDS staging (L2-resident, 64B-segment global frag
// reads); LDS 100KB -> 44KB -> 3 blocks/CU.  Workspace: 354 MB.
// ============================================================================

using bf16x8 = __attribute__((ext_vector_type(8))) short;
using u16x4  = __attribute__((ext_vector_type(4))) short;
using f32x4  = __attribute__((ext_vector_type(4))) float;
typedef unsigned short u16;
typedef unsigned int   u32;

#define DEV __device__ __forceinline__

DEV u16 f2bf(float f) {                      // fp32 -> bf16, round-nearest-even
  u32 u = __float_as_uint(f);
  return (u16)((u + 0x7FFFu + ((u >> 16) & 1u)) >> 16);
}
DEV float bf2f(u16 h) { return __uint_as_float(((u32)h) << 16); }

DEV f32x4 mfma16(bf16x8 a, bf16x8 b, f32x4 c) {
  return __builtin_amdgcn_mfma_f32_16x16x32_bf16(a, b, c, 0, 0, 0);
}
DEV void gload16(const u16* g, u16* l) {
  __builtin_amdgcn_global_load_lds((const __attribute__((address_space(1))) void*)g,
                                   (__attribute__((address_space(3))) void*)l, 16, 0, 0);
}

DEV void fsincos(float x, float* s, float* c) {
  float r = x * 0.15915494309189535f;   // revolutions, exact-identity reduction
  r -= rintf(r);
  float a = r * 6.283185307179586f;
  *s = __sinf(a); *c = __cosf(a);
}

// ---------------------------------------------------------------------------
// prep: weight converts/transposes only (roi handled inside gemm8p now).
//  [0,512)          Wo1 fp32->bf16     (1M elems, 1 iter/thread)
//  [512,1024)       Wo2 fp32->bf16
//  [1024,13568)     Wfc1 12544x1024 transpose+convert (32x32 tiles)
//  [13568,18688)    5x 1024x1024 transpose+convert (Wfc2,Wq1,Wk1,Wq2,Wk2)
// Transpose tile: float4 reads (16B/lane), u16x4 writes (8B/lane).
// ---------------------------------------------------------------------------
struct PrepArgs {
  const float* Wo1; u16* Wo1_b;
  const float* Wo2; u16* Wo2_b;
  const float* Wfc1; u16* Wfc1_t;
  const float* wsrc[5]; u16* wdst[5];
};

__global__ __launch_bounds__(256) void prep_kernel(PrepArgs p) {
  __shared__ float tp[32][36];
  int b = blockIdx.x, tid = threadIdx.x;
  if (b < 1024) {                               // plain converts (1024^2 each)
    const float* src = (b < 512) ? p.Wo1 : p.Wo2;
    u16* dst = (b < 512) ? p.Wo1_b : p.Wo2_b;
    size_t i = ((size_t)(b & 511) * 256 + tid) * 8;
    float4 a = *(const float4*)(src + i);
    float4 c = *(const float4*)(src + i + 4);
    bf16x8 v;
    v[0]=(short)f2bf(a.x); v[1]=(short)f2bf(a.y); v[2]=(short)f2bf(a.z); v[3]=(short)f2bf(a.w);
    v[4]=(short)f2bf(c.x); v[5]=(short)f2bf(c.y); v[6]=(short)f2bf(c.z); v[7]=(short)f2bf(c.w);
    *(bf16x8*)(dst + i) = v;
    return;
  }
  const float* in; u16* out; int r0, c0, R, C;
  if (b < 13568) {
    int idx = b - 1024;
    in = p.Wfc1; out = p.Wfc1_t; R = 12544; C = 1024;
    r0 = (idx >> 5) * 32; c0 = (idx & 31) * 32;
  } else {
    int idx = b - 13568;
    int z = idx >> 10, rest = idx & 1023;
    in = p.wsrc[z]; out = p.wdst[z]; R = 1024; C = 1024;
    r0 = (rest >> 5) * 32; c0 = (rest & 31) * 32;
  }
  {                                             // 32x32 vectorized transpose
    int r = tid >> 3, c4 = (tid & 7) * 4;
    float4 v = *(const float4*)(in + (size_t)(r0 + r) * C + c0 + c4);
    *(float4*)&tp[r][c4] = v;
  }
  __syncthreads();
  {
    int c = tid >> 3, r4 = (tid & 7) * 4;
    u16x4 o;
    o[0] = (short)f2bf(tp[r4 + 0][c]); o[1] = (short)f2bf(tp[r4 + 1][c]);
    o[2] = (short)f2bf(tp[r4 + 2][c]); o[3] = (short)f2bf(tp[r4 + 3][c]);
    *(u16x4*)(out + (size_t)(c0 + c) * R + r0 + r4) = o;
  }
}

// ---------------------------------------------------------------------------
// fc1: 256x256-tile MFMA GEMM, BK=64, 512 threads, splitK=4.  A read as
// FP32 (roi) with reg-staging (8 dense float4 loads -> cvt -> swizzled
// ds_write_b64); B bf16 via global_load_lds (pre-swizzled source).
// Per tile: issue A-regs(t+1)+B-DMA(t+1) -> compute 4 quadrants from buf[t]
// -> cvt+ds_write A(t+1) -> vmcnt(0)+lgkmcnt(0) -> ONE barrier.
// Race-free: buf[(t+1)&1] was last read at t-1, whose reads completed
// before t-1's drain+barrier.
// ---------------------------------------------------------------------------
__global__ __launch_bounds__(512, 2) void gemm8p(
    const float* __restrict__ A, const u16* __restrict__ Bt,
    float* __restrict__ P) {
  const int K = 12544;                 // 4 splits x 49 tiles x BK=64
  __shared__ u16 lds[65536];           // 2 buf x (A 32KB + B 32KB) = 128 KB
  int tid = threadIdx.x;
  int w = tid >> 6, l = tid & 63, h = l >> 4, l15 = l & 15;
  int wm = w >> 2, wn = w & 3;

  int b = ((blockIdx.x & 7) << 5) | (blockIdx.x >> 3);   // XCD-chunked swizzle
  int bz = b >> 6, rest = b & 63;
  int bm = (rest & 15) * 256;
  int bn = (rest >> 4) * 256;
  size_t k0 = (size_t)bz * 3136;

  // ---- A fp32 reg-staging: seg s in [0,4): row = s*64 + (tid>>3),
  //      cols c0e..c0e+3 and 32+c0e..35  (two dense float4 per segment)
  int arow = tid >> 3;
  int c0e = (tid & 7) * 4;
  const float* pA0 = A + (size_t)(bm + arow) * K + k0 + c0e;
  const float* pA1 = pA0 + 32;
  const size_t aseg = (size_t)64 * K;
  int awe0 = ((arow * 128 + c0e * 2) ^ ((arow & 7) << 4)) >> 1;        // elems
  int awe1 = ((arow * 128 + 64 + c0e * 2) ^ ((arow & 7) << 4)) >> 1;

  // ---- B staging: pre-swizzled per-lane global source, gload16 x4
  int X = ((tid >> 3) & 7) << 4;
  int lb2 = (tid * 16) ^ X;
  int lr = lb2 >> 7, lc = (lb2 & 127) >> 1;
  const u16* pB = Bt + (size_t)(bn + lr) * K + k0 + lc;
  const size_t o64 = (size_t)64 * K, o128 = (size_t)128 * K, o192 = (size_t)192 * K;

  // ds_read swizzled per-lane offsets (loop-invariant)
  int swz = (l15 & 7) << 3;
  int xk0 = (h * 8) ^ swz;
  int xk1 = 32 ^ xk0;
  int rA = (wm * 64 + l15) * 64;
  int rB = (wn * 32 + l15) * 64;

  f32x4 acc[8][4];
#pragma unroll
  for (int i = 0; i < 8; i++)
#pragma unroll
    for (int j = 0; j < 4; j++) acc[i][j] = (f32x4){0.f, 0.f, 0.f, 0.f};

  float4 a0[4], a1[4];
  bf16x8 af[4][2], bl[2][2], bh[2][2];

#define AISSUE(kk) { _Pragma("unroll") for (int s = 0; s < 4; s++) {     \
    a0[s] = *(const float4*)(pA0 + s * aseg + (kk));                     \
    a1[s] = *(const float4*)(pA1 + s * aseg + (kk)); } }
#define BISSUE(WB, kk) {                                                 \
    gload16(pB + (kk),        (WB) + tid * 8);                           \
    gload16(pB + o64 + (kk),  (WB) + 4096 + tid * 8);                    \
    gload16(pB + o128 + (kk), (WB) + 8192 + tid * 8);                    \
    gload16(pB + o192 + (kk), (WB) + 12288 + tid * 8); }
#define AWRITE(WA) { _Pragma("unroll") for (int s = 0; s < 4; s++) {     \
    u16x4 v0, v1;                                                        \
    v0[0]=(short)f2bf(a0[s].x); v0[1]=(short)f2bf(a0[s].y);              \
    v0[2]=(short)f2bf(a0[s].z); v0[3]=(short)f2bf(a0[s].w);              \
    v1[0]=(short)f2bf(a1[s].x); v1[1]=(short)f2bf(a1[s].y);              \
    v1[2]=(short)f2bf(a1[s].z); v1[3]=(short)f2bf(a1[s].w);              \
    *(u16x4*)&(WA)[awe0 + s * 4096] = v0;                                \
    *(u16x4*)&(WA)[awe1 + s * 4096] = v1; } }
#define READ_AF(BASE)                                                    \
  _Pragma("unroll") for (int i = 0; i < 4; i++) {                        \
    af[i][0] = *(const bf16x8*)&LA[(BASE) + rA + i * 1024 + xk0];        \
    af[i][1] = *(const bf16x8*)&LA[(BASE) + rA + i * 1024 + xk1];        \
  }
#define Q_MFMA(QR, QC, BF)                                               \
  __builtin_amdgcn_s_setprio(1);                                         \
  _Pragma("unroll") for (int i = 0; i < 4; i++)                          \
    _Pragma("unroll") for (int j = 0; j < 2; j++) {                      \
      acc[(QR)*4+i][(QC)*2+j] = mfma16(af[i][0], BF[j][0], acc[(QR)*4+i][(QC)*2+j]); \
      acc[(QR)*4+i][(QC)*2+j] = mfma16(af[i][1], BF[j][1], acc[(QR)*4+i][(QC)*2+j]); \
    }                                                                    \
  __builtin_amdgcn_s_setprio(0);

  // prologue: tile 0 -> buf0
  AISSUE(0);
  BISSUE(lds + 16384, 0);
  AWRITE(lds);                          // compiler inserts vmcnt(4) for a-regs
  asm volatile("s_waitcnt vmcnt(0) lgkmcnt(0)" ::: "memory");
  __builtin_amdgcn_s_barrier();

  for (int t = 0; t < 49; t++) {
    const u16* LA = lds + (t & 1) * 32768;
    const u16* LB = LA + 16384;
    u16* WA = lds + ((t + 1) & 1) * 32768;
    u16* WB = WA + 16384;
    if (t < 48) {
      int ktn = (t + 1) * 64;
      AISSUE(ktn);
      BISSUE(WB, ktn);
    }
    __builtin_amdgcn_sched_barrier(0);
    READ_AF(0);
#pragma unroll
    for (int j = 0; j < 2; j++) {
      bl[j][0] = *(const bf16x8*)&LB[rB + j * 1024 + xk0];
      bl[j][1] = *(const bf16x8*)&LB[rB + j * 1024 + xk1];
    }
    Q_MFMA(0, 0, bl);
    __builtin_amdgcn_sched_barrier(0);
#pragma unroll
    for (int j = 0; j < 2; j++) {
      bh[j][0] = *(const bf16x8*)&LB[8192 + rB + j * 1024 + xk0];
      bh[j][1] = *(const bf16x8*)&LB[8192 + rB + j * 1024 + xk1];
    }
    Q_MFMA(0, 1, bh);
    __builtin_amdgcn_sched_barrier(0);
    READ_AF(8192);
    Q_MFMA(1, 1, bh);
    __builtin_amdgcn_sched_barrier(0);
    Q_MFMA(1, 0, bl);
    __builtin_amdgcn_sched_barrier(0);
    if (t < 48) { AWRITE(WA); }
    asm volatile("s_waitcnt vmcnt(0) lgkmcnt(0)" ::: "memory");
    __builtin_amdgcn_sched_barrier(0);
    __builtin_amdgcn_s_barrier();       // buf[(t+1)&1] fully staged; all reads
  }                                     // of it (from t-1) long since drained
#undef AISSUE
#undef BISSUE
#undef AWRITE
#undef READ_AF
#undef Q_MFMA

  float* dst = P + (size_t)bz * 4096 * 1024;
#pragma unroll
  for (int qr = 0; qr < 2; qr++)
#pragma unroll
    for (int i = 0; i < 4; i++)
#pragma unroll
      for (int qc = 0; qc < 2; qc++)
#pragma unroll
        for (int j = 0; j < 2; j++) {
          int row0 = bm + qr * 128 + wm * 64 + i * 16 + h * 4;
          int col  = bn + qc * 128 + wn * 32 + j * 16 + l15;
          f32x4 v = acc[qr * 4 + i][qc * 2 + j];
#pragma unroll
          for (int r = 0; r < 4; r++)
            dst[(size_t)(row0 + r) * 1024 + col] = v[r];
        }
}

// ---------------------------------------------------------------------------
// fc_reduce (blocks [0,2048)) || pos_logw (blocks [2048,6144)) in one launch.
// ---------------------------------------------------------------------------
__constant__ float C100D[8] = {100.f, 42.16965034285822f, 17.78279410038923f,
                               7.498942093324559f, 3.1622776601683795f,
                               1.333521432163324f, 0.5623413251903491f,
                               0.23713737056616552f};

__global__ __launch_bounds__(256) void reduce_pos_kernel(
    const float* __restrict__ P, const float* __restrict__ bias,
    float* __restrict__ xf, u16* __restrict__ xb,
    const float* __restrict__ bbox,
    const float* __restrict__ Wpos1, const float* __restrict__ Wpos2,
    const float* __restrict__ bpos1, const float* __restrict__ bpos2,
    u16* __restrict__ logw1, u16* __restrict__ logw2) {
  __shared__ u16 pool[18944];     // emb 64*88 | wp 32*88 | lw 2*16*328
  int tid = threadIdx.x;
  if (blockIdx.x < 2048) {        // ---- fc1 split-K reduce ----
    const size_t MN = (size_t)4096 * 1024;
    size_t i = ((size_t)blockIdx.x * 256 + tid) * 4;
    size_t stride = (size_t)2048 * 256 * 4;
    for (; i < MN; i += stride) {
      float4 a = *(const float4*)(P + i);
      float4 b = *(const float4*)(P + MN + i);
      float4 c = *(const float4*)(P + 2 * MN + i);
      float4 d = *(const float4*)(P + 3 * MN + i);
      float4 bv = *(const float4*)(bias + (i & 1023));
      float4 r;
      r.x = a.x + b.x + c.x + d.x + bv.x;
      r.y = a.y + b.y + c.y + d.y + bv.y;
      r.z = a.z + b.z + c.z + d.z + bv.z;
      r.w = a.w + b.w + c.w + d.w + bv.w;
      *(float4*)(xf + i) = r;
      u16x4 hv;
      hv[0] = (short)f2bf(r.x); hv[1] = (short)f2bf(r.y);
      hv[2] = (short)f2bf(r.z); hv[3] = (short)f2bf(r.w);
      *(u16x4*)(xb + i) = hv;
    }
    return;
  }
  // ---- pos_logw ----
  u16* emb_s = pool;              // [64][88]
  u16* wp_s  = pool + 5632;       // [32][88]
  u16* lw_s  = pool + 8448;       // [2*16][328]
  int n = blockIdx.x - 2048;
  int w = tid >> 6, l = tid & 63, h = l >> 4, l15 = l & 15;
  for (int idx = tid; idx < 1024; idx += 256) {   // stage Wpos^T both layers
    int e = idx >> 4, c = idx & 15;               // Wpos[e][c], EMB=64 GROUP=16
    wp_s[c * 88 + e]        = f2bf(Wpos1[idx]);
    wp_s[(16 + c) * 88 + e] = f2bf(Wpos2[idx]);
  }
  float4 bn = ((const float4*)bbox)[n];
  float bw_n = bn.z - bn.x + 1.f, bh_n = bn.w - bn.y + 1.f;
  float cx_n = 0.5f * (bn.x + bn.z), cy_n = 0.5f * (bn.y + bn.w);
  float bps0 = bpos1[l15], bps1 = bpos2[l15];
  int p = tid >> 2, k = tid & 3;

  for (int m0 = 0; m0 < 320; m0 += 64) {
    int m = m0 + p;
    float4 bm = ((const float4*)bbox)[m];
    float v;
    if (k == 0)      v = logf(fmaxf(fabsf((cx_n - 0.5f * (bm.x + bm.z)) / bw_n), 1e-3f));
    else if (k == 1) v = logf(fmaxf(fabsf((cy_n - 0.5f * (bm.y + bm.w)) / bh_n), 1e-3f));
    else if (k == 2) v = logf(bw_n / (bm.z - bm.x + 1.f));
    else             v = logf(bh_n / (bm.w - bm.y + 1.f));
    __syncthreads();                      // protect previous tile's frag reads
#pragma unroll
    for (int tt = 0; tt < 8; tt++) {
      float s, c; fsincos(v * C100D[tt], &s, &c);
      emb_s[p * 88 + k * 16 + tt]     = f2bf(s);
      emb_s[p * 88 + k * 16 + 8 + tt] = f2bf(c);
    }
    __syncthreads();
    f32x4 acc0 = {0.f, 0.f, 0.f, 0.f}, acc1 = {0.f, 0.f, 0.f, 0.f};
    bf16x8 a0 = *(const bf16x8*)&emb_s[(w * 16 + l15) * 88 + h * 8];
    bf16x8 a1 = *(const bf16x8*)&emb_s[(w * 16 + l15) * 88 + 32 + h * 8];
    bf16x8 b00 = *(const bf16x8*)&wp_s[l15 * 88 + h * 8];
    bf16x8 b01 = *(const bf16x8*)&wp_s[l15 * 88 + 32 + h * 8];
    bf16x8 b10 = *(const bf16x8*)&wp_s[(16 + l15) * 88 + h * 8];
    bf16x8 b11 = *(const bf16x8*)&wp_s[(16 + l15) * 88 + 32 + h * 8];
    acc0 = mfma16(a0, b00, acc0); acc0 = mfma16(a1, b01, acc0);
    acc1 = mfma16(a0, b10, acc1); acc1 = mfma16(a1, b11, acc1);
#pragma unroll
    for (int r = 0; r < 4; r++) {
      int mm = m0 + w * 16 + h * 4 + r;
      lw_s[l15 * 328 + mm]        = f2bf(logf(fmaxf(acc0[r] + bps0, 1e-6f)));
      lw_s[(16 + l15) * 328 + mm] = f2bf(logf(fmaxf(acc1[r] + bps1, 1e-6f)));
    }
  }
  __syncthreads();
  for (int i = tid; i < 1280; i += 256) {       // 2 layers * 16 g * 40 segs
    int layer = i / 640, rest = i - layer * 640;
    int gg = rest / 40, seg = rest - gg * 40;
    bf16x8 v = *(const bf16x8*)&lw_s[(layer * 16 + gg) * 328 + seg * 8];
    u16* dst = (layer ? logw2 : logw1) + ((size_t)gg * 4096 + n) * 320 + seg * 8;
    *(bf16x8*)dst = v;
  }
}

// ---------------------------------------------------------------------------
// gemmU: 128x128-tile BK=64 pipelined GEMM (single wait/tile, 64KB LDS ->
// 2 blocks/CU), up to 3 problems per grid.  C = A[MxK]*Bt[NxK]^T (+bias).
// ---------------------------------------------------------------------------
struct GDesc {
  const u16* A; const u16* Bt; const float* bias;
  u16* Cb; float* Cf;
  int M, N, K, ldc, nt;          // nt = #128-wide col tiles
};

__global__ __launch_bounds__(256, 2) void gemmU(GDesc g0, GDesc g1, GDesc g2,
                                                int c0, int c1) {
  __shared__ u16 lds[32768];     // 2 buf x (A 128x64 + B 128x64) bf16 = 64 KB
  GDesc g; int lb = blockIdx.x;
  if (lb < c0) { g = g0; lb = (lb & 7) * (c0 >> 3) + (lb >> 3); }  // XCD swz
  else if (lb < c1) { g = g1; lb -= c0; }
  else { g = g2; lb -= c1; }
  int bm = (lb / g.nt) * 128, bn = (lb % g.nt) * 128;
  int tid = threadIdx.x;
  int w = tid >> 6, l = tid & 63, h = l >> 4, l15 = l & 15;
  int wm = w >> 1, wn = w & 1;
  int K = g.K;

  int X = ((tid >> 3) & 7) << 4;
  int lbyte = (tid * 16) ^ X;
  int lr = lbyte >> 7, lc = (lbyte & 127) >> 1;
  const u16 *pa[4], *pb[4];
#pragma unroll
  for (int c = 0; c < 4; c++) {
    pa[c] = g.A  + (size_t)min(bm + c * 32 + lr, g.M - 1) * K + lc;
    pb[c] = g.Bt + (size_t)min(bn + c * 32 + lr, g.N - 1) * K + lc;
  }

  int swz = (l15 & 7) << 3;
  int xk0 = (h * 8) ^ swz;
  int xk1 = 32 ^ xk0;
  int rA = (wm * 64 + l15) * 64;
  int rB = (wn * 64 + l15) * 64;

  f32x4 acc[4][4];
#pragma unroll
  for (int i = 0; i < 4; i++)
#pragma unroll
    for (int j = 0; j < 4; j++) acc[i][j] = (f32x4){0.f, 0.f, 0.f, 0.f};

#define ISSUEU(W, kk)                                     \
  { gload16(pa[0] + (kk), (W) + tid * 8);                 \
    gload16(pa[1] + (kk), (W) + 2048 + tid * 8);          \
    gload16(pa[2] + (kk), (W) + 4096 + tid * 8);          \
    gload16(pa[3] + (kk), (W) + 6144 + tid * 8);          \
    gload16(pb[0] + (kk), (W) + 8192 + tid * 8);          \
    gload16(pb[1] + (kk), (W) + 10240 + tid * 8);         \
    gload16(pb[2] + (kk), (W) + 12288 + tid * 8);         \
    gload16(pb[3] + (kk), (W) + 14336 + tid * 8); }

  ISSUEU(lds, 0);
  int ktiles = K >> 6;
  for (int t = 0; t < ktiles; t++) {
    const u16* LA = lds + (t & 1) * 16384;
    const u16* LB = LA + 8192;
    u16* W = lds + ((t ^ 1) & 1) * 16384;
    if (t < ktiles - 1) {
      ISSUEU(W, (t + 1) * 64);
      asm volatile("s_waitcnt vmcnt(8)" ::: "memory");
    } else {
      asm volatile("s_waitcnt vmcnt(0)" ::: "memory");
    }
    __builtin_amdgcn_s_barrier();
    asm volatile("" ::: "memory");
    bf16x8 a[4][2], bfr[4][2];
#pragma unroll
    for (int i = 0; i < 4; i++) {
      a[i][0] = *(const bf16x8*)&LA[rA + i * 1024 + xk0];
      a[i][1] = *(const bf16x8*)&LA[rA + i * 1024 + xk1];
    }
#pragma unroll
    for (int j = 0; j < 4; j++) {
      bfr[j][0] = *(const bf16x8*)&LB[rB + j * 1024 + xk0];
      bfr[j][1] = *(const bf16x8*)&LB[rB + j * 1024 + xk1];
    }
    __builtin_amdgcn_s_setprio(1);
#pragma unroll
    for (int i = 0; i < 4; i++)
#pragma unroll
      for (int j = 0; j < 4; j++) {
        acc[i][j] = mfma16(a[i][0], bfr[j][0], acc[i][j]);
        acc[i][j] = mfma16(a[i][1], bfr[j][1], acc[i][j]);
      }
    __builtin_amdgcn_s_setprio(0);
    asm volatile("" ::: "memory");
    __builtin_amdgcn_s_barrier();
  }
#undef ISSUEU

#pragma unroll
  for (int i = 0; i < 4; i++) {
#pragma unroll
    for (int j = 0; j < 4; j++) {
      int col = bn + wn * 64 + j * 16 + l15;
      if (col >= g.ldc) continue;
      float bv = (g.bias != nullptr && col < g.N) ? g.bias[col] : 0.f;
      int row0 = bm + wm * 64 + i * 16 + h * 4;
#pragma unroll
      for (int r = 0; r < 4; r++) {
        int row = row0 + r;
        if (row >= g.M) continue;
        float v = acc[i][j][r] + bv;
        size_t off = (size_t)row * g.ldc + col;
        g.Cb[off] = f2bf(v);
        if (g.Cf != nullptr) g.Cf[off] = v;
      }
    }
  }
}

// ---------------------------------------------------------------------------
// fused attention per (64-row n-tile, head g).  No K/KVt LDS staging (both
// L2-resident; 64B-segment global frag reads).  LDS = logw[64][328] then
// P[64][344] (union, 44KB) -> 3 blocks/CU.
// ---------------------------------------------------------------------------
template <bool LAST>
__global__ __launch_bounds__(256) void attn_kernel(
    const u16* __restrict__ qb, const u16* __restrict__ kb,
    const u16* __restrict__ kvt, const u16* __restrict__ logw,
    const float* __restrict__ xf, const float* __restrict__ bo,
    float* __restrict__ outf, u16* __restrict__ outb) {
  __shared__ u16 ps[64 * 344];      // logw [64][328]; then P [64][344]
  int tid = threadIdx.x;
  int g = blockIdx.y, n0 = blockIdx.x * 64;
  int w = tid >> 6, l = tid & 63, h = l >> 4, l15 = l & 15;

  {                                 // stage logw tile (contiguous 40KB)
    const u16* src = logw + ((size_t)g * 4096 + n0) * 320;
    for (int i = tid; i < 64 * 40; i += 256) {
      int row = i / 40, seg = i - row * 40;
      *(bf16x8*)&ps[row * 328 + seg * 8] = *(const bf16x8*)(src + row * 320 + seg * 8);
    }
  }
  int nrow = n0 + w * 16 + l15;
  const u16* qp = qb + (size_t)nrow * 1024 + g * 64;
  bf16x8 aq0 = *(const bf16x8*)(qp + h * 8);
  bf16x8 aq1 = *(const bf16x8*)(qp + 32 + h * 8);

  f32x4 acc[19];
#pragma unroll
  for (int f = 0; f < 19; f++) acc[f] = (f32x4){0.f, 0.f, 0.f, 0.f};
  const u16* kp = kb + g * 64 + h * 8;
#pragma unroll
  for (int f = 0; f < 19; f++) {      // QK^T, K frags direct from global (L2)
    bf16x8 b0 = *(const bf16x8*)(kp + (size_t)(f * 16 + l15) * 1024);
    bf16x8 b1 = *(const bf16x8*)(kp + (size_t)(f * 16 + l15) * 1024 + 32);
    acc[f] = mfma16(aq0, b0, acc[f]);
    acc[f] = mfma16(aq1, b1, acc[f]);
  }
  __syncthreads();                    // logw staged

  int nbase = n0 + w * 16 + h * 4;
  int lrow = w * 16 + h * 4;
  float mx[4] = {-INFINITY, -INFINITY, -INFINITY, -INFINITY};
  float sm[4] = {0.f, 0.f, 0.f, 0.f};
#pragma unroll
  for (int f = 0; f < 19; f++) {
    int m = f * 16 + l15;
#pragma unroll
    for (int r = 0; r < 4; r++) {
      float lw = -INFINITY;
      if (m < 300) lw = bf2f(ps[(lrow + r) * 328 + m]);
      float lg = acc[f][r] * 0.125f + lw;
      acc[f][r] = lg;
      mx[r] = fmaxf(mx[r], lg);
    }
  }
#pragma unroll
  for (int d = 1; d < 16; d <<= 1)
#pragma unroll
    for (int r = 0; r < 4; r++) mx[r] = fmaxf(mx[r], __shfl_xor(mx[r], d));
#pragma unroll
  for (int f = 0; f < 19; f++)
#pragma unroll
    for (int r = 0; r < 4; r++) {
      float p = __expf(acc[f][r] - mx[r]);
      acc[f][r] = p; sm[r] += p;
    }
#pragma unroll
  for (int d = 1; d < 16; d <<= 1)
#pragma unroll
    for (int r = 0; r < 4; r++) sm[r] += __shfl_xor(sm[r], d);
  float inv[4];
#pragma unroll
  for (int r = 0; r < 4; r++) inv[r] = 1.f / sm[r];

  __syncthreads();                    // all waves done reading logw
#pragma unroll
  for (int f = 0; f < 19; f++)
#pragma unroll
    for (int r = 0; r < 4; r++)
      ps[(lrow + r) * 344 + f * 16 + l15] = f2bf(acc[f][r]);
#pragma unroll
  for (int r = 0; r < 4; r++)         // zero pad m 304..319
    ps[(lrow + r) * 344 + 304 + l15] = 0;

  f32x4 acc2[4];
#pragma unroll
  for (int fo = 0; fo < 4; fo++) acc2[fo] = (f32x4){0.f, 0.f, 0.f, 0.f};
  const u16* vp = kvt + (size_t)g * 64 * 320 + h * 8;
#pragma unroll
  for (int ks = 0; ks < 10; ks++) {   // PV: P rows are wave-local; KVt global
    bf16x8 ap = *(const bf16x8*)&ps[(w * 16 + l15) * 344 + ks * 32 + h * 8];
#pragma unroll
    for (int fo = 0; fo < 4; fo++) {
      bf16x8 bv = *(const bf16x8*)(vp + (size_t)(fo * 16 + l15) * 320 + ks * 32);
      acc2[fo] = mfma16(ap, bv, acc2[fo]);
    }
  }
#pragma unroll
  for (int fo = 0; fo < 4; fo++) {
    int col = g * 64 + fo * 16 + l15;
    float bov = bo[col];
#pragma unroll
    for (int r = 0; r < 4; r++) {
      int row = nbase + r;
      float v = xf[(size_t)row * 1024 + col] + acc2[fo][r] * inv[r] + bov;
      v = fmaxf(v, 0.f);
      if (LAST) outf[(size_t)row * 1024 + col] = v;
      else      outb[(size_t)row * 1024 + col] = f2bf(v);
    }
  }
}

// ---------------------------------------------------------------------------
extern "C" void kernel_launch(void* const* d_in, const int* in_sizes, int n_in,
                              void* d_out, int out_size, void* d_ws, size_t ws_size,
                              hipStream_t stream) {
  (void)in_sizes; (void)n_in; (void)out_size; (void)ws_size;
  const float* roi   = (const float*)d_in[0];
  const float* bbox  = (const float*)d_in[1];
  const float* Wfc1  = (const float*)d_in[2];
  const float* bfc1  = (const float*)d_in[3];
  const float* Wfc2  = (const float*)d_in[4];
  const float* bfc2  = (const float*)d_in[5];
  const float* Wpos1 = (const float*)d_in[6];
  const float* bpos1 = (const float*)d_in[7];
  const float* Wq1   = (const float*)d_in[8];
  const float* bq1   = (const float*)d_in[9];
  const float* Wk1   = (const float*)d_in[10];
  const float* bk1   = (const float*)d_in[11];
  const float* Wo1   = (const float*)d_in[12];
  const float* bo1   = (const float*)d_in[13];
  const float* Wpos2 = (const float*)d_in[14];
  const float* bpos2 = (const float*)d_in[15];
  const float* Wq2   = (const float*)d_in[16];
  const float* bq2   = (const float*)d_in[17];
  const float* Wk2   = (const float*)d_in[18];
  const float* bk2   = (const float*)d_in[19];
  const float* Wo2   = (const float*)d_in[20];
  const float* bo2   = (const float*)d_in[21];

  char* ws = (char*)d_ws;                       // ---- workspace arena ----
  u16*  Wfc1_t = (u16*)(ws + 102760448);        //  25,690,112
  u16*  Wfc2_t = (u16*)(ws + 128450560);        //   2,097,152 each
  u16*  Wq1_t  = (u16*)(ws + 130547712);
  u16*  Wk1_t  = (u16*)(ws + 132644864);
  u16*  Wq2_t  = (u16*)(ws + 134742016);
  u16*  Wk2_t  = (u16*)(ws + 136839168);
  u16*  Wo1_b  = (u16*)(ws + 138936320);
  u16*  Wo2_b  = (u16*)(ws + 141033472);
  float* Pp    = (float*)(ws + 143134720);      //  67,108,864 (splitK partials)
  float* xf    = (float*)(ws + 227020800);      //  16,777,216
  u16*  xb_f   = (u16*)(ws + 243798016);        //   8,388,608 (fc out, bf16)
  u16*  xb_a   = (u16*)(ws + 252186624);        //   8,388,608 (attn out, bf16)
  u16*  q_b    = (u16*)(ws + 260575232);        //   8,388,608
  u16*  k_b    = (u16*)(ws + 268963840);        //     614,400
  u16*  kvt_b  = (u16*)(ws + 269578240);        //     655,360
  u16*  logw1  = (u16*)(ws + 270233600);        //  41,943,040
  u16*  logw2  = (u16*)(ws + 312176640);        //  41,943,040 (end 354,119,680)

  {                                             // 1. prep (weight converts)
    PrepArgs p;
    p.Wo1 = Wo1;   p.Wo1_b = Wo1_b;
    p.Wo2 = Wo2;   p.Wo2_b = Wo2_b;
    p.Wfc1 = Wfc1; p.Wfc1_t = Wfc1_t;
    p.wsrc[0] = Wfc2; p.wdst[0] = Wfc2_t;
    p.wsrc[1] = Wq1;  p.wdst[1] = Wq1_t;
    p.wsrc[2] = Wk1;  p.wdst[2] = Wk1_t;
    p.wsrc[3] = Wq2;  p.wdst[3] = Wq2_t;
    p.wsrc[4] = Wk2;  p.wdst[4] = Wk2_t;
    prep_kernel<<<18688, 256, 0, stream>>>(p);
  }
  // 2. fc1 split-K=4 (reads fp32 roi directly)
  gemm8p<<<256, 512, 0, stream>>>(roi, Wfc1_t, Pp);
  // 3. reduce || pos tables
  reduce_pos_kernel<<<6144, 256, 0, stream>>>(Pp, bfc1, xf, xb_f, bbox,
                                              Wpos1, Wpos2, bpos1, bpos2,
                                              logw1, logw2);
  // ---- layer 1 ----
  {
    GDesc q  = {xb_f,  Wq1_t, bq1, q_b,   nullptr, 4096, 1024, 1024, 1024, 8};
    GDesc kk = {xb_f,  Wk1_t, bk1, k_b,   nullptr,  300, 1024, 1024, 1024, 8};
    GDesc kv = {Wo1_b, xb_f,  nullptr, kvt_b, nullptr, 1024, 300, 1024, 320, 3};
    gemmU<<<304, 256, 0, stream>>>(q, kk, kv, 256, 280);
  }
  attn_kernel<false><<<dim3(64, 16), 256, 0, stream>>>(q_b, k_b, kvt_b, logw1, xf, bo1, nullptr, xb_a);

  // ---- layer 2 ----
  {
    GDesc fc = {xb_a, Wfc2_t, bfc2, xb_f, xf, 4096, 1024, 1024, 1024, 8};
    gemmU<<<256, 256, 0, stream>>>(fc, fc, fc, 256, 256);
  }
  {
    GDesc q  = {xb_f,  Wq2_t, bq2, q_b,   nullptr, 4096, 1024, 1024, 1024, 8};
    GDesc kk = {xb_f,  Wk2_t, bk2, k_b,   nullptr,  300, 1024, 1024, 1024, 8};
    GDesc kv = {Wo2_b, xb_f,  nullptr, kvt_b, nullptr, 1024, 300, 1024, 320, 3};
    gemmU<<<304, 256, 0, stream>>>(q, kk, kv, 256, 280);
  }
  attn_kernel<true><<<dim3(64, 16), 256, 0, stream>>>(q_b, k_b, kvt_b, logw2, xf, bo2, (float*)d_out, nullptr);
}

// Round 7
// 409.594 us; speedup vs baseline: 2.0238x; 1.0392x over previous
//
#include <hip/hip_runtime.h>

// ============================================================================
// FastRCNN Relation FC Head, MI355X round 7.
// vs round 6: gemm8p schedule fixed - counted vmcnt (never drains to 0 in
// steady state), loads span a full K-tile:
//   ph0: issue A(t+1) glb x8; vmcnt(10)+lgkmcnt(0); bar; Q00   (16 MFMA)
//   ph1: issue B(t+1)lo DMA x2; vmcnt(10); bar;      Q01        (16 MFMA)
//   ph2: issue B(t+1)hi DMA x2;                      Q11+Q10    (32 MFMA)
//   ph3: AWRITE(t+1) (compiler-inserted vmcnt(4) for A regs)
// A-writes are contiguous ds_write_b128 (lane owns 8 consecutive cols),
// conflict-free under the XOR swizzle.  Everything else = round 6.
// Workspace: 354 MB.
// ============================================================================

using bf16x8 = __attribute__((ext_vector_type(8))) short;
using u16x4  = __attribute__((ext_vector_type(4))) short;
using f32x4  = __attribute__((ext_vector_type(4))) float;
typedef unsigned short u16;
typedef unsigned int   u32;

#define DEV __device__ __forceinline__

DEV u16 f2bf(float f) {                      // fp32 -> bf16, round-nearest-even
  u32 u = __float_as_uint(f);
  return (u16)((u + 0x7FFFu + ((u >> 16) & 1u)) >> 16);
}
DEV float bf2f(u16 h) { return __uint_as_float(((u32)h) << 16); }

DEV f32x4 mfma16(bf16x8 a, bf16x8 b, f32x4 c) {
  return __builtin_amdgcn_mfma_f32_16x16x32_bf16(a, b, c, 0, 0, 0);
}
DEV void gload16(const u16* g, u16* l) {
  __builtin_amdgcn_global_load_lds((const __attribute__((address_space(1))) void*)g,
                                   (__attribute__((address_space(3))) void*)l, 16, 0, 0);
}

DEV void fsincos(float x, float* s, float* c) {
  float r = x * 0.15915494309189535f;   // revolutions, exact-identity reduction
  r -= rintf(r);
  float a = r * 6.283185307179586f;
  *s = __sinf(a); *c = __cosf(a);
}

// ---------------------------------------------------------------------------
// prep: weight converts/transposes only.
//  [0,512) Wo1, [512,1024) Wo2 fp32->bf16; [1024,13568) Wfc1 T;
//  [13568,18688) 5x 1024^2 T (Wfc2,Wq1,Wk1,Wq2,Wk2).
// ---------------------------------------------------------------------------
struct PrepArgs {
  const float* Wo1; u16* Wo1_b;
  const float* Wo2; u16* Wo2_b;
  const float* Wfc1; u16* Wfc1_t;
  const float* wsrc[5]; u16* wdst[5];
};

__global__ __launch_bounds__(256) void prep_kernel(PrepArgs p) {
  __shared__ float tp[32][36];
  int b = blockIdx.x, tid = threadIdx.x;
  if (b < 1024) {                               // plain converts (1024^2 each)
    const float* src = (b < 512) ? p.Wo1 : p.Wo2;
    u16* dst = (b < 512) ? p.Wo1_b : p.Wo2_b;
    size_t i = ((size_t)(b & 511) * 256 + tid) * 8;
    float4 a = *(const float4*)(src + i);
    float4 c = *(const float4*)(src + i + 4);
    bf16x8 v;
    v[0]=(short)f2bf(a.x); v[1]=(short)f2bf(a.y); v[2]=(short)f2bf(a.z); v[3]=(short)f2bf(a.w);
    v[4]=(short)f2bf(c.x); v[5]=(short)f2bf(c.y); v[6]=(short)f2bf(c.z); v[7]=(short)f2bf(c.w);
    *(bf16x8*)(dst + i) = v;
    return;
  }
  const float* in; u16* out; int r0, c0, R, C;
  if (b < 13568) {
    int idx = b - 1024;
    in = p.Wfc1; out = p.Wfc1_t; R = 12544; C = 1024;
    r0 = (idx >> 5) * 32; c0 = (idx & 31) * 32;
  } else {
    int idx = b - 13568;
    int z = idx >> 10, rest = idx & 1023;
    in = p.wsrc[z]; out = p.wdst[z]; R = 1024; C = 1024;
    r0 = (rest >> 5) * 32; c0 = (rest & 31) * 32;
  }
  {                                             // 32x32 vectorized transpose
    int r = tid >> 3, c4 = (tid & 7) * 4;
    float4 v = *(const float4*)(in + (size_t)(r0 + r) * C + c0 + c4);
    *(float4*)&tp[r][c4] = v;
  }
  __syncthreads();
  {
    int c = tid >> 3, r4 = (tid & 7) * 4;
    u16x4 o;
    o[0] = (short)f2bf(tp[r4 + 0][c]); o[1] = (short)f2bf(tp[r4 + 1][c]);
    o[2] = (short)f2bf(tp[r4 + 2][c]); o[3] = (short)f2bf(tp[r4 + 3][c]);
    *(u16x4*)(out + (size_t)(c0 + c) * R + r0 + r4) = o;
  }
}

// ---------------------------------------------------------------------------
// fc1: 256x256-tile MFMA GEMM, BK=64, 512 threads, splitK=4.  A = fp32 roi
// read directly (reg-staged cvt, ds_write_b128); B bf16 via global_load_lds.
// Counted-vmcnt 4-phase schedule (see header).  XOR swizzle both sides.
// ---------------------------------------------------------------------------
__global__ __launch_bounds__(512, 2) void gemm8p(
    const float* __restrict__ A, const u16* __restrict__ Bt,
    float* __restrict__ P) {
  const int K = 12544;                 // 4 splits x 49 tiles x BK=64
  __shared__ u16 lds[65536];           // 2 buf x (A 32KB + B 32KB) = 128 KB
  int tid = threadIdx.x;
  int w = tid >> 6, l = tid & 63, h = l >> 4, l15 = l & 15;
  int wm = w >> 2, wn = w & 3;

  int b = ((blockIdx.x & 7) << 5) | (blockIdx.x >> 3);   // XCD-chunked swizzle
  int bz = b >> 6, rest = b & 63;
  int bm = (rest & 15) * 256;
  int bn = (rest >> 4) * 256;
  size_t k0 = (size_t)bz * 3136;

  // ---- A fp32 reg-staging: lane owns 8 consecutive cols of one row/chunk
  int arow = tid >> 3;                      // row 0..63 within chunk
  int c0 = (tid & 7) * 8;                   // col (elems)
  const float* pA0 = A + (size_t)(bm + arow) * K + k0 + c0;
  const size_t aseg = (size_t)64 * K;
  int awe = ((arow * 128 + c0 * 2) ^ ((arow & 7) << 4)) >> 1;          // elems

  // ---- B staging: pre-swizzled per-lane global source, gload16
  int X = ((tid >> 3) & 7) << 4;
  int lb2 = (tid * 16) ^ X;
  int lr = lb2 >> 7, lc = (lb2 & 127) >> 1;
  const u16* pB = Bt + (size_t)(bn + lr) * K + k0 + lc;
  const size_t o64 = (size_t)64 * K, o128 = (size_t)128 * K, o192 = (size_t)192 * K;

  // ds_read swizzled per-lane offsets (loop-invariant)
  int swz = (l15 & 7) << 3;
  int xk0 = (h * 8) ^ swz;
  int xk1 = 32 ^ xk0;
  int rA = (wm * 64 + l15) * 64;
  int rB = (wn * 32 + l15) * 64;

  f32x4 acc[8][4];
#pragma unroll
  for (int i = 0; i < 8; i++)
#pragma unroll
    for (int j = 0; j < 4; j++) acc[i][j] = (f32x4){0.f, 0.f, 0.f, 0.f};

  float4 a0[4], a1[4];
  bf16x8 af[4][2], bl[2][2], bh[2][2];

#define AISSUE(kk) { _Pragma("unroll") for (int s = 0; s < 4; s++) {     \
    a0[s] = *(const float4*)(pA0 + s * aseg + (kk));                     \
    a1[s] = *(const float4*)(pA0 + s * aseg + (kk) + 4); } }
#define BISSUE_LO(WB, kk) {                                              \
    gload16(pB + (kk),        (WB) + tid * 8);                           \
    gload16(pB + o64 + (kk),  (WB) + 4096 + tid * 8); }
#define BISSUE_HI(WB, kk) {                                              \
    gload16(pB + o128 + (kk), (WB) + 8192 + tid * 8);                    \
    gload16(pB + o192 + (kk), (WB) + 12288 + tid * 8); }
#define AWRITE(WA) { _Pragma("unroll") for (int s = 0; s < 4; s++) {     \
    bf16x8 v;                                                            \
    v[0]=(short)f2bf(a0[s].x); v[1]=(short)f2bf(a0[s].y);                \
    v[2]=(short)f2bf(a0[s].z); v[3]=(short)f2bf(a0[s].w);                \
    v[4]=(short)f2bf(a1[s].x); v[5]=(short)f2bf(a1[s].y);                \
    v[6]=(short)f2bf(a1[s].z); v[7]=(short)f2bf(a1[s].w);                \
    *(bf16x8*)&(WA)[awe + s * 4096] = v; } }
#define READ_AF(BASE)                                                    \
  _Pragma("unroll") for (int i = 0; i < 4; i++) {                        \
    af[i][0] = *(const bf16x8*)&LA[(BASE) + rA + i * 1024 + xk0];        \
    af[i][1] = *(const bf16x8*)&LA[(BASE) + rA + i * 1024 + xk1];        \
  }
#define READ_BL {                                                        \
  _Pragma("unroll") for (int j = 0; j < 2; j++) {                        \
    bl[j][0] = *(const bf16x8*)&LB[rB + j * 1024 + xk0];                 \
    bl[j][1] = *(const bf16x8*)&LB[rB + j * 1024 + xk1]; } }
#define READ_BH {                                                        \
  _Pragma("unroll") for (int j = 0; j < 2; j++) {                        \
    bh[j][0] = *(const bf16x8*)&LB[8192 + rB + j * 1024 + xk0];          \
    bh[j][1] = *(const bf16x8*)&LB[8192 + rB + j * 1024 + xk1]; } }
#define Q_MFMA(QR, QC, BF)                                               \
  __builtin_amdgcn_s_setprio(1);                                         \
  _Pragma("unroll") for (int i = 0; i < 4; i++)                          \
    _Pragma("unroll") for (int j = 0; j < 2; j++) {                      \
      acc[(QR)*4+i][(QC)*2+j] = mfma16(af[i][0], BF[j][0], acc[(QR)*4+i][(QC)*2+j]); \
      acc[(QR)*4+i][(QC)*2+j] = mfma16(af[i][1], BF[j][1], acc[(QR)*4+i][(QC)*2+j]); \
    }                                                                    \
  __builtin_amdgcn_s_setprio(0);
#define SBAR __builtin_amdgcn_sched_barrier(0)

  // prologue: tile 0 -> buf0
  AISSUE(0);
  BISSUE_LO(lds + 16384, 0);
  BISSUE_HI(lds + 16384, 0);
  AWRITE(lds);                          // compiler inserts vmcnt(4) for a-regs
  asm volatile("s_waitcnt vmcnt(0) lgkmcnt(0)" ::: "memory");
  __builtin_amdgcn_s_barrier();

  for (int t = 0; t < 48; t++) {
    const u16* LA = lds + (t & 1) * 32768;
    const u16* LB = LA + 16384;
    u16* WA = lds + ((t + 1) & 1) * 32768;
    u16* WB = WA + 16384;
    int ktn = (t + 1) * 64;
    // ph0: issue A(t+1); need B(t)lo + prior AWRITE published
    AISSUE(ktn);
    asm volatile("s_waitcnt vmcnt(10) lgkmcnt(0)" ::: "memory");
    __builtin_amdgcn_s_barrier();
    SBAR;
    READ_AF(0);
    READ_BL;
    Q_MFMA(0, 0, bl);
    SBAR;
    // ph1: issue B(t+1)lo; need B(t)hi
    BISSUE_LO(WB, ktn);
    asm volatile("s_waitcnt vmcnt(10)" ::: "memory");
    __builtin_amdgcn_s_barrier();
    SBAR;
    READ_BH;
    Q_MFMA(0, 1, bh);
    SBAR;
    // ph2: issue B(t+1)hi; Q11 + Q10 (no new sync)
    BISSUE_HI(WB, ktn);
    READ_AF(8192);
    Q_MFMA(1, 1, bh);
    SBAR;
    Q_MFMA(1, 0, bl);
    SBAR;
    // ph3: write A(t+1) (compiler waits vmcnt for a-regs; lgkm drained at
    // next ph0 before the barrier publishes it)
    AWRITE(WA);
  }
  {  // ---- tail tile t=48 (buf0): no issues; counted drain 2 -> 0 ----
    const u16* LA = lds;
    const u16* LB = lds + 16384;
    asm volatile("s_waitcnt vmcnt(2) lgkmcnt(0)" ::: "memory");
    __builtin_amdgcn_s_barrier();
    SBAR;
    READ_AF(0);
    READ_BL;
    Q_MFMA(0, 0, bl);
    SBAR;
    asm volatile("s_waitcnt vmcnt(0)" ::: "memory");
    __builtin_amdgcn_s_barrier();
    SBAR;
    READ_BH;
    Q_MFMA(0, 1, bh);
    SBAR;
    READ_AF(8192);
    Q_MFMA(1, 1, bh);
    Q_MFMA(1, 0, bl);
  }
#undef AISSUE
#undef BISSUE_LO
#undef BISSUE_HI
#undef AWRITE
#undef READ_AF
#undef READ_BL
#undef READ_BH
#undef Q_MFMA
#undef SBAR

  float* dst = P + (size_t)bz * 4096 * 1024;
#pragma unroll
  for (int qr = 0; qr < 2; qr++)
#pragma unroll
    for (int i = 0; i < 4; i++)
#pragma unroll
      for (int qc = 0; qc < 2; qc++)
#pragma unroll
        for (int j = 0; j < 2; j++) {
          int row0 = bm + qr * 128 + wm * 64 + i * 16 + h * 4;
          int col  = bn + qc * 128 + wn * 32 + j * 16 + l15;
          f32x4 v = acc[qr * 4 + i][qc * 2 + j];
#pragma unroll
          for (int r = 0; r < 4; r++)
            dst[(size_t)(row0 + r) * 1024 + col] = v[r];
        }
}

// ---------------------------------------------------------------------------
// fc_reduce (blocks [0,2048)) || pos_logw (blocks [2048,6144)) in one launch.
// ---------------------------------------------------------------------------
__constant__ float C100D[8] = {100.f, 42.16965034285822f, 17.78279410038923f,
                               7.498942093324559f, 3.1622776601683795f,
                               1.333521432163324f, 0.5623413251903491f,
                               0.23713737056616552f};

__global__ __launch_bounds__(256) void reduce_pos_kernel(
    const float* __restrict__ P, const float* __restrict__ bias,
    float* __restrict__ xf, u16* __restrict__ xb,
    const float* __restrict__ bbox,
    const float* __restrict__ Wpos1, const float* __restrict__ Wpos2,
    const float* __restrict__ bpos1, const float* __restrict__ bpos2,
    u16* __restrict__ logw1, u16* __restrict__ logw2) {
  __shared__ u16 pool[18944];     // emb 64*88 | wp 32*88 | lw 2*16*328
  int tid = threadIdx.x;
  if (blockIdx.x < 2048) {        // ---- fc1 split-K reduce ----
    const size_t MN = (size_t)4096 * 1024;
    size_t i = ((size_t)blockIdx.x * 256 + tid) * 4;
    size_t stride = (size_t)2048 * 256 * 4;
    for (; i < MN; i += stride) {
      float4 a = *(const float4*)(P + i);
      float4 b = *(const float4*)(P + MN + i);
      float4 c = *(const float4*)(P + 2 * MN + i);
      float4 d = *(const float4*)(P + 3 * MN + i);
      float4 bv = *(const float4*)(bias + (i & 1023));
      float4 r;
      r.x = a.x + b.x + c.x + d.x + bv.x;
      r.y = a.y + b.y + c.y + d.y + bv.y;
      r.z = a.z + b.z + c.z + d.z + bv.z;
      r.w = a.w + b.w + c.w + d.w + bv.w;
      *(float4*)(xf + i) = r;
      u16x4 hv;
      hv[0] = (short)f2bf(r.x); hv[1] = (short)f2bf(r.y);
      hv[2] = (short)f2bf(r.z); hv[3] = (short)f2bf(r.w);
      *(u16x4*)(xb + i) = hv;
    }
    return;
  }
  // ---- pos_logw ----
  u16* emb_s = pool;              // [64][88]
  u16* wp_s  = pool + 5632;       // [32][88]
  u16* lw_s  = pool + 8448;       // [2*16][328]
  int n = blockIdx.x - 2048;
  int w = tid >> 6, l = tid & 63, h = l >> 4, l15 = l & 15;
  for (int idx = tid; idx < 1024; idx += 256) {   // stage Wpos^T both layers
    int e = idx >> 4, c = idx & 15;               // Wpos[e][c], EMB=64 GROUP=16
    wp_s[c * 88 + e]        = f2bf(Wpos1[idx]);
    wp_s[(16 + c) * 88 + e] = f2bf(Wpos2[idx]);
  }
  float4 bn = ((const float4*)bbox)[n];
  float bw_n = bn.z - bn.x + 1.f, bh_n = bn.w - bn.y + 1.f;
  float cx_n = 0.5f * (bn.x + bn.z), cy_n = 0.5f * (bn.y + bn.w);
  float bps0 = bpos1[l15], bps1 = bpos2[l15];
  int p = tid >> 2, k = tid & 3;

  for (int m0 = 0; m0 < 320; m0 += 64) {
    int m = m0 + p;
    float4 bm = ((const float4*)bbox)[m];
    float v;
    if (k == 0)      v = logf(fmaxf(fabsf((cx_n - 0.5f * (bm.x + bm.z)) / bw_n), 1e-3f));
    else if (k == 1) v = logf(fmaxf(fabsf((cy_n - 0.5f * (bm.y + bm.w)) / bh_n), 1e-3f));
    else if (k == 2) v = logf(bw_n / (bm.z - bm.x + 1.f));
    else             v = logf(bh_n / (bm.w - bm.y + 1.f));
    __syncthreads();                      // protect previous tile's frag reads
#pragma unroll
    for (int tt = 0; tt < 8; tt++) {
      float s, c; fsincos(v * C100D[tt], &s, &c);
      emb_s[p * 88 + k * 16 + tt]     = f2bf(s);
      emb_s[p * 88 + k * 16 + 8 + tt] = f2bf(c);
    }
    __syncthreads();
    f32x4 acc0 = {0.f, 0.f, 0.f, 0.f}, acc1 = {0.f, 0.f, 0.f, 0.f};
    bf16x8 a0 = *(const bf16x8*)&emb_s[(w * 16 + l15) * 88 + h * 8];
    bf16x8 a1 = *(const bf16x8*)&emb_s[(w * 16 + l15) * 88 + 32 + h * 8];
    bf16x8 b00 = *(const bf16x8*)&wp_s[l15 * 88 + h * 8];
    bf16x8 b01 = *(const bf16x8*)&wp_s[l15 * 88 + 32 + h * 8];
    bf16x8 b10 = *(const bf16x8*)&wp_s[(16 + l15) * 88 + h * 8];
    bf16x8 b11 = *(const bf16x8*)&wp_s[(16 + l15) * 88 + 32 + h * 8];
    acc0 = mfma16(a0, b00, acc0); acc0 = mfma16(a1, b01, acc0);
    acc1 = mfma16(a0, b10, acc1); acc1 = mfma16(a1, b11, acc1);
#pragma unroll
    for (int r = 0; r < 4; r++) {
      int mm = m0 + w * 16 + h * 4 + r;
      lw_s[l15 * 328 + mm]        = f2bf(logf(fmaxf(acc0[r] + bps0, 1e-6f)));
      lw_s[(16 + l15) * 328 + mm] = f2bf(logf(fmaxf(acc1[r] + bps1, 1e-6f)));
    }
  }
  __syncthreads();
  for (int i = tid; i < 1280; i += 256) {       // 2 layers * 16 g * 40 segs
    int layer = i / 640, rest = i - layer * 640;
    int gg = rest / 40, seg = rest - gg * 40;
    bf16x8 v = *(const bf16x8*)&lw_s[(layer * 16 + gg) * 328 + seg * 8];
    u16* dst = (layer ? logw2 : logw1) + ((size_t)gg * 4096 + n) * 320 + seg * 8;
    *(bf16x8*)dst = v;
  }
}

// ---------------------------------------------------------------------------
// gemmU: 128x128-tile BK=64 pipelined GEMM (single wait/tile, 64KB LDS ->
// 2 blocks/CU), up to 3 problems per grid.  C = A[MxK]*Bt[NxK]^T (+bias).
// ---------------------------------------------------------------------------
struct GDesc {
  const u16* A; const u16* Bt; const float* bias;
  u16* Cb; float* Cf;
  int M, N, K, ldc, nt;          // nt = #128-wide col tiles
};

__global__ __launch_bounds__(256, 2) void gemmU(GDesc g0, GDesc g1, GDesc g2,
                                                int c0, int c1) {
  __shared__ u16 lds[32768];     // 2 buf x (A 128x64 + B 128x64) bf16 = 64 KB
  GDesc g; int lb = blockIdx.x;
  if (lb < c0) { g = g0; lb = (lb & 7) * (c0 >> 3) + (lb >> 3); }  // XCD swz
  else if (lb < c1) { g = g1; lb -= c0; }
  else { g = g2; lb -= c1; }
  int bm = (lb / g.nt) * 128, bn = (lb % g.nt) * 128;
  int tid = threadIdx.x;
  int w = tid >> 6, l = tid & 63, h = l >> 4, l15 = l & 15;
  int wm = w >> 1, wn = w & 1;
  int K = g.K;

  int X = ((tid >> 3) & 7) << 4;
  int lbyte = (tid * 16) ^ X;
  int lr = lbyte >> 7, lc = (lbyte & 127) >> 1;
  const u16 *pa[4], *pb[4];
#pragma unroll
  for (int c = 0; c < 4; c++) {
    pa[c] = g.A  + (size_t)min(bm + c * 32 + lr, g.M - 1) * K + lc;
    pb[c] = g.Bt + (size_t)min(bn + c * 32 + lr, g.N - 1) * K + lc;
  }

  int swz = (l15 & 7) << 3;
  int xk0 = (h * 8) ^ swz;
  int xk1 = 32 ^ xk0;
  int rA = (wm * 64 + l15) * 64;
  int rB = (wn * 64 + l15) * 64;

  f32x4 acc[4][4];
#pragma unroll
  for (int i = 0; i < 4; i++)
#pragma unroll
    for (int j = 0; j < 4; j++) acc[i][j] = (f32x4){0.f, 0.f, 0.f, 0.f};

#define ISSUEU(W, kk)                                     \
  { gload16(pa[0] + (kk), (W) + tid * 8);                 \
    gload16(pa[1] + (kk), (W) + 2048 + tid * 8);          \
    gload16(pa[2] + (kk), (W) + 4096 + tid * 8);          \
    gload16(pa[3] + (kk), (W) + 6144 + tid * 8);          \
    gload16(pb[0] + (kk), (W) + 8192 + tid * 8);          \
    gload16(pb[1] + (kk), (W) + 10240 + tid * 8);         \
    gload16(pb[2] + (kk), (W) + 12288 + tid * 8);         \
    gload16(pb[3] + (kk), (W) + 14336 + tid * 8); }

  ISSUEU(lds, 0);
  int ktiles = K >> 6;
  for (int t = 0; t < ktiles; t++) {
    const u16* LA = lds + (t & 1) * 16384;
    const u16* LB = LA + 8192;
    u16* W = lds + ((t ^ 1) & 1) * 16384;
    if (t < ktiles - 1) {
      ISSUEU(W, (t + 1) * 64);
      asm volatile("s_waitcnt vmcnt(8)" ::: "memory");
    } else {
      asm volatile("s_waitcnt vmcnt(0)" ::: "memory");
    }
    __builtin_amdgcn_s_barrier();
    asm volatile("" ::: "memory");
    bf16x8 a[4][2], bfr[4][2];
#pragma unroll
    for (int i = 0; i < 4; i++) {
      a[i][0] = *(const bf16x8*)&LA[rA + i * 1024 + xk0];
      a[i][1] = *(const bf16x8*)&LA[rA + i * 1024 + xk1];
    }
#pragma unroll
    for (int j = 0; j < 4; j++) {
      bfr[j][0] = *(const bf16x8*)&LB[rB + j * 1024 + xk0];
      bfr[j][1] = *(const bf16x8*)&LB[rB + j * 1024 + xk1];
    }
    __builtin_amdgcn_s_setprio(1);
#pragma unroll
    for (int i = 0; i < 4; i++)
#pragma unroll
      for (int j = 0; j < 4; j++) {
        acc[i][j] = mfma16(a[i][0], bfr[j][0], acc[i][j]);
        acc[i][j] = mfma16(a[i][1], bfr[j][1], acc[i][j]);
      }
    __builtin_amdgcn_s_setprio(0);
    asm volatile("" ::: "memory");
    __builtin_amdgcn_s_barrier();
  }
#undef ISSUEU

#pragma unroll
  for (int i = 0; i < 4; i++) {
#pragma unroll
    for (int j = 0; j < 4; j++) {
      int col = bn + wn * 64 + j * 16 + l15;
      if (col >= g.ldc) continue;
      float bv = (g.bias != nullptr && col < g.N) ? g.bias[col] : 0.f;
      int row0 = bm + wm * 64 + i * 16 + h * 4;
#pragma unroll
      for (int r = 0; r < 4; r++) {
        int row = row0 + r;
        if (row >= g.M) continue;
        float v = acc[i][j][r] + bv;
        size_t off = (size_t)row * g.ldc + col;
        g.Cb[off] = f2bf(v);
        if (g.Cf != nullptr) g.Cf[off] = v;
      }
    }
  }
}

// ---------------------------------------------------------------------------
// fused attention per (64-row n-tile, head g).  No K/KVt LDS staging (both
// L2-resident; 64B-segment global frag reads).  LDS = logw[64][328] then
// P[64][344] (union, 44KB) -> 3 blocks/CU.
// ---------------------------------------------------------------------------
template <bool LAST>
__global__ __launch_bounds__(256) void attn_kernel(
    const u16* __restrict__ qb, const u16* __restrict__ kb,
    const u16* __restrict__ kvt, const u16* __restrict__ logw,
    const float* __restrict__ xf, const float* __restrict__ bo,
    float* __restrict__ outf, u16* __restrict__ outb) {
  __shared__ u16 ps[64 * 344];      // logw [64][328]; then P [64][344]
  int tid = threadIdx.x;
  int g = blockIdx.y, n0 = blockIdx.x * 64;
  int w = tid >> 6, l = tid & 63, h = l >> 4, l15 = l & 15;

  {                                 // stage logw tile (contiguous 40KB)
    const u16* src = logw + ((size_t)g * 4096 + n0) * 320;
    for (int i = tid; i < 64 * 40; i += 256) {
      int row = i / 40, seg = i - row * 40;
      *(bf16x8*)&ps[row * 328 + seg * 8] = *(const bf16x8*)(src + row * 320 + seg * 8);
    }
  }
  int nrow = n0 + w * 16 + l15;
  const u16* qp = qb + (size_t)nrow * 1024 + g * 64;
  bf16x8 aq0 = *(const bf16x8*)(qp + h * 8);
  bf16x8 aq1 = *(const bf16x8*)(qp + 32 + h * 8);

  f32x4 acc[19];
#pragma unroll
  for (int f = 0; f < 19; f++) acc[f] = (f32x4){0.f, 0.f, 0.f, 0.f};
  const u16* kp = kb + g * 64 + h * 8;
#pragma unroll
  for (int f = 0; f < 19; f++) {      // QK^T, K frags direct from global (L2)
    bf16x8 b0 = *(const bf16x8*)(kp + (size_t)(f * 16 + l15) * 1024);
    bf16x8 b1 = *(const bf16x8*)(kp + (size_t)(f * 16 + l15) * 1024 + 32);
    acc[f] = mfma16(aq0, b0, acc[f]);
    acc[f] = mfma16(aq1, b1, acc[f]);
  }
  __syncthreads();                    // logw staged

  int nbase = n0 + w * 16 + h * 4;
  int lrow = w * 16 + h * 4;
  float mx[4] = {-INFINITY, -INFINITY, -INFINITY, -INFINITY};
  float sm[4] = {0.f, 0.f, 0.f, 0.f};
#pragma unroll
  for (int f = 0; f < 19; f++) {
    int m = f * 16 + l15;
#pragma unroll
    for (int r = 0; r < 4; r++) {
      float lw = -INFINITY;
      if (m < 300) lw = bf2f(ps[(lrow + r) * 328 + m]);
      float lg = acc[f][r] * 0.125f + lw;
      acc[f][r] = lg;
      mx[r] = fmaxf(mx[r], lg);
    }
  }
#pragma unroll
  for (int d = 1; d < 16; d <<= 1)
#pragma unroll
    for (int r = 0; r < 4; r++) mx[r] = fmaxf(mx[r], __shfl_xor(mx[r], d));
#pragma unroll
  for (int f = 0; f < 19; f++)
#pragma unroll
    for (int r = 0; r < 4; r++) {
      float p = __expf(acc[f][r] - mx[r]);
      acc[f][r] = p; sm[r] += p;
    }
#pragma unroll
  for (int d = 1; d < 16; d <<= 1)
#pragma unroll
    for (int r = 0; r < 4; r++) sm[r] += __shfl_xor(sm[r], d);
  float inv[4];
#pragma unroll
  for (int r = 0; r < 4; r++) inv[r] = 1.f / sm[r];

  __syncthreads();                    // all waves done reading logw
#pragma unroll
  for (int f = 0; f < 19; f++)
#pragma unroll
    for (int r = 0; r < 4; r++)
      ps[(lrow + r) * 344 + f * 16 + l15] = f2bf(acc[f][r]);
#pragma unroll
  for (int r = 0; r < 4; r++)         // zero pad m 304..319
    ps[(lrow + r) * 344 + 304 + l15] = 0;

  f32x4 acc2[4];
#pragma unroll
  for (int fo = 0; fo < 4; fo++) acc2[fo] = (f32x4){0.f, 0.f, 0.f, 0.f};
  const u16* vp = kvt + (size_t)g * 64 * 320 + h * 8;
#pragma unroll
  for (int ks = 0; ks < 10; ks++) {   // PV: P rows are wave-local; KVt global
    bf16x8 ap = *(const bf16x8*)&ps[(w * 16 + l15) * 344 + ks * 32 + h * 8];
#pragma unroll
    for (int fo = 0; fo < 4; fo++) {
      bf16x8 bv = *(const bf16x8*)(vp + (size_t)(fo * 16 + l15) * 320 + ks * 32);
      acc2[fo] = mfma16(ap, bv, acc2[fo]);
    }
  }
#pragma unroll
  for (int fo = 0; fo < 4; fo++) {
    int col = g * 64 + fo * 16 + l15;
    float bov = bo[col];
#pragma unroll
    for (int r = 0; r < 4; r++) {
      int row = nbase + r;
      float v = xf[(size_t)row * 1024 + col] + acc2[fo][r] * inv[r] + bov;
      v = fmaxf(v, 0.f);
      if (LAST) outf[(size_t)row * 1024 + col] = v;
      else      outb[(size_t)row * 1024 + col] = f2bf(v);
    }
  }
}

// ---------------------------------------------------------------------------
extern "C" void kernel_launch(void* const* d_in, const int* in_sizes, int n_in,
                              void* d_out, int out_size, void* d_ws, size_t ws_size,
                              hipStream_t stream) {
  (void)in_sizes; (void)n_in; (void)out_size; (void)ws_size;
  const float* roi   = (const float*)d_in[0];
  const float* bbox  = (const float*)d_in[1];
  const float* Wfc1  = (const float*)d_in[2];
  const float* bfc1  = (const float*)d_in[3];
  const float* Wfc2  = (const float*)d_in[4];
  const float* bfc2  = (const float*)d_in[5];
  const float* Wpos1 = (const float*)d_in[6];
  const float* bpos1 = (const float*)d_in[7];
  const float* Wq1   = (const float*)d_in[8];
  const float* bq1   = (const float*)d_in[9];
  const float* Wk1   = (const float*)d_in[10];
  const float* bk1   = (const float*)d_in[11];
  const float* Wo1   = (const float*)d_in[12];
  const float* bo1   = (const float*)d_in[13];
  const float* Wpos2 = (const float*)d_in[14];
  const float* bpos2 = (const float*)d_in[15];
  const float* Wq2   = (const float*)d_in[16];
  const float* bq2   = (const float*)d_in[17];
  const float* Wk2   = (const float*)d_in[18];
  const float* bk2   = (const float*)d_in[19];
  const float* Wo2   = (const float*)d_in[20];
  const float* bo2   = (const float*)d_in[21];

  char* ws = (char*)d_ws;                       // ---- workspace arena ----
  u16*  Wfc1_t = (u16*)(ws + 102760448);        //  25,690,112
  u16*  Wfc2_t = (u16*)(ws + 128450560);        //   2,097,152 each
  u16*  Wq1_t  = (u16*)(ws + 130547712);
  u16*  Wk1_t  = (u16*)(ws + 132644864);
  u16*  Wq2_t  = (u16*)(ws + 134742016);
  u16*  Wk2_t  = (u16*)(ws + 136839168);
  u16*  Wo1_b  = (u16*)(ws + 138936320);
  u16*  Wo2_b  = (u16*)(ws + 141033472);
  float* Pp    = (float*)(ws + 143134720);      //  67,108,864 (splitK partials)
  float* xf    = (float*)(ws + 227020800);      //  16,777,216
  u16*  xb_f   = (u16*)(ws + 243798016);        //   8,388,608 (fc out, bf16)
  u16*  xb_a   = (u16*)(ws + 252186624);        //   8,388,608 (attn out, bf16)
  u16*  q_b    = (u16*)(ws + 260575232);        //   8,388,608
  u16*  k_b    = (u16*)(ws + 268963840);        //     614,400
  u16*  kvt_b  = (u16*)(ws + 269578240);        //     655,360
  u16*  logw1  = (u16*)(ws + 270233600);        //  41,943,040
  u16*  logw2  = (u16*)(ws + 312176640);        //  41,943,040 (end 354,119,680)

  {                                             // 1. prep (weight converts)
    PrepArgs p;
    p.Wo1 = Wo1;   p.Wo1_b = Wo1_b;
    p.Wo2 = Wo2;   p.Wo2_b = Wo2_b;
    p.Wfc1 = Wfc1; p.Wfc1_t = Wfc1_t;
    p.wsrc[0] = Wfc2; p.wdst[0] = Wfc2_t;
    p.wsrc[1] = Wq1;  p.wdst[1] = Wq1_t;
    p.wsrc[2] = Wk1;  p.wdst[2] = Wk1_t;
    p.wsrc[3] = Wq2;  p.wdst[3] = Wq2_t;
    p.wsrc[4] = Wk2;  p.wdst[4] = Wk2_t;
    prep_kernel<<<18688, 256, 0, stream>>>(p);
  }
  // 2. fc1 split-K=4 (reads fp32 roi directly)
  gemm8p<<<256, 512, 0, stream>>>(roi, Wfc1_t, Pp);
  // 3. reduce || pos tables
  reduce_pos_kernel<<<6144, 256, 0, stream>>>(Pp, bfc1, xf, xb_f, bbox,
                                              Wpos1, Wpos2, bpos1, bpos2,
                                              logw1, logw2);
  // ---- layer 1 ----
  {
    GDesc q  = {xb_f,  Wq1_t, bq1, q_b,   nullptr, 4096, 1024, 1024, 1024, 8};
    GDesc kk = {xb_f,  Wk1_t, bk1, k_b,   nullptr,  300, 1024, 1024, 1024, 8};
    GDesc kv = {Wo1_b, xb_f,  nullptr, kvt_b, nullptr, 1024, 300, 1024, 320, 3};
    gemmU<<<304, 256, 0, stream>>>(q, kk, kv, 256, 280);
  }
  attn_kernel<false><<<dim3(64, 16), 256, 0, stream>>>(q_b, k_b, kvt_b, logw1, xf, bo1, nullptr, xb_a);

  // ---- layer 2 ----
  {
    GDesc fc = {xb_a, Wfc2_t, bfc2, xb_f, xf, 4096, 1024, 1024, 1024, 8};
    gemmU<<<256, 256, 0, stream>>>(fc, fc, fc, 256, 256);
  }
  {
    GDesc q  = {xb_f,  Wq2_t, bq2, q_b,   nullptr, 4096, 1024, 1024, 1024, 8};
    GDesc kk = {xb_f,  Wk2_t, bk2, k_b,   nullptr,  300, 1024, 1024, 1024, 8};
    GDesc kv = {Wo2_b, xb_f,  nullptr, kvt_b, nullptr, 1024, 300, 1024, 320, 3};
    gemmU<<<304, 256, 0, stream>>>(q, kk, kv, 256, 280);
  }
  attn_kernel<true><<<dim3(64, 16), 256, 0, stream>>>(q_b, k_b, kvt_b, logw2, xf, bo2, (float*)d_out, nullptr);
}